// Round 2
// baseline (17079.288 us; speedup 1.0000x reference)
//
#include <hip/hip_runtime.h>
#include <math.h>

#define BB 16
#define LL 4096
#define DIN 8
#define DD 512
#define HH 8
#define DKK 64
#define DFF 2048
#define OUTLEN 96
#define TAIL0 (LL - OUTLEN)   /* 4000 */
#define NTAIL (BB * OUTLEN)   /* 1536 */
#define UMAX 10
#define CH 8192               /* FFN row chunk */

// ---------- wave helpers (64 lanes) ----------
__device__ inline float wsum(float v){
#pragma unroll
  for (int o = 32; o > 0; o >>= 1) v += __shfl_xor(v, o);
  return v;
}
__device__ inline float wmax(float v){
#pragma unroll
  for (int o = 32; o > 0; o >>= 1) v = fmaxf(v, __shfl_xor(v, o));
  return v;
}

// ---------- embed: h = x @ w_embed + b_embed ----------
__global__ __launch_bounds__(256) void embed_kernel(const float* __restrict__ x,
    const float* __restrict__ we, const float* __restrict__ be, float* __restrict__ h){
  int row = blockIdx.x;                 // b*LL + l
  __shared__ float xs[DIN];
  if (threadIdx.x < DIN) xs[threadIdx.x] = x[(size_t)row * DIN + threadIdx.x];
  __syncthreads();
  for (int j = threadIdx.x; j < DD; j += 256){
    float acc = be[j];
#pragma unroll
    for (int i = 0; i < DIN; ++i) acc += xs[i] * we[i * DD + j];
    h[(size_t)row * DD + j] = acc;
  }
}

// ---------- fp32 tiled GEMM: C = A(MxK) @ W(KxN) (+bias)(relu) ----------
template<bool RELU, bool BIAS>
__global__ __launch_bounds__(256) void gemm_tile(const float* __restrict__ A,
    const float* __restrict__ W, const float* __restrict__ bias,
    float* __restrict__ C, int M, int N, int K){
  __shared__ float As[32][68];   // [k][m], padded
  __shared__ float Bs[32][64];   // [k][n]
  const int tid = threadIdx.x;
  const int tx = tid & 15;       // n
  const int ty = tid >> 4;       // m
  const int m0 = blockIdx.y * 64;
  const int n0 = blockIdx.x * 64;

  float acc[4][4] = {{0.f}};

  for (int k0 = 0; k0 < K; k0 += 32){
    {
      int r  = tid >> 3;              // 0..31
      int c4 = (tid & 7) * 4;         // 0..28
      float4 a0 = *(const float4*)&A[(size_t)(m0 + r) * K + k0 + c4];
      float4 a1 = *(const float4*)&A[(size_t)(m0 + r + 32) * K + k0 + c4];
      As[c4+0][r] = a0.x; As[c4+1][r] = a0.y; As[c4+2][r] = a0.z; As[c4+3][r] = a0.w;
      As[c4+0][r+32] = a1.x; As[c4+1][r+32] = a1.y; As[c4+2][r+32] = a1.z; As[c4+3][r+32] = a1.w;
    }
    {
      int r  = tid >> 4;              // 0..15
      int c4 = (tid & 15) * 4;        // 0..60
      *(float4*)&Bs[r][c4]    = *(const float4*)&W[(size_t)(k0 + r) * N + n0 + c4];
      *(float4*)&Bs[r+16][c4] = *(const float4*)&W[(size_t)(k0 + r + 16) * N + n0 + c4];
    }
    __syncthreads();
#pragma unroll
    for (int kk = 0; kk < 32; ++kk){
      const float4 a  = *(const float4*)&As[kk][ty*4];
      const float4 b4 = *(const float4*)&Bs[kk][tx*4];
      acc[0][0] += a.x*b4.x; acc[0][1] += a.x*b4.y; acc[0][2] += a.x*b4.z; acc[0][3] += a.x*b4.w;
      acc[1][0] += a.y*b4.x; acc[1][1] += a.y*b4.y; acc[1][2] += a.y*b4.z; acc[1][3] += a.y*b4.w;
      acc[2][0] += a.z*b4.x; acc[2][1] += a.z*b4.y; acc[2][2] += a.z*b4.z; acc[2][3] += a.z*b4.w;
      acc[3][0] += a.w*b4.x; acc[3][1] += a.w*b4.y; acc[3][2] += a.w*b4.z; acc[3][3] += a.w*b4.w;
    }
    __syncthreads();
  }

  float4 bv = make_float4(0.f,0.f,0.f,0.f);
  if (BIAS) bv = *(const float4*)&bias[n0 + tx*4];
#pragma unroll
  for (int i = 0; i < 4; ++i){
    int gm = m0 + ty*4 + i;
    float4 r;
    r.x = acc[i][0] + bv.x; r.y = acc[i][1] + bv.y;
    r.z = acc[i][2] + bv.z; r.w = acc[i][3] + bv.w;
    if (RELU){ r.x = fmaxf(r.x,0.f); r.y = fmaxf(r.y,0.f); r.z = fmaxf(r.z,0.f); r.w = fmaxf(r.w,0.f); }
    *(float4*)&C[(size_t)gm * N + n0 + tx*4] = r;
  }
}

// ---------- qs scoring for one batch: qb is LLxDD, qsb is HHxLL ----------
__global__ __launch_bounds__(256) void qs_kernel(const float* __restrict__ qb, float* __restrict__ qsb){
  int tid = threadIdx.x;
  int lane = tid & 63;
  int wv = tid >> 6;
  int rid = blockIdx.x * 4 + wv;        // < HH*LL ; rid = h*LL + l
  int hh = rid >> 12;
  int l  = rid & (LL - 1);
  float qv = qb[(size_t)l * DD + hh * DKK + lane];
  float l2 = sqrtf(wsum(qv * qv));
  float mx = wmax(qv);
  float e  = expf(qv - mx);
  float se = wsum(e);
  float p  = e / se;
  float ent = -wsum(p * logf(p + 1e-9f));
  float mu  = wsum(qv) * (1.0f / 64.0f);
  float dv  = qv - mu;
  float var = wsum(dv * dv) * (1.0f / 63.0f);
  float val = 0.5f * l2 + 0.3f * ent + 0.2f * var;
  if (lane == 0) qsb[rid] = val;
}

// ---------- u factor from head-0 stats of this batch ----------
__global__ __launch_bounds__(256) void ufac_kernel(const float* __restrict__ qsb, int* __restrict__ u, int b){
  __shared__ double r1[256], r2[256];
  int tid = threadIdx.x;
  const float* row = qsb;               // head 0
  double s = 0.0, s2 = 0.0;
  for (int l = tid; l < LL; l += 256){ double v = row[l]; s += v; s2 += v * v; }
  r1[tid] = s; r2[tid] = s2; __syncthreads();
  for (int st = 128; st; st >>= 1){
    if (tid < st){ r1[tid] += r1[tid+st]; r2[tid] += r2[tid+st]; }
    __syncthreads();
  }
  if (tid == 0){
    double mean = r1[0] / (double)LL;
    double var  = (r2[0] - (double)LL * mean * mean) / (double)(LL - 1);
    if (var < 0.0) var = 0.0;
    double f = rint(sqrt(var) / (mean + 1e-6) * 10.0);  // round-half-even like jnp.round
    if (f < 3.0) f = 3.0;
    if (f > 10.0) f = 10.0;
    u[b] = (int)f;
  }
}

// ---------- top-10 per head (one block per h), ties -> lowest index ----------
__global__ __launch_bounds__(256) void topk_kernel(const float* __restrict__ qsb, int* __restrict__ topidx, int b){
  __shared__ float vals[LL];
  __shared__ float bv[256];
  __shared__ int   bi[256];
  int hh = blockIdx.x, tid = threadIdx.x;
  const float* row = qsb + (size_t)hh * LL;
  for (int l = tid; l < LL; l += 256) vals[l] = row[l];
  __syncthreads();
  for (int it = 0; it < UMAX; ++it){
    float best = -INFINITY; int bidx = 0;
    for (int l = tid; l < LL; l += 256){
      float v = vals[l];
      if (v > best){ best = v; bidx = l; }
    }
    bv[tid] = best; bi[tid] = bidx; __syncthreads();
    for (int st = 128; st; st >>= 1){
      if (tid < st){
        if (bv[tid+st] > bv[tid] || (bv[tid+st] == bv[tid] && bi[tid+st] < bi[tid])){
          bv[tid] = bv[tid+st]; bi[tid] = bi[tid+st];
        }
      }
      __syncthreads();
    }
    if (tid == 0){ topidx[(b * HH + hh) * UMAX + it] = bi[0]; vals[bi[0]] = -INFINITY; }
    __syncthreads();
  }
}

// ---------- sparse attention rows for one batch ----------
__global__ __launch_bounds__(256) void attn_kernel(const float* __restrict__ qb,
    const float* __restrict__ kb, const float* __restrict__ vb,
    const int* __restrict__ topidx, const int* __restrict__ u,
    float* __restrict__ outrows, int b, int lmin){
  int blk = blockIdx.x;                  // < HH*UMAX
  int hh = blk / UMAX, rank = blk % UMAX;
  if (rank >= u[b]) return;
  int qpos = topidx[(b * HH + hh) * UMAX + rank];
  if (qpos < lmin) return;

  __shared__ float sc[LL];
  __shared__ float qrow[DKK];
  __shared__ float red[256];
  int tid = threadIdx.x;
  if (tid < DKK) qrow[tid] = qb[(size_t)qpos * DD + hh * DKK + tid];
  __syncthreads();

  float m = -INFINITY;
  for (int l = tid; l < LL; l += 256){
    const float* kr = kb + (size_t)l * DD + hh * DKK;
    float s = 0.f;
#pragma unroll
    for (int d = 0; d < DKK; d += 4){
      float4 k4 = *(const float4*)&kr[d];
      s += qrow[d] * k4.x + qrow[d+1] * k4.y + qrow[d+2] * k4.z + qrow[d+3] * k4.w;
    }
    s *= 0.125f;                 // 1/sqrt(64)
    sc[l] = s;
    m = fmaxf(m, s);
  }
  red[tid] = m; __syncthreads();
  for (int st = 128; st; st >>= 1){ if (tid < st) red[tid] = fmaxf(red[tid], red[tid+st]); __syncthreads(); }
  float M = red[0]; __syncthreads();

  float ssum = 0.f;
  for (int l = tid; l < LL; l += 256){ float e = expf(sc[l] - M); sc[l] = e; ssum += e; }
  red[tid] = ssum; __syncthreads();
  for (int st = 128; st; st >>= 1){ if (tid < st) red[tid] += red[tid+st]; __syncthreads(); }
  float S = red[0]; __syncthreads();

  int d = tid & 63, g = tid >> 6;
  float acc = 0.f;
  for (int l = g; l < LL; l += 4)
    acc += sc[l] * vb[(size_t)l * DD + hh * DKK + d];
  red[tid] = acc; __syncthreads();
  if (tid < 64){
    float o = (red[d] + red[64+d] + red[128+d] + red[192+d]) / S;
    outrows[(size_t)(hh * UMAX + rank) * DKK + d] = o;
  }
}

// ---------- scatter delta = out_row @ wo[h-block] into target (atomicAdd) ----------
__global__ __launch_bounds__(256) void scatter_kernel(const float* __restrict__ outrows,
    const float* __restrict__ wo, const int* __restrict__ topidx, const int* __restrict__ u,
    float* __restrict__ target, int b, int tailmode){
  int blk = blockIdx.x;                  // < HH*UMAX
  int hh = blk / UMAX, rank = blk % UMAX;
  if (rank >= u[b]) return;
  int qpos = topidx[(b * HH + hh) * UMAX + rank];
  size_t drow;
  if (tailmode){
    if (qpos < TAIL0) return;
    drow = (size_t)(b * OUTLEN + (qpos - TAIL0));
  } else {
    drow = (size_t)b * LL + qpos;
  }
  __shared__ float orow[DKK];
  int tid = threadIdx.x;
  if (tid < DKK) orow[tid] = outrows[(size_t)(hh * UMAX + rank) * DKK + tid];
  __syncthreads();
  for (int j = tid; j < DD; j += 256){
    float acc = 0.f;
#pragma unroll
    for (int dd = 0; dd < DKK; ++dd) acc += orow[dd] * wo[(size_t)(hh * DKK + dd) * DD + j];
    atomicAdd(&target[drow * DD + j], acc);
  }
}

// ---------- zero fill ----------
__global__ void zero_kernel(float* __restrict__ p, size_t n){
  size_t i = (size_t)blockIdx.x * 256 + threadIdx.x;
  size_t stride = (size_t)gridDim.x * 256;
  for (; i < n; i += stride) p[i] = 0.f;
}

// ---------- O_row = LN(X_row [+Y_row] [+bias]) * g + bb ----------
__global__ __launch_bounds__(256) void add_ln_kernel(const float* __restrict__ X,
    const float* __restrict__ Y, const float* __restrict__ bias, float* __restrict__ O,
    const float* __restrict__ g, const float* __restrict__ bb, int tailmapX){
  __shared__ float red[256];
  int r = blockIdx.x, tid = threadIdx.x;
  const float* xr;
  if (tailmapX){
    int b = r / OUTLEN;
    int l = TAIL0 + (r % OUTLEN);
    xr = X + ((size_t)b * LL + l) * DD;
  } else {
    xr = X + (size_t)r * DD;
  }
  float v0 = xr[tid];
  float v1 = xr[tid + 256];
  if (Y){
    const float* yr = Y + (size_t)r * DD;
    v0 += yr[tid]; v1 += yr[tid + 256];
  }
  if (bias){ v0 += bias[tid]; v1 += bias[tid + 256]; }
  red[tid] = v0 + v1; __syncthreads();
  for (int st = 128; st; st >>= 1){ if (tid < st) red[tid] += red[tid+st]; __syncthreads(); }
  float mu = red[0] * (1.0f / DD); __syncthreads();
  float d0 = v0 - mu, d1 = v1 - mu;
  red[tid] = d0*d0 + d1*d1; __syncthreads();
  for (int st = 128; st; st >>= 1){ if (tid < st) red[tid] += red[tid+st]; __syncthreads(); }
  float rstd = rsqrtf(red[0] * (1.0f / DD) + 1e-5f);
  float* orow = O + (size_t)r * DD;
  orow[tid]       = d0 * rstd * g[tid]       + bb[tid];
  orow[tid + 256] = d1 * rstd * g[tid + 256] + bb[tid + 256];
}

// ---------- final: pred = htail @ w_out + b_out ----------
__global__ __launch_bounds__(64) void pred_kernel(const float* __restrict__ ht,
    const float* __restrict__ wout, const float* __restrict__ bout, float* __restrict__ out){
  int r = blockIdx.x, lane = threadIdx.x;
  float acc = 0.f;
  for (int dd = lane; dd < DD; dd += 64) acc += ht[(size_t)r * DD + dd] * wout[dd];
  acc = wsum(acc);
  if (lane == 0) out[r] = acc + bout[0];
}

extern "C" void kernel_launch(void* const* d_in, const int* in_sizes, int n_in,
                              void* d_out, int out_size, void* d_ws, size_t ws_size,
                              hipStream_t stream){
  const float* x    = (const float*)d_in[0];
  const float* wemb = (const float*)d_in[1];
  const float* bemb = (const float*)d_in[2];
  const float* wq   = (const float*)d_in[3];
  const float* bq   = (const float*)d_in[4];
  const float* wk   = (const float*)d_in[5];
  const float* bk   = (const float*)d_in[6];
  const float* wv   = (const float*)d_in[7];
  const float* bvv  = (const float*)d_in[8];
  const float* wo   = (const float*)d_in[9];
  const float* bo   = (const float*)d_in[10];
  const float* w1   = (const float*)d_in[11];
  const float* b1   = (const float*)d_in[12];
  const float* w2   = (const float*)d_in[13];
  const float* b2   = (const float*)d_in[14];
  const float* g1   = (const float*)d_in[15];
  const float* be1  = (const float*)d_in[16];
  const float* g2   = (const float*)d_in[17];
  const float* be2  = (const float*)d_in[18];
  const float* wout = (const float*)d_in[19];
  const float* bout = (const float*)d_in[20];
  float* out = (float*)d_out;
  float* ws  = (float*)d_ws;

  const size_t NH  = (size_t)BB * LL * DD;      // 33,554,432 floats (128 MiB)
  const size_t PB  = (size_t)LL * DD;           // per-batch QKV: 2,097,152 floats (8 MiB)

  float* h       = ws;                          // NH
  float* qb      = h + NH;                      // PB
  float* kb      = qb + PB;                     // PB
  float* vb      = kb + PB;                     // PB
  float* hid     = vb + PB;                     // CH*DFF = 16,777,216 (64 MiB)
  float* fbuf    = hid + (size_t)CH * DFF;      // CH*DD  =  4,194,304 (16 MiB)
  float* qsb     = fbuf + (size_t)CH * DD;      // HH*LL  = 32,768
  float* outrows = qsb + (size_t)HH * LL;       // HH*UMAX*DKK = 5,120
  float* htail   = outrows + (size_t)HH * UMAX * DKK;  // NTAIL*DD = 786,432
  float* ftail   = htail + (size_t)NTAIL * DD;  // 786,432
  int*   topidx  = (int*)(ftail + (size_t)NTAIL * DD); // BB*HH*UMAX = 1280
  int*   ufac    = topidx + BB * HH * UMAX;     // BB
  // total ~234.3 MiB

  // 1. embed
  embed_kernel<<<BB * LL, 256, 0, stream>>>(x, wemb, bemb, h);

  for (int layer = 0; layer < 2; ++layer){
    const bool tail = (layer == 1);
    if (tail) zero_kernel<<<1024, 256, 0, stream>>>(ftail, (size_t)NTAIL * DD);

    for (int b = 0; b < BB; ++b){
      const float* hb = h + (size_t)b * PB;
      // per-batch QKV projections (fp32; scoring path must stay accurate)
      gemm_tile<false, true><<<dim3(DD/64, LL/64), 256, 0, stream>>>(hb, wq, bq,  qb, LL, DD, DD);
      qs_kernel<<<(HH*LL)/4, 256, 0, stream>>>(qb, qsb);
      ufac_kernel<<<1, 256, 0, stream>>>(qsb, ufac, b);
      topk_kernel<<<HH, 256, 0, stream>>>(qsb, topidx, b);
      gemm_tile<false, true><<<dim3(DD/64, LL/64), 256, 0, stream>>>(hb, wk, bk,  kb, LL, DD, DD);
      gemm_tile<false, true><<<dim3(DD/64, LL/64), 256, 0, stream>>>(hb, wv, bvv, vb, LL, DD, DD);
      attn_kernel<<<HH*UMAX, 256, 0, stream>>>(qb, kb, vb, topidx, ufac, outrows, b, tail ? TAIL0 : 0);
      if (!tail){
        // add attn-out projection delta directly into h (bo added inside LN)
        scatter_kernel<<<HH*UMAX, 256, 0, stream>>>(outrows, wo, topidx, ufac, h, b, 0);
      } else {
        scatter_kernel<<<HH*UMAX, 256, 0, stream>>>(outrows, wo, topidx, ufac, ftail, b, 1);
      }
    }

    if (!tail){
      // h = LN(h + bo)
      add_ln_kernel<<<BB*LL, 256, 0, stream>>>(h, nullptr, bo, h, g1, be1, 0);
      // FFN chunked: h_c = LN(h_c + relu(h_c@w1+b1)@w2+b2)
      for (int c = 0; c < (BB*LL)/CH; ++c){
        float* hc = h + (size_t)c * CH * DD;
        gemm_tile<true,  true><<<dim3(DFF/64, CH/64), 256, 0, stream>>>(hc, w1, b1, hid, CH, DFF, DD);
        gemm_tile<false, true><<<dim3(DD/64,  CH/64), 256, 0, stream>>>(hid, w2, b2, fbuf, CH, DD, DFF);
        add_ln_kernel<<<CH, 256, 0, stream>>>(hc, fbuf, nullptr, hc, g2, be2, 0);
      }
    } else {
      // only last OUTLEN positions per batch matter after layer-2 attention
      add_ln_kernel<<<NTAIL, 256, 0, stream>>>(h, ftail, bo, htail, g1, be1, 1);
      gemm_tile<true,  true><<<dim3(DFF/64, NTAIL/64), 256, 0, stream>>>(htail, w1, b1, hid, NTAIL, DFF, DD);
      gemm_tile<false, true><<<dim3(DD/64,  NTAIL/64), 256, 0, stream>>>(hid,   w2, b2, fbuf, NTAIL, DD, DFF);
      add_ln_kernel<<<NTAIL, 256, 0, stream>>>(htail, fbuf, nullptr, htail, g2, be2, 0);
      pred_kernel<<<NTAIL, 64, 0, stream>>>(htail, wout, bout, out);
    }
  }
  (void)in_sizes; (void)n_in; (void)out_size; (void)ws_size;
}

// Round 3
// 11896.938 us; speedup vs baseline: 1.4356x; 1.4356x over previous
//
#include <hip/hip_runtime.h>
#include <math.h>

#define BB 16
#define LL 4096
#define DIN 8
#define DD 512
#define HH 8
#define DKK 64
#define DFF 2048
#define OUTLEN 96
#define TAIL0 (LL - OUTLEN)   /* 4000 */
#define NTAIL (BB * OUTLEN)   /* 1536 */
#define UMAX 10
#define CH 4096               /* FFN row chunk */
#define QKVLD 1536            /* fused QKV row stride */

typedef unsigned short ushort_t;
typedef short bf16x8 __attribute__((ext_vector_type(8)));
typedef float f32x4 __attribute__((ext_vector_type(4)));

#define GLD16(gp, lp) __builtin_amdgcn_global_load_lds((const __attribute__((address_space(1))) void*)(gp), (__attribute__((address_space(3))) void*)(lp), 16, 0, 0)

// ---------- helpers ----------
__device__ inline float wsum(float v){
#pragma unroll
  for (int o = 32; o > 0; o >>= 1) v += __shfl_xor(v, o);
  return v;
}
__device__ inline float wmax(float v){
#pragma unroll
  for (int o = 32; o > 0; o >>= 1) v = fmaxf(v, __shfl_xor(v, o));
  return v;
}
__device__ inline ushort_t f2bf_rtn(float f){
  unsigned u = __float_as_uint(f);
  unsigned r = u + 0x7FFF + ((u >> 16) & 1);
  return (ushort_t)(r >> 16);
}
// split x = hi + lo (hi = truncate-to-bf16, lo = rtn(residual))
__device__ inline void split2(float x, ushort_t& hi, ushort_t& lo){
  unsigned u = __float_as_uint(x);
  hi = (ushort_t)(u >> 16);
  float hif = __uint_as_float((unsigned)hi << 16);
  lo = f2bf_rtn(x - hif);
}

// ---------- embed: h = x @ w_embed + b_embed ----------
__global__ __launch_bounds__(256) void embed_kernel(const float* __restrict__ x,
    const float* __restrict__ we, const float* __restrict__ be, float* __restrict__ h){
  int row = blockIdx.x;
  __shared__ float xs[DIN];
  if (threadIdx.x < DIN) xs[threadIdx.x] = x[(size_t)row * DIN + threadIdx.x];
  __syncthreads();
  for (int j = threadIdx.x; j < DD; j += 256){
    float acc = be[j];
#pragma unroll
    for (int i = 0; i < DIN; ++i) acc += xs[i] * we[i * DD + j];
    h[(size_t)row * DD + j] = acc;
  }
}

// ---------- split fp32 array -> bf16 hi/lo (vectorized x4) ----------
__global__ __launch_bounds__(256) void split_kernel(const float* __restrict__ x,
    ushort_t* __restrict__ hi, ushort_t* __restrict__ lo, int n4){
  int i = blockIdx.x * 256 + threadIdx.x;
  if (i >= n4) return;
  float4 v = ((const float4*)x)[i];
  ushort4 hv, lv;
  split2(v.x, hv.x, lv.x); split2(v.y, hv.y, lv.y);
  split2(v.z, hv.z, lv.z); split2(v.w, hv.w, lv.w);
  ((ushort4*)hi)[i] = hv;
  ((ushort4*)lo)[i] = lv;
}

// ---------- weight prep: transpose K x N -> N x K, split hi/lo ----------
__global__ __launch_bounds__(256) void wsplit_t_kernel(const float* __restrict__ W,
    ushort_t* __restrict__ Th, ushort_t* __restrict__ Tl, int K, int N){
  int idx = blockIdx.x * 256 + threadIdx.x;
  if (idx >= N * K) return;
  int n = idx / K, k = idx - n * K;
  ushort_t hi, lo;
  split2(W[(size_t)k * N + n], hi, lo);
  Th[idx] = hi; Tl[idx] = lo;
}

// ---------- fused QKV weight prep: [wq|wk|wv] -> (1536 x 512) hi/lo ----------
__global__ __launch_bounds__(256) void wqkv_prep_kernel(const float* __restrict__ wq,
    const float* __restrict__ wk, const float* __restrict__ wv,
    ushort_t* __restrict__ Th, ushort_t* __restrict__ Tl){
  int idx = blockIdx.x * 256 + threadIdx.x;
  if (idx >= QKVLD * DD) return;
  int n = idx >> 9, k = idx & (DD - 1);
  const float* src = (n < 512) ? wq : (n < 1024) ? wk : wv;
  ushort_t hi, lo;
  split2(src[(size_t)k * DD + (n & 511)], hi, lo);
  Th[idx] = hi; Tl[idx] = lo;
}
__global__ __launch_bounds__(256) void bqkv_prep_kernel(const float* __restrict__ bq,
    const float* __restrict__ bk, const float* __restrict__ bv, float* __restrict__ bo_){
  int n = blockIdx.x * 256 + threadIdx.x;
  if (n >= QKVLD) return;
  bo_[n] = (n < 512) ? bq[n] : (n < 1024) ? bk[n - 512] : bv[n - 1024];
}

// ---------- bf16x3 MFMA GEMM ----------
// A: M x K (bf16 hi/lo, row-major). B: N x K (bf16 hi/lo, row-major = W^T).
// C = A@W + bias, fp32 out (ldc) or split-bf16 out (Ch/Cl, ldc). M%128==0, N%128==0, K%32==0.
template<bool RELU, bool SPLIT_OUT>
__global__ __launch_bounds__(256) void gemm_x3(
    const ushort_t* __restrict__ Ah, const ushort_t* __restrict__ Al,
    const ushort_t* __restrict__ Bh, const ushort_t* __restrict__ Bl,
    const float* __restrict__ bias, float* __restrict__ C,
    ushort_t* __restrict__ Ch, ushort_t* __restrict__ Cl,
    int M, int N, int K, int ldc){
  __shared__ __align__(16) ushort_t AsH[128 * 32];
  __shared__ __align__(16) ushort_t AsL[128 * 32];
  __shared__ __align__(16) ushort_t BsH[128 * 32];
  __shared__ __align__(16) ushort_t BsL[128 * 32];
  const int tid  = threadIdx.x;
  const int lane = tid & 63;
  const int wv   = tid >> 6;            // 0..3
  const int m0   = blockIdx.y * 128;
  const int n0   = blockIdx.x * 128;
  const int wm   = (wv & 1) * 64;
  const int wn   = (wv >> 1) * 64;

  // staging geometry: chunk c in [0,512): row=c>>2, q=c&3 (16B each)
  const int rowA = tid >> 2;            // 0..63
  const int qe   = (tid & 3) * 8;       // element offset within row
  const int lds0 = tid * 8;             // ushort offset of chunk c0
  const int lds1 = (tid + 256) * 8;

  f32x4 acc[4][4];
#pragma unroll
  for (int i = 0; i < 4; ++i)
#pragma unroll
    for (int j = 0; j < 4; ++j) acc[i][j] = (f32x4){0.f, 0.f, 0.f, 0.f};

  const int arow = lane & 15;
  const int koff = (lane >> 4) * 8;

  for (int k0 = 0; k0 < K; k0 += 32){
    const size_t ga0 = (size_t)(m0 + rowA) * K + k0 + qe;
    const size_t ga1 = (size_t)(m0 + rowA + 64) * K + k0 + qe;
    const size_t gb0 = (size_t)(n0 + rowA) * K + k0 + qe;
    const size_t gb1 = (size_t)(n0 + rowA + 64) * K + k0 + qe;
    GLD16(Ah + ga0, &AsH[lds0]);  GLD16(Ah + ga1, &AsH[lds1]);
    GLD16(Al + ga0, &AsL[lds0]);  GLD16(Al + ga1, &AsL[lds1]);
    GLD16(Bh + gb0, &BsH[lds0]);  GLD16(Bh + gb1, &BsH[lds1]);
    GLD16(Bl + gb0, &BsL[lds0]);  GLD16(Bl + gb1, &BsL[lds1]);
    __syncthreads();

    bf16x8 ah[4], al[4], bh[4], bl[4];
#pragma unroll
    for (int i = 0; i < 4; ++i){
      ah[i] = *(const bf16x8*)&AsH[(wm + i * 16 + arow) * 32 + koff];
      al[i] = *(const bf16x8*)&AsL[(wm + i * 16 + arow) * 32 + koff];
      bh[i] = *(const bf16x8*)&BsH[(wn + i * 16 + arow) * 32 + koff];
      bl[i] = *(const bf16x8*)&BsL[(wn + i * 16 + arow) * 32 + koff];
    }
#pragma unroll
    for (int i = 0; i < 4; ++i)
#pragma unroll
      for (int j = 0; j < 4; ++j){
        acc[i][j] = __builtin_amdgcn_mfma_f32_16x16x32_bf16(ah[i], bh[j], acc[i][j], 0, 0, 0);
        acc[i][j] = __builtin_amdgcn_mfma_f32_16x16x32_bf16(al[i], bh[j], acc[i][j], 0, 0, 0);
        acc[i][j] = __builtin_amdgcn_mfma_f32_16x16x32_bf16(ah[i], bl[j], acc[i][j], 0, 0, 0);
      }
    __syncthreads();
  }

  // epilogue: D row = (lane>>4)*4 + r, col = lane&15  [m89/m91 verified]
  const int crow = (lane >> 4) * 4;
  const int ccol = lane & 15;
#pragma unroll
  for (int i = 0; i < 4; ++i){
    const int gr0 = m0 + wm + i * 16 + crow;
#pragma unroll
    for (int j = 0; j < 4; ++j){
      const int gc = n0 + wn + j * 16 + ccol;
      const float bvv = bias[gc];
#pragma unroll
      for (int r = 0; r < 4; ++r){
        float v = acc[i][j][r] + bvv;
        if (RELU) v = fmaxf(v, 0.f);
        const size_t off = (size_t)(gr0 + r) * ldc + gc;
        if (SPLIT_OUT){
          ushort_t hu, lu; split2(v, hu, lu);
          Ch[off] = hu; Cl[off] = lu;
        } else {
          C[off] = v;
        }
      }
    }
  }
}

// ---------- qs scoring for one batch (Q part of fused qkv buffer) ----------
__global__ __launch_bounds__(256) void qs_kernel(const float* __restrict__ qkvb, float* __restrict__ qsb){
  int tid = threadIdx.x;
  int lane = tid & 63;
  int wv = tid >> 6;
  int rid = blockIdx.x * 4 + wv;        // h*LL + l
  int hh = rid >> 12;
  int l  = rid & (LL - 1);
  float qv = qkvb[(size_t)l * QKVLD + hh * DKK + lane];
  float l2 = sqrtf(wsum(qv * qv));
  float mx = wmax(qv);
  float e  = expf(qv - mx);
  float se = wsum(e);
  float p  = e / se;
  float ent = -wsum(p * logf(p + 1e-9f));
  float mu  = wsum(qv) * (1.0f / 64.0f);
  float dv  = qv - mu;
  float var = wsum(dv * dv) * (1.0f / 63.0f);
  float val = 0.5f * l2 + 0.3f * ent + 0.2f * var;
  if (lane == 0) qsb[rid] = val;
}

// ---------- fused selection: blocks 0-7 = top-10 per head, block 8 = u factor ----------
__global__ __launch_bounds__(256) void select_kernel(const float* __restrict__ qsb,
    int* __restrict__ topidx, int* __restrict__ ufac, int b){
  __shared__ float vals[LL];
  __shared__ float bv[256];
  __shared__ int   bi[256];
  __shared__ double r1[256], r2[256];
  int tid = threadIdx.x;
  if (blockIdx.x == 8){
    const float* row = qsb;             // head 0
    double s = 0.0, s2 = 0.0;
    for (int l = tid; l < LL; l += 256){ double v = row[l]; s += v; s2 += v * v; }
    r1[tid] = s; r2[tid] = s2; __syncthreads();
    for (int st = 128; st; st >>= 1){
      if (tid < st){ r1[tid] += r1[tid+st]; r2[tid] += r2[tid+st]; }
      __syncthreads();
    }
    if (tid == 0){
      double mean = r1[0] / (double)LL;
      double var  = (r2[0] - (double)LL * mean * mean) / (double)(LL - 1);
      if (var < 0.0) var = 0.0;
      double f = rint(sqrt(var) / (mean + 1e-6) * 10.0);
      if (f < 3.0) f = 3.0;
      if (f > 10.0) f = 10.0;
      ufac[b] = (int)f;
    }
    return;
  }
  int hh = blockIdx.x;
  const float* row = qsb + (size_t)hh * LL;
  for (int l = tid; l < LL; l += 256) vals[l] = row[l];
  __syncthreads();
  for (int it = 0; it < UMAX; ++it){
    float best = -INFINITY; int bidx = 0;
    for (int l = tid; l < LL; l += 256){
      float v = vals[l];
      if (v > best){ best = v; bidx = l; }
    }
    bv[tid] = best; bi[tid] = bidx; __syncthreads();
    for (int st = 128; st; st >>= 1){
      if (tid < st){
        if (bv[tid+st] > bv[tid] || (bv[tid+st] == bv[tid] && bi[tid+st] < bi[tid])){
          bv[tid] = bv[tid+st]; bi[tid] = bi[tid+st];
        }
      }
      __syncthreads();
    }
    if (tid == 0){ topidx[(b * HH + hh) * UMAX + it] = bi[0]; vals[bi[0]] = -INFINITY; }
    __syncthreads();
  }
}

// ---------- fused attention + wo-projection scatter ----------
__global__ __launch_bounds__(256) void attn_scatter_kernel(const float* __restrict__ qkvb,
    const float* __restrict__ wo, const int* __restrict__ topidx, const int* __restrict__ ufac,
    float* __restrict__ target, int b, int tailmode){
  int hh = blockIdx.x / UMAX, rank = blockIdx.x % UMAX;
  if (rank >= ufac[b]) return;
  int qpos = topidx[(b * HH + hh) * UMAX + rank];
  size_t drow;
  if (tailmode){
    if (qpos < TAIL0) return;
    drow = (size_t)(b * OUTLEN + (qpos - TAIL0));
  } else {
    drow = (size_t)b * LL + qpos;
  }
  __shared__ float sc[LL];
  __shared__ float qrow[DKK];
  __shared__ float red[256];
  __shared__ float orow[DKK];
  int tid = threadIdx.x;
  const float* Kb = qkvb + 512;
  const float* Vb = qkvb + 1024;
  if (tid < DKK) qrow[tid] = qkvb[(size_t)qpos * QKVLD + hh * DKK + tid];
  __syncthreads();

  float m = -INFINITY;
  for (int l = tid; l < LL; l += 256){
    const float* kr = Kb + (size_t)l * QKVLD + hh * DKK;
    float s = 0.f;
#pragma unroll
    for (int d = 0; d < DKK; d += 4){
      float4 k4 = *(const float4*)&kr[d];
      s += qrow[d] * k4.x + qrow[d+1] * k4.y + qrow[d+2] * k4.z + qrow[d+3] * k4.w;
    }
    s *= 0.125f;
    sc[l] = s;
    m = fmaxf(m, s);
  }
  red[tid] = m; __syncthreads();
  for (int st = 128; st; st >>= 1){ if (tid < st) red[tid] = fmaxf(red[tid], red[tid+st]); __syncthreads(); }
  float M = red[0]; __syncthreads();

  float ssum = 0.f;
  for (int l = tid; l < LL; l += 256){ float e = expf(sc[l] - M); sc[l] = e; ssum += e; }
  red[tid] = ssum; __syncthreads();
  for (int st = 128; st; st >>= 1){ if (tid < st) red[tid] += red[tid+st]; __syncthreads(); }
  float S = red[0]; __syncthreads();

  int d = tid & 63, g = tid >> 6;
  float acc = 0.f;
  for (int l = g; l < LL; l += 4)
    acc += sc[l] * Vb[(size_t)l * QKVLD + hh * DKK + d];
  red[tid] = acc; __syncthreads();
  if (tid < 64) orow[d] = (red[d] + red[64+d] + red[128+d] + red[192+d]) / S;
  __syncthreads();

  for (int j = tid; j < DD; j += 256){
    float a = 0.f;
#pragma unroll
    for (int dd = 0; dd < DKK; ++dd) a += orow[dd] * wo[(size_t)(hh * DKK + dd) * DD + j];
    atomicAdd(&target[drow * DD + j], a);
  }
}

// ---------- zero fill ----------
__global__ void zero_kernel(float* __restrict__ p, size_t n){
  size_t i = (size_t)blockIdx.x * 256 + threadIdx.x;
  size_t stride = (size_t)gridDim.x * 256;
  for (; i < n; i += stride) p[i] = 0.f;
}

// ---------- O_row = LN(X_row [+Y_row] [+bias]) * g + bb ----------
__global__ __launch_bounds__(256) void add_ln_kernel(const float* __restrict__ X,
    const float* __restrict__ Y, const float* __restrict__ bias, float* __restrict__ O,
    const float* __restrict__ g, const float* __restrict__ bb, int tailmapX){
  __shared__ float red[256];
  int r = blockIdx.x, tid = threadIdx.x;
  const float* xr;
  if (tailmapX){
    int b = r / OUTLEN;
    int l = TAIL0 + (r % OUTLEN);
    xr = X + ((size_t)b * LL + l) * DD;
  } else {
    xr = X + (size_t)r * DD;
  }
  float v0 = xr[tid];
  float v1 = xr[tid + 256];
  if (Y){
    const float* yr = Y + (size_t)r * DD;
    v0 += yr[tid]; v1 += yr[tid + 256];
  }
  if (bias){ v0 += bias[tid]; v1 += bias[tid + 256]; }
  red[tid] = v0 + v1; __syncthreads();
  for (int st = 128; st; st >>= 1){ if (tid < st) red[tid] += red[tid+st]; __syncthreads(); }
  float mu = red[0] * (1.0f / DD); __syncthreads();
  float d0 = v0 - mu, d1 = v1 - mu;
  red[tid] = d0*d0 + d1*d1; __syncthreads();
  for (int st = 128; st; st >>= 1){ if (tid < st) red[tid] += red[tid+st]; __syncthreads(); }
  float rstd = rsqrtf(red[0] * (1.0f / DD) + 1e-5f);
  float* orow = O + (size_t)r * DD;
  orow[tid]       = d0 * rstd * g[tid]       + bb[tid];
  orow[tid + 256] = d1 * rstd * g[tid + 256] + bb[tid + 256];
}

// ---------- final: pred = htail @ w_out + b_out ----------
__global__ __launch_bounds__(64) void pred_kernel(const float* __restrict__ ht,
    const float* __restrict__ wout, const float* __restrict__ bout, float* __restrict__ out){
  int r = blockIdx.x, lane = threadIdx.x;
  float acc = 0.f;
  for (int dd = lane; dd < DD; dd += 64) acc += ht[(size_t)r * DD + dd] * wout[dd];
  acc = wsum(acc);
  if (lane == 0) out[r] = acc + bout[0];
}

extern "C" void kernel_launch(void* const* d_in, const int* in_sizes, int n_in,
                              void* d_out, int out_size, void* d_ws, size_t ws_size,
                              hipStream_t stream){
  const float* x    = (const float*)d_in[0];
  const float* wemb = (const float*)d_in[1];
  const float* bemb = (const float*)d_in[2];
  const float* wq   = (const float*)d_in[3];
  const float* bq   = (const float*)d_in[4];
  const float* wk   = (const float*)d_in[5];
  const float* bk   = (const float*)d_in[6];
  const float* wv   = (const float*)d_in[7];
  const float* bvv  = (const float*)d_in[8];
  const float* wo   = (const float*)d_in[9];
  const float* bo   = (const float*)d_in[10];
  const float* w1   = (const float*)d_in[11];
  const float* b1   = (const float*)d_in[12];
  const float* w2   = (const float*)d_in[13];
  const float* b2   = (const float*)d_in[14];
  const float* g1   = (const float*)d_in[15];
  const float* be1  = (const float*)d_in[16];
  const float* g2   = (const float*)d_in[17];
  const float* be2  = (const float*)d_in[18];
  const float* wout = (const float*)d_in[19];
  const float* bout = (const float*)d_in[20];
  float* out = (float*)d_out;
  char* wsb  = (char*)d_ws;

  const size_t PB = (size_t)LL * DD;            // 2,097,152 elems per batch

  size_t o = 0;
  float*    h      = (float*)(wsb + o);  o += (size_t)BB * PB * 4;          // 128 MiB
  float*    qkvb   = (float*)(wsb + o);  o += (size_t)LL * QKVLD * 4;       // 24 MiB
  ushort_t* ah     = (ushort_t*)(wsb + o); o += PB * 2;                     // 4 MiB
  ushort_t* al     = (ushort_t*)(wsb + o); o += PB * 2;                     // 4 MiB
  ushort_t* hidh   = (ushort_t*)(wsb + o); o += (size_t)CH * DFF * 2;       // 16 MiB
  ushort_t* hidl   = (ushort_t*)(wsb + o); o += (size_t)CH * DFF * 2;       // 16 MiB
  float*    fbuf   = (float*)(wsb + o);  o += (size_t)CH * DD * 4;          // 8 MiB
  ushort_t* wtqkvh = (ushort_t*)(wsb + o); o += (size_t)QKVLD * DD * 2;
  ushort_t* wtqkvl = (ushort_t*)(wsb + o); o += (size_t)QKVLD * DD * 2;
  ushort_t* w1th   = (ushort_t*)(wsb + o); o += (size_t)DFF * DD * 2;
  ushort_t* w1tl   = (ushort_t*)(wsb + o); o += (size_t)DFF * DD * 2;
  ushort_t* w2th   = (ushort_t*)(wsb + o); o += (size_t)DD * DFF * 2;
  ushort_t* w2tl   = (ushort_t*)(wsb + o); o += (size_t)DD * DFF * 2;
  float*    bqkv   = (float*)(wsb + o);  o += QKVLD * 4;
  float*    qsb    = (float*)(wsb + o);  o += (size_t)HH * LL * 4;
  float*    htail  = (float*)(wsb + o);  o += (size_t)NTAIL * DD * 4;       // 3 MiB
  float*    ftail  = (float*)(wsb + o);  o += (size_t)NTAIL * DD * 4;       // 3 MiB
  int*      topidx = (int*)(wsb + o);    o += (size_t)BB * HH * UMAX * 4;
  int*      ufac   = (int*)(wsb + o);    o += 64;
  // total ~220 MiB (proven-safe budget)

  // weight prep (every launch; deterministic, ~3M elems)
  wqkv_prep_kernel<<<(QKVLD*DD + 255)/256, 256, 0, stream>>>(wq, wk, wv, wtqkvh, wtqkvl);
  bqkv_prep_kernel<<<(QKVLD + 255)/256, 256, 0, stream>>>(bq, bk, bvv, bqkv);
  wsplit_t_kernel<<<(DFF*DD + 255)/256, 256, 0, stream>>>(w1, w1th, w1tl, DD, DFF);
  wsplit_t_kernel<<<(DD*DFF + 255)/256, 256, 0, stream>>>(w2, w2th, w2tl, DFF, DD);

  // embed
  embed_kernel<<<BB * LL, 256, 0, stream>>>(x, wemb, bemb, h);

  for (int layer = 0; layer < 2; ++layer){
    const bool tail = (layer == 1);
    if (tail) zero_kernel<<<1024, 256, 0, stream>>>(ftail, (size_t)NTAIL * DD);

    for (int b = 0; b < BB; ++b){
      const float* hb = h + (size_t)b * PB;
      split_kernel<<<(int)(PB/4 + 255)/256, 256, 0, stream>>>(hb, ah, al, (int)(PB/4));
      gemm_x3<false, false><<<dim3(QKVLD/128, LL/128), 256, 0, stream>>>(
          ah, al, wtqkvh, wtqkvl, bqkv, qkvb, nullptr, nullptr, LL, QKVLD, DD, QKVLD);
      qs_kernel<<<(HH*LL)/4, 256, 0, stream>>>(qkvb, qsb);
      select_kernel<<<9, 256, 0, stream>>>(qsb, topidx, ufac, b);
      attn_scatter_kernel<<<HH*UMAX, 256, 0, stream>>>(qkvb, wo, topidx, ufac,
          tail ? ftail : h, b, tail ? 1 : 0);
    }

    if (!tail){
      add_ln_kernel<<<BB*LL, 256, 0, stream>>>(h, nullptr, bo, h, g1, be1, 0);
      for (int c = 0; c < (BB*LL)/CH; ++c){
        float* hc = h + (size_t)c * CH * DD;
        split_kernel<<<(int)((size_t)CH*DD/4 + 255)/256, 256, 0, stream>>>(hc, ah, al, (int)((size_t)CH*DD/4));
        gemm_x3<true, true><<<dim3(DFF/128, CH/128), 256, 0, stream>>>(
            ah, al, w1th, w1tl, b1, nullptr, hidh, hidl, CH, DFF, DD, DFF);
        gemm_x3<false, false><<<dim3(DD/128, CH/128), 256, 0, stream>>>(
            hidh, hidl, w2th, w2tl, b2, fbuf, nullptr, nullptr, CH, DD, DFF, DD);
        add_ln_kernel<<<CH, 256, 0, stream>>>(hc, fbuf, nullptr, hc, g2, be2, 0);
      }
    } else {
      add_ln_kernel<<<NTAIL, 256, 0, stream>>>(h, ftail, bo, htail, g1, be1, 1);
      split_kernel<<<(int)((size_t)NTAIL*DD/4 + 255)/256, 256, 0, stream>>>(htail, ah, al, (int)((size_t)NTAIL*DD/4));
      gemm_x3<true, true><<<dim3(DFF/128, NTAIL/128), 256, 0, stream>>>(
          ah, al, w1th, w1tl, b1, nullptr, hidh, hidl, NTAIL, DFF, DD, DFF);
      gemm_x3<false, false><<<dim3(DD/128, NTAIL/128), 256, 0, stream>>>(
          hidh, hidl, w2th, w2tl, b2, fbuf, nullptr, nullptr, NTAIL, DD, DFF, DD);
      add_ln_kernel<<<NTAIL, 256, 0, stream>>>(htail, fbuf, nullptr, htail, g2, be2, 0);
      pred_kernel<<<NTAIL, 64, 0, stream>>>(htail, wout, bout, out);
    }
  }
  (void)in_sizes; (void)n_in; (void)out_size; (void)ws_size;
}

// Round 4
// 5553.498 us; speedup vs baseline: 3.0754x; 2.1422x over previous
//
#include <hip/hip_runtime.h>
#include <math.h>

#define BB 16
#define LL 4096
#define DIN 8
#define DD 512
#define HH 8
#define DKK 64
#define DFF 2048
#define OUTLEN 96
#define TAIL0 (LL - OUTLEN)   /* 4000 */
#define NTAIL (BB * OUTLEN)   /* 1536 */
#define UMAX 10
#define CH 4096               /* FFN row chunk */
#define QKVLD 1536            /* fused QKV row stride */
#define NSPLIT 32
#define LCHUNK (LL / NSPLIT)  /* 128 */
#define PSTRIDE 68            /* partial record: 64 pv + m + s (+pad) */

typedef unsigned short ushort_t;
typedef short bf16x8 __attribute__((ext_vector_type(8)));
typedef float f32x4 __attribute__((ext_vector_type(4)));

#define GLD16(gp, lp) __builtin_amdgcn_global_load_lds((const __attribute__((address_space(1))) void*)(gp), (__attribute__((address_space(3))) void*)(lp), 16, 0, 0)

// ---------- helpers ----------
__device__ inline float wsum(float v){
#pragma unroll
  for (int o = 32; o > 0; o >>= 1) v += __shfl_xor(v, o);
  return v;
}
__device__ inline float wmax(float v){
#pragma unroll
  for (int o = 32; o > 0; o >>= 1) v = fmaxf(v, __shfl_xor(v, o));
  return v;
}
__device__ inline ushort_t f2bf_rtn(float f){
  unsigned u = __float_as_uint(f);
  unsigned r = u + 0x7FFF + ((u >> 16) & 1);
  return (ushort_t)(r >> 16);
}
__device__ inline void split2(float x, ushort_t& hi, ushort_t& lo){
  unsigned u = __float_as_uint(x);
  hi = (ushort_t)(u >> 16);
  float hif = __uint_as_float((unsigned)hi << 16);
  lo = f2bf_rtn(x - hif);
}

// ---------- embed ----------
__global__ __launch_bounds__(256) void embed_kernel(const float* __restrict__ x,
    const float* __restrict__ we, const float* __restrict__ be, float* __restrict__ h){
  int row = blockIdx.x;
  __shared__ float xs[DIN];
  if (threadIdx.x < DIN) xs[threadIdx.x] = x[(size_t)row * DIN + threadIdx.x];
  __syncthreads();
  for (int j = threadIdx.x; j < DD; j += 256){
    float acc = be[j];
#pragma unroll
    for (int i = 0; i < DIN; ++i) acc += xs[i] * we[i * DD + j];
    h[(size_t)row * DD + j] = acc;
  }
}

// ---------- split fp32 -> bf16 hi/lo ----------
__global__ __launch_bounds__(256) void split_kernel(const float* __restrict__ x,
    ushort_t* __restrict__ hi, ushort_t* __restrict__ lo, int n4){
  int i = blockIdx.x * 256 + threadIdx.x;
  if (i >= n4) return;
  float4 v = ((const float4*)x)[i];
  ushort4 hv, lv;
  split2(v.x, hv.x, lv.x); split2(v.y, hv.y, lv.y);
  split2(v.z, hv.z, lv.z); split2(v.w, hv.w, lv.w);
  ((ushort4*)hi)[i] = hv;
  ((ushort4*)lo)[i] = lv;
}

// ---------- weight prep ----------
__global__ __launch_bounds__(256) void wsplit_t_kernel(const float* __restrict__ W,
    ushort_t* __restrict__ Th, ushort_t* __restrict__ Tl, int K, int N){
  int idx = blockIdx.x * 256 + threadIdx.x;
  if (idx >= N * K) return;
  int n = idx / K, k = idx - n * K;
  ushort_t hi, lo;
  split2(W[(size_t)k * N + n], hi, lo);
  Th[idx] = hi; Tl[idx] = lo;
}
__global__ __launch_bounds__(256) void wqkv_prep_kernel(const float* __restrict__ wq,
    const float* __restrict__ wk, const float* __restrict__ wv,
    ushort_t* __restrict__ Th, ushort_t* __restrict__ Tl){
  int idx = blockIdx.x * 256 + threadIdx.x;
  if (idx >= QKVLD * DD) return;
  int n = idx >> 9, k = idx & (DD - 1);
  const float* src = (n < 512) ? wq : (n < 1024) ? wk : wv;
  ushort_t hi, lo;
  split2(src[(size_t)k * DD + (n & 511)], hi, lo);
  Th[idx] = hi; Tl[idx] = lo;
}
__global__ __launch_bounds__(256) void bqkv_prep_kernel(const float* __restrict__ bq,
    const float* __restrict__ bk, const float* __restrict__ bv, float* __restrict__ bo_){
  int n = blockIdx.x * 256 + threadIdx.x;
  if (n >= QKVLD) return;
  bo_[n] = (n < 512) ? bq[n] : (n < 1024) ? bk[n - 512] : bv[n - 1024];
}

// ---------- bf16x3 MFMA GEMM ----------
template<bool RELU, bool SPLIT_OUT>
__global__ __launch_bounds__(256) void gemm_x3(
    const ushort_t* __restrict__ Ah, const ushort_t* __restrict__ Al,
    const ushort_t* __restrict__ Bh, const ushort_t* __restrict__ Bl,
    const float* __restrict__ bias, float* __restrict__ C,
    ushort_t* __restrict__ Ch, ushort_t* __restrict__ Cl,
    int M, int N, int K, int ldc){
  __shared__ __align__(16) ushort_t AsH[128 * 32];
  __shared__ __align__(16) ushort_t AsL[128 * 32];
  __shared__ __align__(16) ushort_t BsH[128 * 32];
  __shared__ __align__(16) ushort_t BsL[128 * 32];
  const int tid  = threadIdx.x;
  const int lane = tid & 63;
  const int wv   = tid >> 6;
  const int m0   = blockIdx.y * 128;
  const int n0   = blockIdx.x * 128;
  const int wm   = (wv & 1) * 64;
  const int wn   = (wv >> 1) * 64;

  const int rowA = tid >> 2;
  const int qe   = (tid & 3) * 8;
  const int lds0 = tid * 8;
  const int lds1 = (tid + 256) * 8;

  f32x4 acc[4][4];
#pragma unroll
  for (int i = 0; i < 4; ++i)
#pragma unroll
    for (int j = 0; j < 4; ++j) acc[i][j] = (f32x4){0.f, 0.f, 0.f, 0.f};

  const int arow = lane & 15;
  const int koff = (lane >> 4) * 8;

  for (int k0 = 0; k0 < K; k0 += 32){
    const size_t ga0 = (size_t)(m0 + rowA) * K + k0 + qe;
    const size_t ga1 = (size_t)(m0 + rowA + 64) * K + k0 + qe;
    const size_t gb0 = (size_t)(n0 + rowA) * K + k0 + qe;
    const size_t gb1 = (size_t)(n0 + rowA + 64) * K + k0 + qe;
    GLD16(Ah + ga0, &AsH[lds0]);  GLD16(Ah + ga1, &AsH[lds1]);
    GLD16(Al + ga0, &AsL[lds0]);  GLD16(Al + ga1, &AsL[lds1]);
    GLD16(Bh + gb0, &BsH[lds0]);  GLD16(Bh + gb1, &BsH[lds1]);
    GLD16(Bl + gb0, &BsL[lds0]);  GLD16(Bl + gb1, &BsL[lds1]);
    __syncthreads();

    bf16x8 ah[4], al[4], bh[4], bl[4];
#pragma unroll
    for (int i = 0; i < 4; ++i){
      ah[i] = *(const bf16x8*)&AsH[(wm + i * 16 + arow) * 32 + koff];
      al[i] = *(const bf16x8*)&AsL[(wm + i * 16 + arow) * 32 + koff];
      bh[i] = *(const bf16x8*)&BsH[(wn + i * 16 + arow) * 32 + koff];
      bl[i] = *(const bf16x8*)&BsL[(wn + i * 16 + arow) * 32 + koff];
    }
#pragma unroll
    for (int i = 0; i < 4; ++i)
#pragma unroll
      for (int j = 0; j < 4; ++j){
        acc[i][j] = __builtin_amdgcn_mfma_f32_16x16x32_bf16(ah[i], bh[j], acc[i][j], 0, 0, 0);
        acc[i][j] = __builtin_amdgcn_mfma_f32_16x16x32_bf16(al[i], bh[j], acc[i][j], 0, 0, 0);
        acc[i][j] = __builtin_amdgcn_mfma_f32_16x16x32_bf16(ah[i], bl[j], acc[i][j], 0, 0, 0);
      }
    __syncthreads();
  }

  const int crow = (lane >> 4) * 4;
  const int ccol = lane & 15;
#pragma unroll
  for (int i = 0; i < 4; ++i){
    const int gr0 = m0 + wm + i * 16 + crow;
#pragma unroll
    for (int j = 0; j < 4; ++j){
      const int gc = n0 + wn + j * 16 + ccol;
      const float bvv = bias[gc];
#pragma unroll
      for (int r = 0; r < 4; ++r){
        float v = acc[i][j][r] + bvv;
        if (RELU) v = fmaxf(v, 0.f);
        const size_t off = (size_t)(gr0 + r) * ldc + gc;
        if (SPLIT_OUT){
          ushort_t hu, lu; split2(v, hu, lu);
          Ch[off] = hu; Cl[off] = lu;
        } else {
          C[off] = v;
        }
      }
    }
  }
}

// ---------- qs scoring ----------
__global__ __launch_bounds__(256) void qs_kernel(const float* __restrict__ qkvb, float* __restrict__ qsb){
  int tid = threadIdx.x;
  int lane = tid & 63;
  int wv = tid >> 6;
  int rid = blockIdx.x * 4 + wv;
  int hh = rid >> 12;
  int l  = rid & (LL - 1);
  float qv = qkvb[(size_t)l * QKVLD + hh * DKK + lane];
  float l2 = sqrtf(wsum(qv * qv));
  float mx = wmax(qv);
  float e  = expf(qv - mx);
  float se = wsum(e);
  float p  = e / se;
  float ent = -wsum(p * logf(p + 1e-9f));
  float mu  = wsum(qv) * (1.0f / 64.0f);
  float dv  = qv - mu;
  float var = wsum(dv * dv) * (1.0f / 63.0f);
  float val = 0.5f * l2 + 0.3f * ent + 0.2f * var;
  if (lane == 0) qsb[rid] = val;
}

// ---------- fused selection ----------
__global__ __launch_bounds__(256) void select_kernel(const float* __restrict__ qsb,
    int* __restrict__ topidx, int* __restrict__ ufac, int b){
  __shared__ float vals[LL];
  __shared__ float bv[256];
  __shared__ int   bi[256];
  __shared__ double r1[256], r2[256];
  int tid = threadIdx.x;
  if (blockIdx.x == 8){
    const float* row = qsb;
    double s = 0.0, s2 = 0.0;
    for (int l = tid; l < LL; l += 256){ double v = row[l]; s += v; s2 += v * v; }
    r1[tid] = s; r2[tid] = s2; __syncthreads();
    for (int st = 128; st; st >>= 1){
      if (tid < st){ r1[tid] += r1[tid+st]; r2[tid] += r2[tid+st]; }
      __syncthreads();
    }
    if (tid == 0){
      double mean = r1[0] / (double)LL;
      double var  = (r2[0] - (double)LL * mean * mean) / (double)(LL - 1);
      if (var < 0.0) var = 0.0;
      double f = rint(sqrt(var) / (mean + 1e-6) * 10.0);
      if (f < 3.0) f = 3.0;
      if (f > 10.0) f = 10.0;
      ufac[b] = (int)f;
    }
    return;
  }
  int hh = blockIdx.x;
  const float* row = qsb + (size_t)hh * LL;
  for (int l = tid; l < LL; l += 256) vals[l] = row[l];
  __syncthreads();
  for (int it = 0; it < UMAX; ++it){
    float best = -INFINITY; int bidx = 0;
    for (int l = tid; l < LL; l += 256){
      float v = vals[l];
      if (v > best){ best = v; bidx = l; }
    }
    bv[tid] = best; bi[tid] = bidx; __syncthreads();
    for (int st = 128; st; st >>= 1){
      if (tid < st){
        if (bv[tid+st] > bv[tid] || (bv[tid+st] == bv[tid] && bi[tid+st] < bi[tid])){
          bv[tid] = bv[tid+st]; bi[tid] = bi[tid+st];
        }
      }
      __syncthreads();
    }
    if (tid == 0){ topidx[(b * HH + hh) * UMAX + it] = bi[0]; vals[bi[0]] = -INFINITY; }
    __syncthreads();
  }
}

// ---------- attention pass 1: partial flash over L-chunks ----------
// grid: dim3(NSPLIT, HH*UMAX). partials: [rowid*NSPLIT+sp]*PSTRIDE : pv[64], m, s
__global__ __launch_bounds__(256) void attn_p1_kernel(const float* __restrict__ qkvb,
    const int* __restrict__ topidx, const int* __restrict__ ufac,
    float* __restrict__ part, int b, int lmin){
  const int rowid = blockIdx.y;
  const int hh = rowid / UMAX, rank = rowid % UMAX;
  if (rank >= ufac[b]) return;
  const int qpos = topidx[(b * HH + hh) * UMAX + rank];
  if (qpos < lmin) return;

  const int tid = threadIdx.x, lane = tid & 63, wv = tid >> 6;
  const int base = blockIdx.x * LCHUNK + wv * (LCHUNK / 4);   // 32 rows per wave

  __shared__ float qrow[DKK];
  __shared__ float wm4[4], ws4[4];
  __shared__ float pvs[4][DKK];
  if (tid < DKK) qrow[tid] = qkvb[(size_t)qpos * QKVLD + hh * DKK + tid];
  __syncthreads();

  const float* Kb = qkvb + 512 + hh * DKK;
  const float* Vb = qkvb + 1024 + hh * DKK;
  const float qv = qrow[lane];

  float sc[32];
  float mloc = -INFINITY;
#pragma unroll
  for (int i = 0; i < 32; ++i){
    float s = wsum(qv * Kb[(size_t)(base + i) * QKVLD + lane]) * 0.125f;
    sc[i] = s;
    mloc = fmaxf(mloc, s);
  }
  if (lane == 0) wm4[wv] = mloc;
  __syncthreads();
  const float M4 = fmaxf(fmaxf(wm4[0], wm4[1]), fmaxf(wm4[2], wm4[3]));

  float ssum = 0.f;
#pragma unroll
  for (int i = 0; i < 32; ++i){ float e = expf(sc[i] - M4); sc[i] = e; ssum += e; }

  float pv = 0.f;
#pragma unroll
  for (int i = 0; i < 32; ++i) pv += sc[i] * Vb[(size_t)(base + i) * QKVLD + lane];

  pvs[wv][lane] = pv;
  if (lane == 0) ws4[wv] = ssum;
  __syncthreads();
  if (wv == 0){
    float* rec = part + (size_t)(rowid * NSPLIT + blockIdx.x) * PSTRIDE;
    rec[lane] = pvs[0][lane] + pvs[1][lane] + pvs[2][lane] + pvs[3][lane];
    if (lane == 0){ rec[64] = M4; rec[65] = ws4[0] + ws4[1] + ws4[2] + ws4[3]; }
  }
}

// ---------- attention pass 2: combine + wo-projection scatter ----------
__global__ __launch_bounds__(256) void attn_p2_kernel(const float* __restrict__ part,
    const float* __restrict__ wo, const int* __restrict__ topidx, const int* __restrict__ ufac,
    float* __restrict__ target, int b, int tailmode){
  const int rowid = blockIdx.x;
  const int hh = rowid / UMAX, rank = rowid % UMAX;
  if (rank >= ufac[b]) return;
  const int qpos = topidx[(b * HH + hh) * UMAX + rank];
  size_t drow;
  if (tailmode){
    if (qpos < TAIL0) return;
    drow = (size_t)(b * OUTLEN + (qpos - TAIL0));
  } else {
    drow = (size_t)b * LL + qpos;
  }
  const int tid = threadIdx.x;
  __shared__ float pm[NSPLIT], ps[NSPLIT];
  __shared__ float orow[DKK];
  if (tid < NSPLIT){
    const float* rec = part + (size_t)(rowid * NSPLIT + tid) * PSTRIDE;
    pm[tid] = rec[64];
    ps[tid] = rec[65];
  }
  __syncthreads();
  float M = -INFINITY;
#pragma unroll
  for (int i = 0; i < NSPLIT; ++i) M = fmaxf(M, pm[i]);
  float S = 0.f;
#pragma unroll
  for (int i = 0; i < NSPLIT; ++i) S += ps[i] * expf(pm[i] - M);
  if (tid < DKK){
    float acc = 0.f;
#pragma unroll
    for (int i = 0; i < NSPLIT; ++i)
      acc += part[(size_t)(rowid * NSPLIT + i) * PSTRIDE + tid] * expf(pm[i] - M);
    orow[tid] = acc / S;
  }
  __syncthreads();
  for (int j = tid; j < DD; j += 256){
    float a = 0.f;
#pragma unroll
    for (int dd = 0; dd < DKK; ++dd) a += orow[dd] * wo[(size_t)(hh * DKK + dd) * DD + j];
    atomicAdd(&target[drow * DD + j], a);
  }
}

// ---------- zero fill ----------
__global__ void zero_kernel(float* __restrict__ p, size_t n){
  size_t i = (size_t)blockIdx.x * 256 + threadIdx.x;
  size_t stride = (size_t)gridDim.x * 256;
  for (; i < n; i += stride) p[i] = 0.f;
}

// ---------- add + LN ----------
__global__ __launch_bounds__(256) void add_ln_kernel(const float* __restrict__ X,
    const float* __restrict__ Y, const float* __restrict__ bias, float* __restrict__ O,
    const float* __restrict__ g, const float* __restrict__ bb, int tailmapX){
  __shared__ float red[256];
  int r = blockIdx.x, tid = threadIdx.x;
  const float* xr;
  if (tailmapX){
    int b = r / OUTLEN;
    int l = TAIL0 + (r % OUTLEN);
    xr = X + ((size_t)b * LL + l) * DD;
  } else {
    xr = X + (size_t)r * DD;
  }
  float v0 = xr[tid];
  float v1 = xr[tid + 256];
  if (Y){
    const float* yr = Y + (size_t)r * DD;
    v0 += yr[tid]; v1 += yr[tid + 256];
  }
  if (bias){ v0 += bias[tid]; v1 += bias[tid + 256]; }
  red[tid] = v0 + v1; __syncthreads();
  for (int st = 128; st; st >>= 1){ if (tid < st) red[tid] += red[tid+st]; __syncthreads(); }
  float mu = red[0] * (1.0f / DD); __syncthreads();
  float d0 = v0 - mu, d1 = v1 - mu;
  red[tid] = d0*d0 + d1*d1; __syncthreads();
  for (int st = 128; st; st >>= 1){ if (tid < st) red[tid] += red[tid+st]; __syncthreads(); }
  float rstd = rsqrtf(red[0] * (1.0f / DD) + 1e-5f);
  float* orow = O + (size_t)r * DD;
  orow[tid]       = d0 * rstd * g[tid]       + bb[tid];
  orow[tid + 256] = d1 * rstd * g[tid + 256] + bb[tid + 256];
}

// ---------- final ----------
__global__ __launch_bounds__(64) void pred_kernel(const float* __restrict__ ht,
    const float* __restrict__ wout, const float* __restrict__ bout, float* __restrict__ out){
  int r = blockIdx.x, lane = threadIdx.x;
  float acc = 0.f;
  for (int dd = lane; dd < DD; dd += 64) acc += ht[(size_t)r * DD + dd] * wout[dd];
  acc = wsum(acc);
  if (lane == 0) out[r] = acc + bout[0];
}

extern "C" void kernel_launch(void* const* d_in, const int* in_sizes, int n_in,
                              void* d_out, int out_size, void* d_ws, size_t ws_size,
                              hipStream_t stream){
  const float* x    = (const float*)d_in[0];
  const float* wemb = (const float*)d_in[1];
  const float* bemb = (const float*)d_in[2];
  const float* wq   = (const float*)d_in[3];
  const float* bq   = (const float*)d_in[4];
  const float* wk   = (const float*)d_in[5];
  const float* bk   = (const float*)d_in[6];
  const float* wv   = (const float*)d_in[7];
  const float* bvv  = (const float*)d_in[8];
  const float* wo   = (const float*)d_in[9];
  const float* bo   = (const float*)d_in[10];
  const float* w1   = (const float*)d_in[11];
  const float* b1   = (const float*)d_in[12];
  const float* w2   = (const float*)d_in[13];
  const float* b2   = (const float*)d_in[14];
  const float* g1   = (const float*)d_in[15];
  const float* be1  = (const float*)d_in[16];
  const float* g2   = (const float*)d_in[17];
  const float* be2  = (const float*)d_in[18];
  const float* wout = (const float*)d_in[19];
  const float* bout = (const float*)d_in[20];
  float* out = (float*)d_out;
  char* wsb  = (char*)d_ws;

  const size_t PB = (size_t)LL * DD;

  size_t o = 0;
  float*    h      = (float*)(wsb + o);  o += (size_t)BB * PB * 4;
  float*    qkvb   = (float*)(wsb + o);  o += (size_t)LL * QKVLD * 4;
  ushort_t* ah     = (ushort_t*)(wsb + o); o += PB * 2;
  ushort_t* al     = (ushort_t*)(wsb + o); o += PB * 2;
  ushort_t* hidh   = (ushort_t*)(wsb + o); o += (size_t)CH * DFF * 2;
  ushort_t* hidl   = (ushort_t*)(wsb + o); o += (size_t)CH * DFF * 2;
  float*    fbuf   = (float*)(wsb + o);  o += (size_t)CH * DD * 4;
  ushort_t* wtqkvh = (ushort_t*)(wsb + o); o += (size_t)QKVLD * DD * 2;
  ushort_t* wtqkvl = (ushort_t*)(wsb + o); o += (size_t)QKVLD * DD * 2;
  ushort_t* w1th   = (ushort_t*)(wsb + o); o += (size_t)DFF * DD * 2;
  ushort_t* w1tl   = (ushort_t*)(wsb + o); o += (size_t)DFF * DD * 2;
  ushort_t* w2th   = (ushort_t*)(wsb + o); o += (size_t)DD * DFF * 2;
  ushort_t* w2tl   = (ushort_t*)(wsb + o); o += (size_t)DD * DFF * 2;
  float*    bqkv   = (float*)(wsb + o);  o += QKVLD * 4;
  float*    qsb    = (float*)(wsb + o);  o += (size_t)HH * LL * 4;
  float*    part   = (float*)(wsb + o);  o += (size_t)HH * UMAX * NSPLIT * PSTRIDE * 4;
  float*    htail  = (float*)(wsb + o);  o += (size_t)NTAIL * DD * 4;
  float*    ftail  = (float*)(wsb + o);  o += (size_t)NTAIL * DD * 4;
  int*      topidx = (int*)(wsb + o);    o += (size_t)BB * HH * UMAX * 4;
  int*      ufac   = (int*)(wsb + o);    o += 64;
  // total ~221 MiB (within proven-safe budget)

  wqkv_prep_kernel<<<(QKVLD*DD + 255)/256, 256, 0, stream>>>(wq, wk, wv, wtqkvh, wtqkvl);
  bqkv_prep_kernel<<<(QKVLD + 255)/256, 256, 0, stream>>>(bq, bk, bvv, bqkv);
  wsplit_t_kernel<<<(DFF*DD + 255)/256, 256, 0, stream>>>(w1, w1th, w1tl, DD, DFF);
  wsplit_t_kernel<<<(DD*DFF + 255)/256, 256, 0, stream>>>(w2, w2th, w2tl, DFF, DD);

  embed_kernel<<<BB * LL, 256, 0, stream>>>(x, wemb, bemb, h);

  for (int layer = 0; layer < 2; ++layer){
    const bool tail = (layer == 1);
    if (tail) zero_kernel<<<1024, 256, 0, stream>>>(ftail, (size_t)NTAIL * DD);

    for (int b = 0; b < BB; ++b){
      const float* hb = h + (size_t)b * PB;
      split_kernel<<<(int)(PB/4 + 255)/256, 256, 0, stream>>>(hb, ah, al, (int)(PB/4));
      gemm_x3<false, false><<<dim3(QKVLD/128, LL/128), 256, 0, stream>>>(
          ah, al, wtqkvh, wtqkvl, bqkv, qkvb, nullptr, nullptr, LL, QKVLD, DD, QKVLD);
      qs_kernel<<<(HH*LL)/4, 256, 0, stream>>>(qkvb, qsb);
      select_kernel<<<9, 256, 0, stream>>>(qsb, topidx, ufac, b);
      attn_p1_kernel<<<dim3(NSPLIT, HH*UMAX), 256, 0, stream>>>(
          qkvb, topidx, ufac, part, b, tail ? TAIL0 : 0);
      attn_p2_kernel<<<HH*UMAX, 256, 0, stream>>>(part, wo, topidx, ufac,
          tail ? ftail : h, b, tail ? 1 : 0);
    }

    if (!tail){
      add_ln_kernel<<<BB*LL, 256, 0, stream>>>(h, nullptr, bo, h, g1, be1, 0);
      for (int c = 0; c < (BB*LL)/CH; ++c){
        float* hc = h + (size_t)c * CH * DD;
        split_kernel<<<(int)((size_t)CH*DD/4 + 255)/256, 256, 0, stream>>>(hc, ah, al, (int)((size_t)CH*DD/4));
        gemm_x3<true, true><<<dim3(DFF/128, CH/128), 256, 0, stream>>>(
            ah, al, w1th, w1tl, b1, nullptr, hidh, hidl, CH, DFF, DD, DFF);
        gemm_x3<false, false><<<dim3(DD/128, CH/128), 256, 0, stream>>>(
            hidh, hidl, w2th, w2tl, b2, fbuf, nullptr, nullptr, CH, DD, DFF, DD);
        add_ln_kernel<<<CH, 256, 0, stream>>>(hc, fbuf, nullptr, hc, g2, be2, 0);
      }
    } else {
      add_ln_kernel<<<NTAIL, 256, 0, stream>>>(h, ftail, bo, htail, g1, be1, 1);
      split_kernel<<<(int)((size_t)NTAIL*DD/4 + 255)/256, 256, 0, stream>>>(htail, ah, al, (int)((size_t)NTAIL*DD/4));
      gemm_x3<true, true><<<dim3(DFF/128, NTAIL/128), 256, 0, stream>>>(
          ah, al, w1th, w1tl, b1, nullptr, hidh, hidl, NTAIL, DFF, DD, DFF);
      gemm_x3<false, false><<<dim3(DD/128, NTAIL/128), 256, 0, stream>>>(
          hidh, hidl, w2th, w2tl, b2, fbuf, nullptr, nullptr, NTAIL, DD, DFF, DD);
      add_ln_kernel<<<NTAIL, 256, 0, stream>>>(htail, fbuf, nullptr, htail, g2, be2, 0);
      pred_kernel<<<NTAIL, 64, 0, stream>>>(htail, wout, bout, out);
    }
  }
  (void)in_sizes; (void)n_in; (void)out_size; (void)ws_size;
}

// Round 5
// 3185.950 us; speedup vs baseline: 5.3608x; 1.7431x over previous
//
#include <hip/hip_runtime.h>
#include <math.h>

#define BB 16
#define LL 4096
#define DIN 8
#define DD 512
#define HH 8
#define DKK 64
#define DFF 2048
#define OUTLEN 96
#define TAIL0 (LL - OUTLEN)   /* 4000 */
#define NTAIL (BB * OUTLEN)   /* 1536 */
#define UMAX 10
#define CH 8192               /* FFN row chunk */
#define QKVN 1536
#define NB 4                  /* batches per quarter */
#define QM (NB * LL)          /* 16384 rows per quarter */
#define NSPLIT 32
#define LCHUNK (LL / NSPLIT)  /* 128 */
#define PSTRIDE 68

typedef unsigned short ushort_t;
typedef unsigned int uint_t;
typedef short bf16x8 __attribute__((ext_vector_type(8)));
typedef float f32x4 __attribute__((ext_vector_type(4)));

#define GLD16(gp, lp) __builtin_amdgcn_global_load_lds((const __attribute__((address_space(1))) void*)(gp), (__attribute__((address_space(3))) void*)(lp), 16, 0, 0)

// ---------- helpers ----------
__device__ inline float wsum(float v){
#pragma unroll
  for (int o = 32; o > 0; o >>= 1) v += __shfl_xor(v, o);
  return v;
}
__device__ inline float wmax(float v){
#pragma unroll
  for (int o = 32; o > 0; o >>= 1) v = fmaxf(v, __shfl_xor(v, o));
  return v;
}
__device__ inline ushort_t f2bf_rtn(float f){
  uint_t u = __float_as_uint(f);
  uint_t r = u + 0x7FFF + ((u >> 16) & 1);
  return (ushort_t)(r >> 16);
}
__device__ inline float bf2f(ushort_t u){
  return __uint_as_float(((uint_t)u) << 16);
}
__device__ inline void split2(float x, ushort_t& hi, ushort_t& lo){
  uint_t u = __float_as_uint(x);
  hi = (ushort_t)(u >> 16);
  lo = f2bf_rtn(x - __uint_as_float(u & 0xFFFF0000u));
}
// pack high-16s of two fp32 into one u32: [u1.hi16 : u0.hi16]
__device__ inline uint_t packhi(uint_t u1, uint_t u0){
  return __builtin_amdgcn_perm(u1, u0, 0x07060302u);
}

// ---------- embed ----------
__global__ __launch_bounds__(256) void embed_kernel(const float* __restrict__ x,
    const float* __restrict__ we, const float* __restrict__ be, float* __restrict__ h){
  int row = blockIdx.x;
  __shared__ float xs[DIN];
  if (threadIdx.x < DIN) xs[threadIdx.x] = x[(size_t)row * DIN + threadIdx.x];
  __syncthreads();
  for (int j = threadIdx.x; j < DD; j += 256){
    float acc = be[j];
#pragma unroll
    for (int i = 0; i < DIN; ++i) acc += xs[i] * we[i * DD + j];
    h[(size_t)row * DD + j] = acc;
  }
}

// ---------- weight prep: transpose K x N -> N x K, split hi/lo ----------
__global__ __launch_bounds__(256) void wsplit_t_kernel(const float* __restrict__ W,
    ushort_t* __restrict__ Th, ushort_t* __restrict__ Tl, int K, int N){
  int idx = blockIdx.x * 256 + threadIdx.x;
  if (idx >= N * K) return;
  int n = idx / K, k = idx - n * K;
  ushort_t hi, lo;
  split2(W[(size_t)k * N + n], hi, lo);
  Th[idx] = hi; Tl[idx] = lo;
}
__global__ __launch_bounds__(256) void wqkv_prep_kernel(const float* __restrict__ wq,
    const float* __restrict__ wk, const float* __restrict__ wv,
    ushort_t* __restrict__ Th, ushort_t* __restrict__ Tl){
  int idx = blockIdx.x * 256 + threadIdx.x;
  if (idx >= QKVN * DD) return;
  int n = idx >> 9, k = idx & (DD - 1);
  const float* src = (n < 512) ? wq : (n < 1024) ? wk : wv;
  ushort_t hi, lo;
  split2(src[(size_t)k * DD + (n & 511)], hi, lo);
  Th[idx] = hi; Tl[idx] = lo;
}
__global__ __launch_bounds__(256) void bqkv_prep_kernel(const float* __restrict__ bq,
    const float* __restrict__ bk, const float* __restrict__ bv, float* __restrict__ bo_){
  int n = blockIdx.x * 256 + threadIdx.x;
  if (n >= QKVN) return;
  bo_[n] = (n < 512) ? bq[n] : (n < 1024) ? bk[n - 512] : bv[n - 1024];
}

// ---------- MFMA GEMM, fp32 A staged in LDS + in-register bf16 hi/lo split ----------
// A: M x K fp32 row-major. B: N x K bf16 hi/lo (pre-transposed weights).
// MODE 0: C fp32 (+bias,relu if KSPLIT==1; atomicAdd partial if KSPLIT==2)
// MODE 1: QKV mixed: cols<512 -> fp32 C (ld 512, +bias); cols>=512 -> bf16 KV (ld 1024, +bias)
// LDS XOR-swizzle: A chunk p at slot p^(row&7); B chunk p at slot p^(row&3).
template<int MODE, bool RELU, int KSPLIT>
__global__ __launch_bounds__(256) void gemm_f32a(
    const float* __restrict__ A,
    const ushort_t* __restrict__ Bh, const ushort_t* __restrict__ Bl,
    const float* __restrict__ bias, float* __restrict__ C,
    ushort_t* __restrict__ KV,
    int M, int N, int K, int ldc){
  __shared__ __align__(16) float    AsF[128 * 32];
  __shared__ __align__(16) ushort_t BsH[128 * 32];
  __shared__ __align__(16) ushort_t BsL[128 * 32];
  const int tid  = threadIdx.x;
  const int lane = tid & 63;
  const int wv   = tid >> 6;
  const int nblk = (KSPLIT == 2) ? (int)(blockIdx.x >> 1) : (int)blockIdx.x;
  const int khalf= (KSPLIT == 2) ? (int)(blockIdx.x & 1) : 0;
  const int m0   = blockIdx.y * 128;
  const int n0   = nblk * 128;
  const int wm   = (wv & 1) * 64;
  const int wn   = (wv >> 1) * 64;

  const int aRow0 = tid >> 3;      // 0..31
  const int aSlot = tid & 7;
  const int bRow0 = tid >> 2;      // 0..63
  const int bSlot = tid & 3;

  f32x4 acc[4][4];
#pragma unroll
  for (int i = 0; i < 4; ++i)
#pragma unroll
    for (int j = 0; j < 4; ++j) acc[i][j] = (f32x4){0.f, 0.f, 0.f, 0.f};

  const int arow = lane & 15;
  const int k4   = (lane >> 4) * 2;   // A chunk pair base
  const int kb   = lane >> 4;         // B chunk

  const int kper = K / KSPLIT;
  const int kbeg = khalf * kper;
  for (int k0 = kbeg; k0 < kbeg + kper; k0 += 32){
#pragma unroll
    for (int cc = 0; cc < 4; ++cc){
      const int row = aRow0 + cc * 32;
      const int sp  = aSlot ^ (row & 7);
      GLD16(A + (size_t)(m0 + row) * K + k0 + sp * 4, &AsF[(tid + cc * 256) * 4]);
    }
#pragma unroll
    for (int cc = 0; cc < 2; ++cc){
      const int row = bRow0 + cc * 64;
      const int sp  = bSlot ^ (row & 3);
      GLD16(Bh + (size_t)(n0 + row) * K + k0 + sp * 8, &BsH[(tid + cc * 256) * 8]);
      GLD16(Bl + (size_t)(n0 + row) * K + k0 + sp * 8, &BsL[(tid + cc * 256) * 8]);
    }
    __syncthreads();

    bf16x8 ah[4], al[4], bh[4], bl[4];
#pragma unroll
    for (int i = 0; i < 4; ++i){
      const int row = wm + i * 16 + arow;
      const float4 a0 = *(const float4*)&AsF[row * 32 + ((k4    ) ^ (row & 7)) * 4];
      const float4 a1 = *(const float4*)&AsF[row * 32 + ((k4 + 1) ^ (row & 7)) * 4];
      const uint_t u0 = __float_as_uint(a0.x), u1 = __float_as_uint(a0.y);
      const uint_t u2 = __float_as_uint(a0.z), u3 = __float_as_uint(a0.w);
      const uint_t u4 = __float_as_uint(a1.x), u5 = __float_as_uint(a1.y);
      const uint_t u6 = __float_as_uint(a1.z), u7 = __float_as_uint(a1.w);
      union { uint_t u[4]; bf16x8 v; } Hh, Ll;
      Hh.u[0] = packhi(u1, u0); Hh.u[1] = packhi(u3, u2);
      Hh.u[2] = packhi(u5, u4); Hh.u[3] = packhi(u7, u6);
      const float d0 = a0.x - __uint_as_float(u0 & 0xFFFF0000u);
      const float d1 = a0.y - __uint_as_float(u1 & 0xFFFF0000u);
      const float d2 = a0.z - __uint_as_float(u2 & 0xFFFF0000u);
      const float d3 = a0.w - __uint_as_float(u3 & 0xFFFF0000u);
      const float d4 = a1.x - __uint_as_float(u4 & 0xFFFF0000u);
      const float d5 = a1.y - __uint_as_float(u5 & 0xFFFF0000u);
      const float d6 = a1.z - __uint_as_float(u6 & 0xFFFF0000u);
      const float d7 = a1.w - __uint_as_float(u7 & 0xFFFF0000u);
      Ll.u[0] = packhi(__float_as_uint(d1), __float_as_uint(d0));
      Ll.u[1] = packhi(__float_as_uint(d3), __float_as_uint(d2));
      Ll.u[2] = packhi(__float_as_uint(d5), __float_as_uint(d4));
      Ll.u[3] = packhi(__float_as_uint(d7), __float_as_uint(d6));
      ah[i] = Hh.v; al[i] = Ll.v;
      const int brow = wn + i * 16 + arow;
      const int bs = (kb ^ (brow & 3)) * 8;
      bh[i] = *(const bf16x8*)&BsH[brow * 32 + bs];
      bl[i] = *(const bf16x8*)&BsL[brow * 32 + bs];
    }
#pragma unroll
    for (int i = 0; i < 4; ++i)
#pragma unroll
      for (int j = 0; j < 4; ++j){
        acc[i][j] = __builtin_amdgcn_mfma_f32_16x16x32_bf16(ah[i], bh[j], acc[i][j], 0, 0, 0);
        acc[i][j] = __builtin_amdgcn_mfma_f32_16x16x32_bf16(al[i], bh[j], acc[i][j], 0, 0, 0);
        acc[i][j] = __builtin_amdgcn_mfma_f32_16x16x32_bf16(ah[i], bl[j], acc[i][j], 0, 0, 0);
      }
    __syncthreads();
  }

  const int crow = (lane >> 4) * 4;
  const int ccol = lane & 15;
#pragma unroll
  for (int i = 0; i < 4; ++i){
    const int gr0 = m0 + wm + i * 16 + crow;
#pragma unroll
    for (int j = 0; j < 4; ++j){
      const int gc = n0 + wn + j * 16 + ccol;
#pragma unroll
      for (int r = 0; r < 4; ++r){
        float v = acc[i][j][r];
        const int gr = gr0 + r;
        if (MODE == 1){
          v += bias[gc];
          if (gc < 512) C[(size_t)gr * 512 + gc] = v;
          else          KV[(size_t)gr * 1024 + (gc - 512)] = f2bf_rtn(v);
        } else {
          if (KSPLIT == 1){
            v += bias[gc];
            if (RELU) v = fmaxf(v, 0.f);
            C[(size_t)gr * ldc + gc] = v;
          } else {
            atomicAdd(&C[(size_t)gr * ldc + gc], v);
          }
        }
      }
    }
  }
}

// ---------- qs scoring, one quarter (NB batches) ----------
__global__ __launch_bounds__(256) void qs_kernel(const float* __restrict__ qbuf, float* __restrict__ qsb){
  int tid = threadIdx.x;
  int lane = tid & 63;
  int wv = tid >> 6;
  int rid = blockIdx.x * 4 + wv;          // < NB*HH*LL
  int bloc = rid >> 15;
  int hh = (rid >> 12) & 7;
  int l  = rid & (LL - 1);
  float qv = qbuf[((size_t)bloc * LL + l) * DD + hh * DKK + lane];
  float l2 = sqrtf(wsum(qv * qv));
  float mx = wmax(qv);
  float e  = expf(qv - mx);
  float se = wsum(e);
  float p  = e / se;
  float ent = -wsum(p * logf(p + 1e-9f));
  float mu  = wsum(qv) * (1.0f / 64.0f);
  float dv  = qv - mu;
  float var = wsum(dv * dv) * (1.0f / 63.0f);
  float val = 0.5f * l2 + 0.3f * ent + 0.2f * var;
  if (lane == 0) qsb[(size_t)(bloc * HH + hh) * LL + l] = val;
}

// ---------- selection: grid (9, NB); x=0..7 top-10 per head, x=8 u factor ----------
__global__ __launch_bounds__(256) void select_kernel(const float* __restrict__ qsb,
    int* __restrict__ topidx, int* __restrict__ ufac, int qtr){
  __shared__ float vals[LL];
  __shared__ float bv[256];
  __shared__ int   bi[256];
  __shared__ double r1[256], r2[256];
  const int bloc = blockIdx.y;
  const int b = qtr * NB + bloc;
  int tid = threadIdx.x;
  if (blockIdx.x == 8){
    const float* row = qsb + (size_t)bloc * HH * LL;  // head 0
    double s = 0.0, s2 = 0.0;
    for (int l = tid; l < LL; l += 256){ double v = row[l]; s += v; s2 += v * v; }
    r1[tid] = s; r2[tid] = s2; __syncthreads();
    for (int st = 128; st; st >>= 1){
      if (tid < st){ r1[tid] += r1[tid+st]; r2[tid] += r2[tid+st]; }
      __syncthreads();
    }
    if (tid == 0){
      double mean = r1[0] / (double)LL;
      double var  = (r2[0] - (double)LL * mean * mean) / (double)(LL - 1);
      if (var < 0.0) var = 0.0;
      double f = rint(sqrt(var) / (mean + 1e-6) * 10.0);
      if (f < 3.0) f = 3.0;
      if (f > 10.0) f = 10.0;
      ufac[b] = (int)f;
    }
    return;
  }
  int hh = blockIdx.x;
  const float* row = qsb + ((size_t)bloc * HH + hh) * LL;
  for (int l = tid; l < LL; l += 256) vals[l] = row[l];
  __syncthreads();
  for (int it = 0; it < UMAX; ++it){
    float best = -INFINITY; int bidx = 0;
    for (int l = tid; l < LL; l += 256){
      float v = vals[l];
      if (v > best){ best = v; bidx = l; }
    }
    bv[tid] = best; bi[tid] = bidx; __syncthreads();
    for (int st = 128; st; st >>= 1){
      if (tid < st){
        if (bv[tid+st] > bv[tid] || (bv[tid+st] == bv[tid] && bi[tid+st] < bi[tid])){
          bv[tid] = bv[tid+st]; bi[tid] = bi[tid+st];
        }
      }
      __syncthreads();
    }
    if (tid == 0){ topidx[(b * HH + hh) * UMAX + it] = bi[0]; vals[bi[0]] = -INFINITY; }
    __syncthreads();
  }
}

// ---------- attention pass 1: grid (NSPLIT, HH*UMAX, NB) ----------
__global__ __launch_bounds__(256) void attn_p1_kernel(const float* __restrict__ qbuf,
    const ushort_t* __restrict__ kvbuf,
    const int* __restrict__ topidx, const int* __restrict__ ufac,
    float* __restrict__ part, int qtr, int lmin){
  const int bloc = blockIdx.z;
  const int b = qtr * NB + bloc;
  const int rowid = blockIdx.y;
  const int hh = rowid / UMAX, rank = rowid % UMAX;
  if (rank >= ufac[b]) return;
  const int qpos = topidx[(b * HH + hh) * UMAX + rank];
  if (qpos < lmin) return;

  const int tid = threadIdx.x, lane = tid & 63, wv = tid >> 6;
  const int base = blockIdx.x * LCHUNK + wv * (LCHUNK / 4);

  __shared__ float qrow[DKK];
  __shared__ float wm4[4], ws4[4];
  __shared__ float pvs[4][DKK];
  if (tid < DKK) qrow[tid] = qbuf[((size_t)bloc * LL + qpos) * DD + hh * DKK + tid];
  __syncthreads();

  const ushort_t* Kp = kvbuf + (size_t)bloc * LL * 1024 + hh * DKK;
  const ushort_t* Vp = Kp + 512;
  const float qv = qrow[lane];

  float sc[32];
  float mloc = -INFINITY;
#pragma unroll
  for (int i = 0; i < 32; ++i){
    float s = wsum(qv * bf2f(Kp[(size_t)(base + i) * 1024 + lane])) * 0.125f;
    sc[i] = s;
    mloc = fmaxf(mloc, s);
  }
  if (lane == 0) wm4[wv] = mloc;
  __syncthreads();
  const float M4 = fmaxf(fmaxf(wm4[0], wm4[1]), fmaxf(wm4[2], wm4[3]));

  float ssum = 0.f;
#pragma unroll
  for (int i = 0; i < 32; ++i){ float e = expf(sc[i] - M4); sc[i] = e; ssum += e; }

  float pv = 0.f;
#pragma unroll
  for (int i = 0; i < 32; ++i) pv += sc[i] * bf2f(Vp[(size_t)(base + i) * 1024 + lane]);

  pvs[wv][lane] = pv;
  if (lane == 0) ws4[wv] = ssum;
  __syncthreads();
  if (wv == 0){
    float* rec = part + (size_t)((bloc * HH * UMAX + rowid) * NSPLIT + blockIdx.x) * PSTRIDE;
    rec[lane] = pvs[0][lane] + pvs[1][lane] + pvs[2][lane] + pvs[3][lane];
    if (lane == 0){ rec[64] = M4; rec[65] = ws4[0] + ws4[1] + ws4[2] + ws4[3]; }
  }
}

// ---------- attention pass 2: combine + wo scatter; grid (HH*UMAX, NB) ----------
__global__ __launch_bounds__(256) void attn_p2_kernel(const float* __restrict__ part,
    const float* __restrict__ wo, const int* __restrict__ topidx, const int* __restrict__ ufac,
    float* __restrict__ target, int qtr, int tailmode){
  const int bloc = blockIdx.y;
  const int b = qtr * NB + bloc;
  const int rowid = blockIdx.x;
  const int hh = rowid / UMAX, rank = rowid % UMAX;
  if (rank >= ufac[b]) return;
  const int qpos = topidx[(b * HH + hh) * UMAX + rank];
  size_t drow;
  if (tailmode){
    if (qpos < TAIL0) return;
    drow = (size_t)(b * OUTLEN + (qpos - TAIL0));
  } else {
    drow = (size_t)b * LL + qpos;
  }
  const int tid = threadIdx.x;
  const float* pbase = part + (size_t)(bloc * HH * UMAX + rowid) * NSPLIT * PSTRIDE;
  __shared__ float pm[NSPLIT], ps[NSPLIT];
  __shared__ float orow[DKK];
  if (tid < NSPLIT){
    pm[tid] = pbase[(size_t)tid * PSTRIDE + 64];
    ps[tid] = pbase[(size_t)tid * PSTRIDE + 65];
  }
  __syncthreads();
  float M = -INFINITY;
#pragma unroll
  for (int i = 0; i < NSPLIT; ++i) M = fmaxf(M, pm[i]);
  float S = 0.f;
#pragma unroll
  for (int i = 0; i < NSPLIT; ++i) S += ps[i] * expf(pm[i] - M);
  if (tid < DKK){
    float acc = 0.f;
#pragma unroll
    for (int i = 0; i < NSPLIT; ++i)
      acc += pbase[(size_t)i * PSTRIDE + tid] * expf(pm[i] - M);
    orow[tid] = acc / S;
  }
  __syncthreads();
  for (int j = tid; j < DD; j += 256){
    float a = 0.f;
#pragma unroll
    for (int dd = 0; dd < DKK; ++dd) a += orow[dd] * wo[(size_t)(hh * DKK + dd) * DD + j];
    atomicAdd(&target[drow * DD + j], a);
  }
}

// ---------- zero fill ----------
__global__ void zero_kernel(float* __restrict__ p, size_t n){
  size_t i = (size_t)blockIdx.x * 256 + threadIdx.x;
  size_t stride = (size_t)gridDim.x * 256;
  for (; i < n; i += stride) p[i] = 0.f;
}

// ---------- O_row = LN(X_row [+Y_row] [+bias]) * g + bb ----------
__global__ __launch_bounds__(256) void add_ln_kernel(const float* __restrict__ X,
    const float* __restrict__ Y, const float* __restrict__ bias, float* __restrict__ O,
    const float* __restrict__ g, const float* __restrict__ bb, int tailmapX){
  __shared__ float red[256];
  int r = blockIdx.x, tid = threadIdx.x;
  const float* xr;
  if (tailmapX){
    int b = r / OUTLEN;
    int l = TAIL0 + (r % OUTLEN);
    xr = X + ((size_t)b * LL + l) * DD;
  } else {
    xr = X + (size_t)r * DD;
  }
  float v0 = xr[tid];
  float v1 = xr[tid + 256];
  if (Y){
    const float* yr = Y + (size_t)r * DD;
    v0 += yr[tid]; v1 += yr[tid + 256];
  }
  if (bias){ v0 += bias[tid]; v1 += bias[tid + 256]; }
  red[tid] = v0 + v1; __syncthreads();
  for (int st = 128; st; st >>= 1){ if (tid < st) red[tid] += red[tid+st]; __syncthreads(); }
  float mu = red[0] * (1.0f / DD); __syncthreads();
  float d0 = v0 - mu, d1 = v1 - mu;
  red[tid] = d0*d0 + d1*d1; __syncthreads();
  for (int st = 128; st; st >>= 1){ if (tid < st) red[tid] += red[tid+st]; __syncthreads(); }
  float rstd = rsqrtf(red[0] * (1.0f / DD) + 1e-5f);
  float* orow = O + (size_t)r * DD;
  orow[tid]       = d0 * rstd * g[tid]       + bb[tid];
  orow[tid + 256] = d1 * rstd * g[tid + 256] + bb[tid + 256];
}

// ---------- final ----------
__global__ __launch_bounds__(64) void pred_kernel(const float* __restrict__ ht,
    const float* __restrict__ wout, const float* __restrict__ bout, float* __restrict__ out){
  int r = blockIdx.x, lane = threadIdx.x;
  float acc = 0.f;
  for (int dd = lane; dd < DD; dd += 64) acc += ht[(size_t)r * DD + dd] * wout[dd];
  acc = wsum(acc);
  if (lane == 0) out[r] = acc + bout[0];
}

extern "C" void kernel_launch(void* const* d_in, const int* in_sizes, int n_in,
                              void* d_out, int out_size, void* d_ws, size_t ws_size,
                              hipStream_t stream){
  const float* x    = (const float*)d_in[0];
  const float* wemb = (const float*)d_in[1];
  const float* bemb = (const float*)d_in[2];
  const float* wq   = (const float*)d_in[3];
  const float* bq   = (const float*)d_in[4];
  const float* wk   = (const float*)d_in[5];
  const float* bk   = (const float*)d_in[6];
  const float* wv   = (const float*)d_in[7];
  const float* bvv  = (const float*)d_in[8];
  const float* wo   = (const float*)d_in[9];
  const float* bo   = (const float*)d_in[10];
  const float* w1   = (const float*)d_in[11];
  const float* b1   = (const float*)d_in[12];
  const float* w2   = (const float*)d_in[13];
  const float* b2   = (const float*)d_in[14];
  const float* g1   = (const float*)d_in[15];
  const float* be1  = (const float*)d_in[16];
  const float* g2   = (const float*)d_in[17];
  const float* be2  = (const float*)d_in[18];
  const float* wout = (const float*)d_in[19];
  const float* bout = (const float*)d_in[20];
  float* out = (float*)d_out;
  char* wsb  = (char*)d_ws;

  const size_t PB = (size_t)LL * DD;

  size_t o = 0;
  float*    h      = (float*)(wsb + o);  o += (size_t)BB * PB * 4;          // 128 MiB
  float*    qbuf   = (float*)(wsb + o);  o += (size_t)QM * DD * 4;          // 32 MiB
  ushort_t* kvbuf  = (ushort_t*)(wsb + o); o += (size_t)QM * 1024 * 2;      // 32 MiB (contiguous after qbuf)
  float*    fbuf   = (float*)(wsb + o);  o += (size_t)CH * DD * 4;          // 16 MiB
  ushort_t* wtqkvh = (ushort_t*)(wsb + o); o += (size_t)QKVN * DD * 2;
  ushort_t* wtqkvl = (ushort_t*)(wsb + o); o += (size_t)QKVN * DD * 2;
  ushort_t* w1th   = (ushort_t*)(wsb + o); o += (size_t)DFF * DD * 2;
  ushort_t* w1tl   = (ushort_t*)(wsb + o); o += (size_t)DFF * DD * 2;
  ushort_t* w2th   = (ushort_t*)(wsb + o); o += (size_t)DD * DFF * 2;
  ushort_t* w2tl   = (ushort_t*)(wsb + o); o += (size_t)DD * DFF * 2;
  float*    bqkv   = (float*)(wsb + o);  o += QKVN * 4;
  float*    qsb    = (float*)(wsb + o);  o += (size_t)NB * HH * LL * 4;
  float*    part   = (float*)(wsb + o);  o += (size_t)NB * HH * UMAX * NSPLIT * PSTRIDE * 4;
  float*    htail  = (float*)(wsb + o);  o += (size_t)NTAIL * DD * 4;
  float*    ftail  = (float*)(wsb + o);  o += (size_t)NTAIL * DD * 4;
  int*      topidx = (int*)(wsb + o);    o += (size_t)BB * HH * UMAX * 4;
  int*      ufac   = (int*)(wsb + o);    o += 64;
  float*    hid    = qbuf;   // FFN hidden (CH x DFF fp32 = 64 MiB) reuses qbuf+kvbuf
  // total ~229 MiB (<=234 proven-safe)

  wqkv_prep_kernel<<<(QKVN*DD + 255)/256, 256, 0, stream>>>(wq, wk, wv, wtqkvh, wtqkvl);
  bqkv_prep_kernel<<<(QKVN + 255)/256, 256, 0, stream>>>(bq, bk, bvv, bqkv);
  wsplit_t_kernel<<<(DFF*DD + 255)/256, 256, 0, stream>>>(w1, w1th, w1tl, DD, DFF);
  wsplit_t_kernel<<<(DD*DFF + 255)/256, 256, 0, stream>>>(w2, w2th, w2tl, DFF, DD);

  embed_kernel<<<BB * LL, 256, 0, stream>>>(x, wemb, bemb, h);

  for (int layer = 0; layer < 2; ++layer){
    const bool tail = (layer == 1);
    if (tail) zero_kernel<<<512, 256, 0, stream>>>(ftail, (size_t)NTAIL * DD);

    for (int qtr = 0; qtr < BB / NB; ++qtr){
      const float* hq = h + (size_t)qtr * NB * PB;
      gemm_f32a<1, false, 1><<<dim3(QKVN/128, QM/128), 256, 0, stream>>>(
          hq, wtqkvh, wtqkvl, bqkv, qbuf, kvbuf, QM, QKVN, DD, QKVN);
      qs_kernel<<<(NB*HH*LL)/4, 256, 0, stream>>>(qbuf, qsb);
      select_kernel<<<dim3(9, NB), 256, 0, stream>>>(qsb, topidx, ufac, qtr);
      attn_p1_kernel<<<dim3(NSPLIT, HH*UMAX, NB), 256, 0, stream>>>(
          qbuf, kvbuf, topidx, ufac, part, qtr, tail ? TAIL0 : 0);
      attn_p2_kernel<<<dim3(HH*UMAX, NB), 256, 0, stream>>>(
          part, wo, topidx, ufac, tail ? ftail : h, qtr, tail ? 1 : 0);
    }

    if (!tail){
      add_ln_kernel<<<BB*LL, 256, 0, stream>>>(h, nullptr, bo, h, g1, be1, 0);
      for (int c = 0; c < (BB*LL)/CH; ++c){
        float* hc = h + (size_t)c * CH * DD;
        gemm_f32a<0, true, 1><<<dim3(DFF/128, CH/128), 256, 0, stream>>>(
            hc, w1th, w1tl, b1, hid, nullptr, CH, DFF, DD, DFF);
        zero_kernel<<<2048, 256, 0, stream>>>(fbuf, (size_t)CH * DD);
        gemm_f32a<0, false, 2><<<dim3((DD/128)*2, CH/128), 256, 0, stream>>>(
            hid, w2th, w2tl, nullptr, fbuf, nullptr, CH, DD, DFF, DD);
        add_ln_kernel<<<CH, 256, 0, stream>>>(hc, fbuf, b2, hc, g2, be2, 0);
      }
    } else {
      add_ln_kernel<<<NTAIL, 256, 0, stream>>>(h, ftail, bo, htail, g1, be1, 1);
      gemm_f32a<0, true, 1><<<dim3(DFF/128, NTAIL/128), 256, 0, stream>>>(
          htail, w1th, w1tl, b1, hid, nullptr, NTAIL, DFF, DD, DFF);
      zero_kernel<<<512, 256, 0, stream>>>(fbuf, (size_t)NTAIL * DD);
      gemm_f32a<0, false, 2><<<dim3((DD/128)*2, NTAIL/128), 256, 0, stream>>>(
          hid, w2th, w2tl, nullptr, fbuf, nullptr, NTAIL, DD, DFF, DD);
      add_ln_kernel<<<NTAIL, 256, 0, stream>>>(htail, fbuf, b2, htail, g2, be2, 0);
      pred_kernel<<<NTAIL, 64, 0, stream>>>(htail, wout, bout, out);
    }
  }
  (void)in_sizes; (void)n_in; (void)out_size; (void)ws_size;
}

// Round 6
// 3169.308 us; speedup vs baseline: 5.3890x; 1.0053x over previous
//
#include <hip/hip_runtime.h>
#include <math.h>

#define BB 16
#define LL 4096
#define DIN 8
#define DD 512
#define HH 8
#define DKK 64
#define DFF 2048
#define OUTLEN 96
#define TAIL0 (LL - OUTLEN)   /* 4000 */
#define NTAIL (BB * OUTLEN)   /* 1536 */
#define UMAX 10
#define CH 4096               /* FFN row chunk (= 1 batch) */
#define QKVN 1536
#define NB 4                  /* batches per quarter */
#define QM (NB * LL)          /* 16384 rows per quarter */
#define NSPLIT 32
#define LCHUNK (LL / NSPLIT)  /* 128 */
#define PSTRIDE 68

typedef unsigned short ushort_t;
typedef unsigned int uint_t;
typedef short bf16x8 __attribute__((ext_vector_type(8)));
typedef float f32x4 __attribute__((ext_vector_type(4)));

#define GLD16(gp, lp) __builtin_amdgcn_global_load_lds((const __attribute__((address_space(1))) void*)(gp), (__attribute__((address_space(3))) void*)(lp), 16, 0, 0)

// ---------- helpers ----------
__device__ inline float wsum(float v){
#pragma unroll
  for (int o = 32; o > 0; o >>= 1) v += __shfl_xor(v, o);
  return v;
}
__device__ inline float wmax(float v){
#pragma unroll
  for (int o = 32; o > 0; o >>= 1) v = fmaxf(v, __shfl_xor(v, o));
  return v;
}
__device__ inline ushort_t f2bf_rtn(float f){
  uint_t u = __float_as_uint(f);
  uint_t r = u + 0x7FFF + ((u >> 16) & 1);
  return (ushort_t)(r >> 16);
}
__device__ inline float bf2f(ushort_t u){
  return __uint_as_float(((uint_t)u) << 16);
}
__device__ inline void split2(float x, ushort_t& hi, ushort_t& lo){
  uint_t u = __float_as_uint(x);
  hi = (ushort_t)(u >> 16);
  lo = f2bf_rtn(x - __uint_as_float(u & 0xFFFF0000u));
}
__device__ inline uint_t packhi(uint_t u1, uint_t u0){
  return __builtin_amdgcn_perm(u1, u0, 0x07060302u);
}

// ---------- embed ----------
__global__ __launch_bounds__(256) void embed_kernel(const float* __restrict__ x,
    const float* __restrict__ we, const float* __restrict__ be, float* __restrict__ h){
  int row = blockIdx.x;
  __shared__ float xs[DIN];
  if (threadIdx.x < DIN) xs[threadIdx.x] = x[(size_t)row * DIN + threadIdx.x];
  __syncthreads();
  for (int j = threadIdx.x; j < DD; j += 256){
    float acc = be[j];
#pragma unroll
    for (int i = 0; i < DIN; ++i) acc += xs[i] * we[i * DD + j];
    h[(size_t)row * DD + j] = acc;
  }
}

// ---------- weight prep ----------
__global__ __launch_bounds__(256) void wsplit_t_kernel(const float* __restrict__ W,
    ushort_t* __restrict__ Th, ushort_t* __restrict__ Tl, int K, int N){
  int idx = blockIdx.x * 256 + threadIdx.x;
  if (idx >= N * K) return;
  int n = idx / K, k = idx - n * K;
  ushort_t hi, lo;
  split2(W[(size_t)k * N + n], hi, lo);
  Th[idx] = hi; Tl[idx] = lo;
}
__global__ __launch_bounds__(256) void wqkv_prep_kernel(const float* __restrict__ wq,
    const float* __restrict__ wk, const float* __restrict__ wv,
    ushort_t* __restrict__ Th, ushort_t* __restrict__ Tl){
  int idx = blockIdx.x * 256 + threadIdx.x;
  if (idx >= QKVN * DD) return;
  int n = idx >> 9, k = idx & (DD - 1);
  const float* src = (n < 512) ? wq : (n < 1024) ? wk : wv;
  ushort_t hi, lo;
  split2(src[(size_t)k * DD + (n & 511)], hi, lo);
  Th[idx] = hi; Tl[idx] = lo;
}
__global__ __launch_bounds__(256) void bqkv_prep_kernel(const float* __restrict__ bq,
    const float* __restrict__ bk, const float* __restrict__ bv, float* __restrict__ bo_){
  int n = blockIdx.x * 256 + threadIdx.x;
  if (n >= QKVN) return;
  bo_[n] = (n < 512) ? bq[n] : (n < 1024) ? bk[n - 512] : bv[n - 1024];
}

// ---------- QKV GEMM: fp32 A staged in LDS + in-register bf16 hi/lo split ----------
// cols<512 -> fp32 Q (ld 512, +bias); cols>=512 -> bf16 KV (ld 1024, +bias)
__global__ __launch_bounds__(256) void gemm_f32a(
    const float* __restrict__ A,
    const ushort_t* __restrict__ Bh, const ushort_t* __restrict__ Bl,
    const float* __restrict__ bias, float* __restrict__ C,
    ushort_t* __restrict__ KV, int K){
  __shared__ __align__(16) float    AsF[128 * 32];
  __shared__ __align__(16) ushort_t BsH[128 * 32];
  __shared__ __align__(16) ushort_t BsL[128 * 32];
  const int tid  = threadIdx.x;
  const int lane = tid & 63;
  const int wv   = tid >> 6;
  const int m0   = blockIdx.y * 128;
  const int n0   = blockIdx.x * 128;
  const int wm   = (wv & 1) * 64;
  const int wn   = (wv >> 1) * 64;

  const int aRow0 = tid >> 3;
  const int aSlot = tid & 7;
  const int bRow0 = tid >> 2;
  const int bSlot = tid & 3;

  f32x4 acc[4][4];
#pragma unroll
  for (int i = 0; i < 4; ++i)
#pragma unroll
    for (int j = 0; j < 4; ++j) acc[i][j] = (f32x4){0.f, 0.f, 0.f, 0.f};

  const int arow = lane & 15;
  const int k4   = (lane >> 4) * 2;
  const int kb   = lane >> 4;

  for (int k0 = 0; k0 < K; k0 += 32){
#pragma unroll
    for (int cc = 0; cc < 4; ++cc){
      const int row = aRow0 + cc * 32;
      const int sp  = aSlot ^ (row & 7);
      GLD16(A + (size_t)(m0 + row) * K + k0 + sp * 4, &AsF[(tid + cc * 256) * 4]);
    }
#pragma unroll
    for (int cc = 0; cc < 2; ++cc){
      const int row = bRow0 + cc * 64;
      const int sp  = bSlot ^ (row & 3);
      GLD16(Bh + (size_t)(n0 + row) * K + k0 + sp * 8, &BsH[(tid + cc * 256) * 8]);
      GLD16(Bl + (size_t)(n0 + row) * K + k0 + sp * 8, &BsL[(tid + cc * 256) * 8]);
    }
    __syncthreads();

    bf16x8 ah[4], al[4], bh[4], bl[4];
#pragma unroll
    for (int i = 0; i < 4; ++i){
      const int row = wm + i * 16 + arow;
      const float4 a0 = *(const float4*)&AsF[row * 32 + ((k4    ) ^ (row & 7)) * 4];
      const float4 a1 = *(const float4*)&AsF[row * 32 + ((k4 + 1) ^ (row & 7)) * 4];
      const uint_t u0 = __float_as_uint(a0.x), u1 = __float_as_uint(a0.y);
      const uint_t u2 = __float_as_uint(a0.z), u3 = __float_as_uint(a0.w);
      const uint_t u4 = __float_as_uint(a1.x), u5 = __float_as_uint(a1.y);
      const uint_t u6 = __float_as_uint(a1.z), u7 = __float_as_uint(a1.w);
      union { uint_t u[4]; bf16x8 v; } Hh, Ll;
      Hh.u[0] = packhi(u1, u0); Hh.u[1] = packhi(u3, u2);
      Hh.u[2] = packhi(u5, u4); Hh.u[3] = packhi(u7, u6);
      const float d0 = a0.x - __uint_as_float(u0 & 0xFFFF0000u);
      const float d1 = a0.y - __uint_as_float(u1 & 0xFFFF0000u);
      const float d2 = a0.z - __uint_as_float(u2 & 0xFFFF0000u);
      const float d3 = a0.w - __uint_as_float(u3 & 0xFFFF0000u);
      const float d4 = a1.x - __uint_as_float(u4 & 0xFFFF0000u);
      const float d5 = a1.y - __uint_as_float(u5 & 0xFFFF0000u);
      const float d6 = a1.z - __uint_as_float(u6 & 0xFFFF0000u);
      const float d7 = a1.w - __uint_as_float(u7 & 0xFFFF0000u);
      Ll.u[0] = packhi(__float_as_uint(d1), __float_as_uint(d0));
      Ll.u[1] = packhi(__float_as_uint(d3), __float_as_uint(d2));
      Ll.u[2] = packhi(__float_as_uint(d5), __float_as_uint(d4));
      Ll.u[3] = packhi(__float_as_uint(d7), __float_as_uint(d6));
      ah[i] = Hh.v; al[i] = Ll.v;
      const int brow = wn + i * 16 + arow;
      const int bs = (kb ^ (brow & 3)) * 8;
      bh[i] = *(const bf16x8*)&BsH[brow * 32 + bs];
      bl[i] = *(const bf16x8*)&BsL[brow * 32 + bs];
    }
#pragma unroll
    for (int i = 0; i < 4; ++i)
#pragma unroll
      for (int j = 0; j < 4; ++j){
        acc[i][j] = __builtin_amdgcn_mfma_f32_16x16x32_bf16(ah[i], bh[j], acc[i][j], 0, 0, 0);
        acc[i][j] = __builtin_amdgcn_mfma_f32_16x16x32_bf16(al[i], bh[j], acc[i][j], 0, 0, 0);
        acc[i][j] = __builtin_amdgcn_mfma_f32_16x16x32_bf16(ah[i], bl[j], acc[i][j], 0, 0, 0);
      }
    __syncthreads();
  }

  const int crow = (lane >> 4) * 4;
  const int ccol = lane & 15;
#pragma unroll
  for (int i = 0; i < 4; ++i){
    const int gr0 = m0 + wm + i * 16 + crow;
#pragma unroll
    for (int j = 0; j < 4; ++j){
      const int gc = n0 + wn + j * 16 + ccol;
      const float bvv = bias[gc];
#pragma unroll
      for (int r = 0; r < 4; ++r){
        float v = acc[i][j][r] + bvv;
        const int gr = gr0 + r;
        if (gc < 512) C[(size_t)gr * 512 + gc] = v;
        else          KV[(size_t)gr * 1024 + (gc - 512)] = f2bf_rtn(v);
      }
    }
  }
}

// ---------- pure-bf16 x3 GEMM (round-3 verified body) ----------
// A: M x K bf16 hi/lo row-major. B: N x K bf16 hi/lo (W^T).
// OUT 0: C fp32 = A@W + bias (+relu). OUT 1: split bf16 out (+bias,+relu).
// OUT 2: partial fp32 (no bias) at C + kq*pstr, split-K = KS.
template<bool RELU, int OUT, int KS>
__global__ __launch_bounds__(256) void gemm_bf16(
    const ushort_t* __restrict__ Ah, const ushort_t* __restrict__ Al,
    const ushort_t* __restrict__ Bh, const ushort_t* __restrict__ Bl,
    const float* __restrict__ bias, float* __restrict__ C,
    ushort_t* __restrict__ Ch, ushort_t* __restrict__ Cl,
    int M, int N, int K, int ldc, size_t pstr){
  __shared__ __align__(16) ushort_t AsH[128 * 32];
  __shared__ __align__(16) ushort_t AsL[128 * 32];
  __shared__ __align__(16) ushort_t BsH[128 * 32];
  __shared__ __align__(16) ushort_t BsL[128 * 32];
  const int tid  = threadIdx.x;
  const int lane = tid & 63;
  const int wv   = tid >> 6;
  const int nblk = (int)blockIdx.x / KS;
  const int kq   = (int)blockIdx.x % KS;
  const int m0   = blockIdx.y * 128;
  const int n0   = nblk * 128;
  const int wm   = (wv & 1) * 64;
  const int wn   = (wv >> 1) * 64;

  const int rowA = tid >> 2;
  const int qe   = (tid & 3) * 8;
  const int lds0 = tid * 8;
  const int lds1 = (tid + 256) * 8;

  f32x4 acc[4][4];
#pragma unroll
  for (int i = 0; i < 4; ++i)
#pragma unroll
    for (int j = 0; j < 4; ++j) acc[i][j] = (f32x4){0.f, 0.f, 0.f, 0.f};

  const int arow = lane & 15;
  const int koff = (lane >> 4) * 8;

  const int kper = K / KS;
  const int kbeg = kq * kper;
  for (int k0 = kbeg; k0 < kbeg + kper; k0 += 32){
    const size_t ga0 = (size_t)(m0 + rowA) * K + k0 + qe;
    const size_t ga1 = (size_t)(m0 + rowA + 64) * K + k0 + qe;
    const size_t gb0 = (size_t)(n0 + rowA) * K + k0 + qe;
    const size_t gb1 = (size_t)(n0 + rowA + 64) * K + k0 + qe;
    GLD16(Ah + ga0, &AsH[lds0]);  GLD16(Ah + ga1, &AsH[lds1]);
    GLD16(Al + ga0, &AsL[lds0]);  GLD16(Al + ga1, &AsL[lds1]);
    GLD16(Bh + gb0, &BsH[lds0]);  GLD16(Bh + gb1, &BsH[lds1]);
    GLD16(Bl + gb0, &BsL[lds0]);  GLD16(Bl + gb1, &BsL[lds1]);
    __syncthreads();

    bf16x8 ah[4], al[4], bh[4], bl[4];
#pragma unroll
    for (int i = 0; i < 4; ++i){
      ah[i] = *(const bf16x8*)&AsH[(wm + i * 16 + arow) * 32 + koff];
      al[i] = *(const bf16x8*)&AsL[(wm + i * 16 + arow) * 32 + koff];
      bh[i] = *(const bf16x8*)&BsH[(wn + i * 16 + arow) * 32 + koff];
      bl[i] = *(const bf16x8*)&BsL[(wn + i * 16 + arow) * 32 + koff];
    }
#pragma unroll
    for (int i = 0; i < 4; ++i)
#pragma unroll
      for (int j = 0; j < 4; ++j){
        acc[i][j] = __builtin_amdgcn_mfma_f32_16x16x32_bf16(ah[i], bh[j], acc[i][j], 0, 0, 0);
        acc[i][j] = __builtin_amdgcn_mfma_f32_16x16x32_bf16(al[i], bh[j], acc[i][j], 0, 0, 0);
        acc[i][j] = __builtin_amdgcn_mfma_f32_16x16x32_bf16(ah[i], bl[j], acc[i][j], 0, 0, 0);
      }
    __syncthreads();
  }

  const int crow = (lane >> 4) * 4;
  const int ccol = lane & 15;
#pragma unroll
  for (int i = 0; i < 4; ++i){
    const int gr0 = m0 + wm + i * 16 + crow;
#pragma unroll
    for (int j = 0; j < 4; ++j){
      const int gc = n0 + wn + j * 16 + ccol;
      const float bvv = (OUT == 2) ? 0.f : bias[gc];
#pragma unroll
      for (int r = 0; r < 4; ++r){
        float v = acc[i][j][r] + bvv;
        if (RELU) v = fmaxf(v, 0.f);
        const size_t off = (size_t)(gr0 + r) * ldc + gc;
        if (OUT == 0)      C[off] = v;
        else if (OUT == 1){ ushort_t hu, lu; split2(v, hu, lu); Ch[off] = hu; Cl[off] = lu; }
        else               C[(size_t)kq * pstr + off] = v;
      }
    }
  }
}

// ---------- qs scoring, one quarter ----------
__global__ __launch_bounds__(256) void qs_kernel(const float* __restrict__ qbuf, float* __restrict__ qsb){
  int tid = threadIdx.x;
  int lane = tid & 63;
  int wv = tid >> 6;
  int rid = blockIdx.x * 4 + wv;
  int bloc = rid >> 15;
  int hh = (rid >> 12) & 7;
  int l  = rid & (LL - 1);
  float qv = qbuf[((size_t)bloc * LL + l) * DD + hh * DKK + lane];
  float l2 = sqrtf(wsum(qv * qv));
  float mx = wmax(qv);
  float e  = expf(qv - mx);
  float se = wsum(e);
  float p  = e / se;
  float ent = -wsum(p * logf(p + 1e-9f));
  float mu  = wsum(qv) * (1.0f / 64.0f);
  float dv  = qv - mu;
  float var = wsum(dv * dv) * (1.0f / 63.0f);
  float val = 0.5f * l2 + 0.3f * ent + 0.2f * var;
  if (lane == 0) qsb[(size_t)(bloc * HH + hh) * LL + l] = val;
}

// ---------- selection ----------
__global__ __launch_bounds__(256) void select_kernel(const float* __restrict__ qsb,
    int* __restrict__ topidx, int* __restrict__ ufac, int qtr){
  __shared__ float vals[LL];
  __shared__ float bv[256];
  __shared__ int   bi[256];
  __shared__ double r1[256], r2[256];
  const int bloc = blockIdx.y;
  const int b = qtr * NB + bloc;
  int tid = threadIdx.x;
  if (blockIdx.x == 8){
    const float* row = qsb + (size_t)bloc * HH * LL;
    double s = 0.0, s2 = 0.0;
    for (int l = tid; l < LL; l += 256){ double v = row[l]; s += v; s2 += v * v; }
    r1[tid] = s; r2[tid] = s2; __syncthreads();
    for (int st = 128; st; st >>= 1){
      if (tid < st){ r1[tid] += r1[tid+st]; r2[tid] += r2[tid+st]; }
      __syncthreads();
    }
    if (tid == 0){
      double mean = r1[0] / (double)LL;
      double var  = (r2[0] - (double)LL * mean * mean) / (double)(LL - 1);
      if (var < 0.0) var = 0.0;
      double f = rint(sqrt(var) / (mean + 1e-6) * 10.0);
      if (f < 3.0) f = 3.0;
      if (f > 10.0) f = 10.0;
      ufac[b] = (int)f;
    }
    return;
  }
  int hh = blockIdx.x;
  const float* row = qsb + ((size_t)bloc * HH + hh) * LL;
  for (int l = tid; l < LL; l += 256) vals[l] = row[l];
  __syncthreads();
  for (int it = 0; it < UMAX; ++it){
    float best = -INFINITY; int bidx = 0;
    for (int l = tid; l < LL; l += 256){
      float v = vals[l];
      if (v > best){ best = v; bidx = l; }
    }
    bv[tid] = best; bi[tid] = bidx; __syncthreads();
    for (int st = 128; st; st >>= 1){
      if (tid < st){
        if (bv[tid+st] > bv[tid] || (bv[tid+st] == bv[tid] && bi[tid+st] < bi[tid])){
          bv[tid] = bv[tid+st]; bi[tid] = bi[tid+st];
        }
      }
      __syncthreads();
    }
    if (tid == 0){ topidx[(b * HH + hh) * UMAX + it] = bi[0]; vals[bi[0]] = -INFINITY; }
    __syncthreads();
  }
}

// ---------- attention pass 1 ----------
__global__ __launch_bounds__(256) void attn_p1_kernel(const float* __restrict__ qbuf,
    const ushort_t* __restrict__ kvbuf,
    const int* __restrict__ topidx, const int* __restrict__ ufac,
    float* __restrict__ part, int qtr, int lmin){
  const int bloc = blockIdx.z;
  const int b = qtr * NB + bloc;
  const int rowid = blockIdx.y;
  const int hh = rowid / UMAX, rank = rowid % UMAX;
  if (rank >= ufac[b]) return;
  const int qpos = topidx[(b * HH + hh) * UMAX + rank];
  if (qpos < lmin) return;

  const int tid = threadIdx.x, lane = tid & 63, wv = tid >> 6;
  const int base = blockIdx.x * LCHUNK + wv * (LCHUNK / 4);

  __shared__ float qrow[DKK];
  __shared__ float wm4[4], ws4[4];
  __shared__ float pvs[4][DKK];
  if (tid < DKK) qrow[tid] = qbuf[((size_t)bloc * LL + qpos) * DD + hh * DKK + tid];
  __syncthreads();

  const ushort_t* Kp = kvbuf + (size_t)bloc * LL * 1024 + hh * DKK;
  const ushort_t* Vp = Kp + 512;
  const float qv = qrow[lane];

  float sc[32];
  float mloc = -INFINITY;
#pragma unroll
  for (int i = 0; i < 32; ++i){
    float s = wsum(qv * bf2f(Kp[(size_t)(base + i) * 1024 + lane])) * 0.125f;
    sc[i] = s;
    mloc = fmaxf(mloc, s);
  }
  if (lane == 0) wm4[wv] = mloc;
  __syncthreads();
  const float M4 = fmaxf(fmaxf(wm4[0], wm4[1]), fmaxf(wm4[2], wm4[3]));

  float ssum = 0.f;
#pragma unroll
  for (int i = 0; i < 32; ++i){ float e = expf(sc[i] - M4); sc[i] = e; ssum += e; }

  float pv = 0.f;
#pragma unroll
  for (int i = 0; i < 32; ++i) pv += sc[i] * bf2f(Vp[(size_t)(base + i) * 1024 + lane]);

  pvs[wv][lane] = pv;
  if (lane == 0) ws4[wv] = ssum;
  __syncthreads();
  if (wv == 0){
    float* rec = part + (size_t)((bloc * HH * UMAX + rowid) * NSPLIT + blockIdx.x) * PSTRIDE;
    rec[lane] = pvs[0][lane] + pvs[1][lane] + pvs[2][lane] + pvs[3][lane];
    if (lane == 0){ rec[64] = M4; rec[65] = ws4[0] + ws4[1] + ws4[2] + ws4[3]; }
  }
}

// ---------- attention pass 2: combine + wo scatter ----------
__global__ __launch_bounds__(256) void attn_p2_kernel(const float* __restrict__ part,
    const float* __restrict__ wo, const int* __restrict__ topidx, const int* __restrict__ ufac,
    float* __restrict__ target, int qtr, int tailmode){
  const int bloc = blockIdx.y;
  const int b = qtr * NB + bloc;
  const int rowid = blockIdx.x;
  const int hh = rowid / UMAX, rank = rowid % UMAX;
  if (rank >= ufac[b]) return;
  const int qpos = topidx[(b * HH + hh) * UMAX + rank];
  size_t drow;
  if (tailmode){
    if (qpos < TAIL0) return;
    drow = (size_t)(b * OUTLEN + (qpos - TAIL0));
  } else {
    drow = (size_t)b * LL + qpos;
  }
  const int tid = threadIdx.x;
  const float* pbase = part + (size_t)(bloc * HH * UMAX + rowid) * NSPLIT * PSTRIDE;
  __shared__ float pm[NSPLIT], ps[NSPLIT];
  __shared__ float orow[DKK];
  if (tid < NSPLIT){
    pm[tid] = pbase[(size_t)tid * PSTRIDE + 64];
    ps[tid] = pbase[(size_t)tid * PSTRIDE + 65];
  }
  __syncthreads();
  float M = -INFINITY;
#pragma unroll
  for (int i = 0; i < NSPLIT; ++i) M = fmaxf(M, pm[i]);
  float S = 0.f;
#pragma unroll
  for (int i = 0; i < NSPLIT; ++i) S += ps[i] * expf(pm[i] - M);
  if (tid < DKK){
    float acc = 0.f;
#pragma unroll
    for (int i = 0; i < NSPLIT; ++i)
      acc += pbase[(size_t)i * PSTRIDE + tid] * expf(pm[i] - M);
    orow[tid] = acc / S;
  }
  __syncthreads();
  for (int j = tid; j < DD; j += 256){
    float a = 0.f;
#pragma unroll
    for (int dd = 0; dd < DKK; ++dd) a += orow[dd] * wo[(size_t)(hh * DKK + dd) * DD + j];
    atomicAdd(&target[drow * DD + j], a);
  }
}

// ---------- zero fill ----------
__global__ void zero_kernel(float* __restrict__ p, size_t n){
  size_t i = (size_t)blockIdx.x * 256 + threadIdx.x;
  size_t stride = (size_t)gridDim.x * 256;
  for (; i < n; i += stride) p[i] = 0.f;
}

// ---------- fused LN: O = LN(X [+Yadd] [+ Σ NPART partials] [+bias]) * g + bb ----------
// optional split-bf16 output (Oh/Ol) for feeding MFMA GEMMs.
template<int NPART, bool SPLITOUT>
__global__ __launch_bounds__(256) void ln_fused(const float* __restrict__ X,
    const float* __restrict__ Yadd, const float* __restrict__ P, size_t pstr,
    const float* __restrict__ bias, float* __restrict__ O,
    ushort_t* __restrict__ Oh, ushort_t* __restrict__ Ol,
    const float* __restrict__ g, const float* __restrict__ bb, int tailmapX){
  __shared__ float red[256];
  int r = blockIdx.x, tid = threadIdx.x;
  const float* xr;
  if (tailmapX){
    int b = r / OUTLEN;
    int l = TAIL0 + (r % OUTLEN);
    xr = X + ((size_t)b * LL + l) * DD;
  } else {
    xr = X + (size_t)r * DD;
  }
  float v0 = xr[tid];
  float v1 = xr[tid + 256];
  if (Yadd){
    v0 += Yadd[(size_t)r * DD + tid];
    v1 += Yadd[(size_t)r * DD + tid + 256];
  }
#pragma unroll
  for (int p = 0; p < NPART; ++p){
    v0 += P[(size_t)p * pstr + (size_t)r * DD + tid];
    v1 += P[(size_t)p * pstr + (size_t)r * DD + tid + 256];
  }
  if (bias){ v0 += bias[tid]; v1 += bias[tid + 256]; }
  red[tid] = v0 + v1; __syncthreads();
  for (int st = 128; st; st >>= 1){ if (tid < st) red[tid] += red[tid+st]; __syncthreads(); }
  float mu = red[0] * (1.0f / DD); __syncthreads();
  float d0 = v0 - mu, d1 = v1 - mu;
  red[tid] = d0*d0 + d1*d1; __syncthreads();
  for (int st = 128; st; st >>= 1){ if (tid < st) red[tid] += red[tid+st]; __syncthreads(); }
  float rstd = rsqrtf(red[0] * (1.0f / DD) + 1e-5f);
  float o0 = d0 * rstd * g[tid]       + bb[tid];
  float o1 = d1 * rstd * g[tid + 256] + bb[tid + 256];
  O[(size_t)r * DD + tid]       = o0;
  O[(size_t)r * DD + tid + 256] = o1;
  if (SPLITOUT){
    ushort_t hu, lu;
    split2(o0, hu, lu); Oh[(size_t)r * DD + tid] = hu;       Ol[(size_t)r * DD + tid] = lu;
    split2(o1, hu, lu); Oh[(size_t)r * DD + tid + 256] = hu; Ol[(size_t)r * DD + tid + 256] = lu;
  }
}

// ---------- final ----------
__global__ __launch_bounds__(64) void pred_kernel(const float* __restrict__ ht,
    const float* __restrict__ wout, const float* __restrict__ bout, float* __restrict__ out){
  int r = blockIdx.x, lane = threadIdx.x;
  float acc = 0.f;
  for (int dd = lane; dd < DD; dd += 64) acc += ht[(size_t)r * DD + dd] * wout[dd];
  acc = wsum(acc);
  if (lane == 0) out[r] = acc + bout[0];
}

extern "C" void kernel_launch(void* const* d_in, const int* in_sizes, int n_in,
                              void* d_out, int out_size, void* d_ws, size_t ws_size,
                              hipStream_t stream){
  const float* x    = (const float*)d_in[0];
  const float* wemb = (const float*)d_in[1];
  const float* bemb = (const float*)d_in[2];
  const float* wq   = (const float*)d_in[3];
  const float* bq   = (const float*)d_in[4];
  const float* wk   = (const float*)d_in[5];
  const float* bk   = (const float*)d_in[6];
  const float* wv   = (const float*)d_in[7];
  const float* bvv  = (const float*)d_in[8];
  const float* wo   = (const float*)d_in[9];
  const float* bo   = (const float*)d_in[10];
  const float* w1   = (const float*)d_in[11];
  const float* b1   = (const float*)d_in[12];
  const float* w2   = (const float*)d_in[13];
  const float* b2   = (const float*)d_in[14];
  const float* g1   = (const float*)d_in[15];
  const float* be1  = (const float*)d_in[16];
  const float* g2   = (const float*)d_in[17];
  const float* be2  = (const float*)d_in[18];
  const float* wout = (const float*)d_in[19];
  const float* bout = (const float*)d_in[20];
  float* out = (float*)d_out;
  char* wsb  = (char*)d_ws;

  const size_t PB = (size_t)LL * DD;
  const size_t MiB = 1024 * 1024;

  size_t o = 0;
  float* h = (float*)(wsb + o); o += (size_t)BB * PB * 4;                 // 128 MiB
  char*  arena = wsb + o;       o += 72 * MiB;                            // shared arena
  // QKV-phase layout:
  float*    qbuf  = (float*)arena;                       // QM*DD*4   = 32 MiB
  ushort_t* kvbuf = (ushort_t*)(arena + 32 * MiB);       // QM*1024*2 = 32 MiB
  // FFN-phase layout (overlays):
  ushort_t* ash  = (ushort_t*)arena;                     // CH*DD*2  = 4 MiB
  ushort_t* asl  = (ushort_t*)(arena + 4 * MiB);         // 4 MiB
  ushort_t* hidh = (ushort_t*)(arena + 8 * MiB);         // CH*DFF*2 = 16 MiB
  ushort_t* hidl = (ushort_t*)(arena + 24 * MiB);        // 16 MiB
  float*    pbuf = (float*)(arena + 40 * MiB);           // 4*CH*DD*4 = 32 MiB
  // weights + small buffers:
  ushort_t* wtqkvh = (ushort_t*)(wsb + o); o += (size_t)QKVN * DD * 2;
  ushort_t* wtqkvl = (ushort_t*)(wsb + o); o += (size_t)QKVN * DD * 2;
  ushort_t* w1th   = (ushort_t*)(wsb + o); o += (size_t)DFF * DD * 2;
  ushort_t* w1tl   = (ushort_t*)(wsb + o); o += (size_t)DFF * DD * 2;
  ushort_t* w2th   = (ushort_t*)(wsb + o); o += (size_t)DD * DFF * 2;
  ushort_t* w2tl   = (ushort_t*)(wsb + o); o += (size_t)DD * DFF * 2;
  float*    bqkv   = (float*)(wsb + o);  o += QKVN * 4;
  float*    qsb    = (float*)(wsb + o);  o += (size_t)NB * HH * LL * 4;
  float*    part   = (float*)(wsb + o);  o += (size_t)NB * HH * UMAX * NSPLIT * PSTRIDE * 4;
  float*    htail  = (float*)(wsb + o);  o += (size_t)NTAIL * DD * 4;
  float*    ftail  = (float*)(wsb + o);  o += (size_t)NTAIL * DD * 4;
  int*      topidx = (int*)(wsb + o);    o += (size_t)BB * HH * UMAX * 4;
  int*      ufac   = (int*)(wsb + o);    o += 64;
  // total ~221 MiB (<= 234 proven-safe)

  wqkv_prep_kernel<<<(QKVN*DD + 255)/256, 256, 0, stream>>>(wq, wk, wv, wtqkvh, wtqkvl);
  bqkv_prep_kernel<<<(QKVN + 255)/256, 256, 0, stream>>>(bq, bk, bvv, bqkv);
  wsplit_t_kernel<<<(DFF*DD + 255)/256, 256, 0, stream>>>(w1, w1th, w1tl, DD, DFF);
  wsplit_t_kernel<<<(DD*DFF + 255)/256, 256, 0, stream>>>(w2, w2th, w2tl, DFF, DD);

  embed_kernel<<<BB * LL, 256, 0, stream>>>(x, wemb, bemb, h);

  for (int layer = 0; layer < 2; ++layer){
    const bool tail = (layer == 1);
    if (tail) zero_kernel<<<512, 256, 0, stream>>>(ftail, (size_t)NTAIL * DD);

    for (int qtr = 0; qtr < BB / NB; ++qtr){
      const float* hq = h + (size_t)qtr * NB * PB;
      gemm_f32a<<<dim3(QKVN/128, QM/128), 256, 0, stream>>>(
          hq, wtqkvh, wtqkvl, bqkv, qbuf, kvbuf, DD);
      qs_kernel<<<(NB*HH*LL)/4, 256, 0, stream>>>(qbuf, qsb);
      select_kernel<<<dim3(9, NB), 256, 0, stream>>>(qsb, topidx, ufac, qtr);
      attn_p1_kernel<<<dim3(NSPLIT, HH*UMAX, NB), 256, 0, stream>>>(
          qbuf, kvbuf, topidx, ufac, part, qtr, tail ? TAIL0 : 0);
      attn_p2_kernel<<<dim3(HH*UMAX, NB), 256, 0, stream>>>(
          part, wo, topidx, ufac, tail ? ftail : h, qtr, tail ? 1 : 0);
    }

    if (!tail){
      for (int c = 0; c < (BB*LL)/CH; ++c){
        float* hc = h + (size_t)c * CH * DD;
        ln_fused<0, true><<<CH, 256, 0, stream>>>(
            hc, nullptr, nullptr, 0, bo, hc, ash, asl, g1, be1, 0);
        gemm_bf16<true, 1, 1><<<dim3(DFF/128, CH/128), 256, 0, stream>>>(
            ash, asl, w1th, w1tl, b1, nullptr, hidh, hidl, CH, DFF, DD, DFF, 0);
        gemm_bf16<false, 2, 4><<<dim3((DD/128)*4, CH/128), 256, 0, stream>>>(
            hidh, hidl, w2th, w2tl, nullptr, pbuf, nullptr, nullptr, CH, DD, DFF, DD, (size_t)CH*DD);
        ln_fused<4, false><<<CH, 256, 0, stream>>>(
            hc, nullptr, pbuf, (size_t)CH*DD, b2, hc, nullptr, nullptr, g2, be2, 0);
      }
    } else {
      ln_fused<0, true><<<NTAIL, 256, 0, stream>>>(
          h, ftail, nullptr, 0, bo, htail, ash, asl, g1, be1, 1);
      gemm_bf16<true, 1, 1><<<dim3(DFF/128, NTAIL/128), 256, 0, stream>>>(
          ash, asl, w1th, w1tl, b1, nullptr, hidh, hidl, NTAIL, DFF, DD, DFF, 0);
      gemm_bf16<false, 2, 4><<<dim3((DD/128)*4, NTAIL/128), 256, 0, stream>>>(
          hidh, hidl, w2th, w2tl, nullptr, pbuf, nullptr, nullptr, NTAIL, DD, DFF, DD, (size_t)NTAIL*DD);
      ln_fused<4, false><<<NTAIL, 256, 0, stream>>>(
          htail, nullptr, pbuf, (size_t)NTAIL*DD, b2, htail, nullptr, nullptr, g2, be2, 0);
      pred_kernel<<<NTAIL, 64, 0, stream>>>(htail, wout, bout, out);
    }
  }
  (void)in_sizes; (void)n_in; (void)out_size; (void)ws_size;
}

// Round 7
// 2583.135 us; speedup vs baseline: 6.6118x; 1.2269x over previous
//
#include <hip/hip_runtime.h>
#include <math.h>

#define BB 16
#define LL 4096
#define DIN 8
#define DD 512
#define HH 8
#define DKK 64
#define DFF 2048
#define OUTLEN 96
#define TAIL0 (LL - OUTLEN)   /* 4000 */
#define NTAIL (BB * OUTLEN)   /* 1536 */
#define UMAX 10
#define CH 8192               /* FFN row chunk */
#define QKVN 1536
#define NB 4                  /* batches per quarter */
#define QM (NB * LL)          /* 16384 rows per quarter */
#define NSPLIT 32
#define LCHUNK (LL / NSPLIT)  /* 128 */
#define PSTRIDE 68
#define MAXSLOT 128

typedef unsigned short ushort_t;
typedef unsigned int uint_t;
typedef short bf16x8 __attribute__((ext_vector_type(8)));
typedef float f32x4 __attribute__((ext_vector_type(4)));

#define GLD16(gp, lp) __builtin_amdgcn_global_load_lds((const __attribute__((address_space(1))) void*)(gp), (__attribute__((address_space(3))) void*)(lp), 16, 0, 0)

// ---------- helpers ----------
__device__ inline float wsum(float v){
#pragma unroll
  for (int o = 32; o > 0; o >>= 1) v += __shfl_xor(v, o);
  return v;
}
__device__ inline float wmax(float v){
#pragma unroll
  for (int o = 32; o > 0; o >>= 1) v = fmaxf(v, __shfl_xor(v, o));
  return v;
}
__device__ inline ushort_t f2bf_rtn(float f){
  uint_t u = __float_as_uint(f);
  uint_t r = u + 0x7FFF + ((u >> 16) & 1);
  return (ushort_t)(r >> 16);
}
__device__ inline float bf2f(ushort_t u){
  return __uint_as_float(((uint_t)u) << 16);
}
__device__ inline void split2(float x, ushort_t& hi, ushort_t& lo){
  uint_t u = __float_as_uint(x);
  hi = (ushort_t)(u >> 16);
  lo = f2bf_rtn(x - __uint_as_float(u & 0xFFFF0000u));
}

// ---------- embed: h(split) = x @ w_embed + b_embed ----------
__global__ __launch_bounds__(256) void embed_kernel(const float* __restrict__ x,
    const float* __restrict__ we, const float* __restrict__ be,
    ushort_t* __restrict__ hh, ushort_t* __restrict__ hl){
  int row = blockIdx.x;
  __shared__ float xs[DIN];
  if (threadIdx.x < DIN) xs[threadIdx.x] = x[(size_t)row * DIN + threadIdx.x];
  __syncthreads();
  for (int j = threadIdx.x; j < DD; j += 256){
    float acc = be[j];
#pragma unroll
    for (int i = 0; i < DIN; ++i) acc += xs[i] * we[i * DD + j];
    ushort_t hu, lu; split2(acc, hu, lu);
    hh[(size_t)row * DD + j] = hu;
    hl[(size_t)row * DD + j] = lu;
  }
}

// ---------- weight prep ----------
__global__ __launch_bounds__(256) void wsplit_t_kernel(const float* __restrict__ W,
    ushort_t* __restrict__ Th, ushort_t* __restrict__ Tl, int K, int N){
  int idx = blockIdx.x * 256 + threadIdx.x;
  if (idx >= N * K) return;
  int n = idx / K, k = idx - n * K;
  ushort_t hi, lo;
  split2(W[(size_t)k * N + n], hi, lo);
  Th[idx] = hi; Tl[idx] = lo;
}
__global__ __launch_bounds__(256) void wqkv_prep_kernel(const float* __restrict__ wq,
    const float* __restrict__ wk, const float* __restrict__ wv,
    ushort_t* __restrict__ Th, ushort_t* __restrict__ Tl){
  int idx = blockIdx.x * 256 + threadIdx.x;
  if (idx >= QKVN * DD) return;
  int n = idx >> 9, k = idx & (DD - 1);
  const float* src = (n < 512) ? wq : (n < 1024) ? wk : wv;
  ushort_t hi, lo;
  split2(src[(size_t)k * DD + (n & 511)], hi, lo);
  Th[idx] = hi; Tl[idx] = lo;
}
__global__ __launch_bounds__(256) void bqkv_prep_kernel(const float* __restrict__ bq,
    const float* __restrict__ bk, const float* __restrict__ bv, float* __restrict__ bo_){
  int n = blockIdx.x * 256 + threadIdx.x;
  if (n >= QKVN) return;
  bo_[n] = (n < 512) ? bq[n] : (n < 1024) ? bk[n - 512] : bv[n - 1024];
}

// ---------- QKV GEMM: A pre-split bf16, Q cols x3 -> fp32, KV cols x2 -> bf16 ----------
__global__ __launch_bounds__(256) void gemm_qkv(
    const ushort_t* __restrict__ Ah, const ushort_t* __restrict__ Al,
    const ushort_t* __restrict__ Bh, const ushort_t* __restrict__ Bl,
    const float* __restrict__ bias, float* __restrict__ Q,
    ushort_t* __restrict__ KV){
  __shared__ __align__(16) ushort_t AsH[128 * 32];
  __shared__ __align__(16) ushort_t AsL[128 * 32];
  __shared__ __align__(16) ushort_t BsH[128 * 32];
  __shared__ __align__(16) ushort_t BsL[128 * 32];
  const int tid  = threadIdx.x;
  const int lane = tid & 63;
  const int wv   = tid >> 6;
  const int m0   = blockIdx.y * 128;
  const int n0   = blockIdx.x * 128;
  const bool isQ = (n0 < 512);
  const int wm   = (wv & 1) * 64;
  const int wn   = (wv >> 1) * 64;

  const int rowA = tid >> 2;
  const int qe   = (tid & 3) * 8;
  const int lds0 = tid * 8;
  const int lds1 = (tid + 256) * 8;

  f32x4 acc[4][4];
#pragma unroll
  for (int i = 0; i < 4; ++i)
#pragma unroll
    for (int j = 0; j < 4; ++j) acc[i][j] = (f32x4){0.f, 0.f, 0.f, 0.f};

  const int arow = lane & 15;
  const int koff = (lane >> 4) * 8;
  const int K = DD;

  for (int k0 = 0; k0 < K; k0 += 32){
    const size_t ga0 = (size_t)(m0 + rowA) * K + k0 + qe;
    const size_t ga1 = (size_t)(m0 + rowA + 64) * K + k0 + qe;
    const size_t gb0 = (size_t)(n0 + rowA) * K + k0 + qe;
    const size_t gb1 = (size_t)(n0 + rowA + 64) * K + k0 + qe;
    GLD16(Ah + ga0, &AsH[lds0]);  GLD16(Ah + ga1, &AsH[lds1]);
    GLD16(Al + ga0, &AsL[lds0]);  GLD16(Al + ga1, &AsL[lds1]);
    GLD16(Bh + gb0, &BsH[lds0]);  GLD16(Bh + gb1, &BsH[lds1]);
    if (isQ){ GLD16(Bl + gb0, &BsL[lds0]);  GLD16(Bl + gb1, &BsL[lds1]); }
    __syncthreads();

    bf16x8 ah[4], al[4], bh[4], bl[4];
#pragma unroll
    for (int i = 0; i < 4; ++i){
      ah[i] = *(const bf16x8*)&AsH[(wm + i * 16 + arow) * 32 + koff];
      al[i] = *(const bf16x8*)&AsL[(wm + i * 16 + arow) * 32 + koff];
      bh[i] = *(const bf16x8*)&BsH[(wn + i * 16 + arow) * 32 + koff];
      if (isQ) bl[i] = *(const bf16x8*)&BsL[(wn + i * 16 + arow) * 32 + koff];
    }
#pragma unroll
    for (int i = 0; i < 4; ++i)
#pragma unroll
      for (int j = 0; j < 4; ++j){
        acc[i][j] = __builtin_amdgcn_mfma_f32_16x16x32_bf16(ah[i], bh[j], acc[i][j], 0, 0, 0);
        acc[i][j] = __builtin_amdgcn_mfma_f32_16x16x32_bf16(al[i], bh[j], acc[i][j], 0, 0, 0);
        if (isQ)
          acc[i][j] = __builtin_amdgcn_mfma_f32_16x16x32_bf16(ah[i], bl[j], acc[i][j], 0, 0, 0);
      }
    __syncthreads();
  }

  const int crow = (lane >> 4) * 4;
  const int ccol = lane & 15;
#pragma unroll
  for (int i = 0; i < 4; ++i){
    const int gr0 = m0 + wm + i * 16 + crow;
#pragma unroll
    for (int j = 0; j < 4; ++j){
      const int gc = n0 + wn + j * 16 + ccol;
      const float bvv = bias[gc];
#pragma unroll
      for (int r = 0; r < 4; ++r){
        float v = acc[i][j][r] + bvv;
        const int gr = gr0 + r;
        if (isQ) Q[(size_t)gr * 512 + gc] = v;
        else     KV[(size_t)gr * 1024 + (gc - 512)] = f2bf_rtn(v);
      }
    }
  }
}

// ---------- FFN1: A split bf16, B=w1 hi only (x2), out = relu bf16 ----------
__global__ __launch_bounds__(256) void gemm_ffn1(
    const ushort_t* __restrict__ Ah, const ushort_t* __restrict__ Al,
    const ushort_t* __restrict__ Bh, const float* __restrict__ bias,
    ushort_t* __restrict__ Chid){
  __shared__ __align__(16) ushort_t AsH[128 * 32];
  __shared__ __align__(16) ushort_t AsL[128 * 32];
  __shared__ __align__(16) ushort_t BsH[128 * 32];
  const int tid  = threadIdx.x;
  const int lane = tid & 63;
  const int wv   = tid >> 6;
  const int m0   = blockIdx.y * 128;
  const int n0   = blockIdx.x * 128;
  const int wm   = (wv & 1) * 64;
  const int wn   = (wv >> 1) * 64;
  const int rowA = tid >> 2;
  const int qe   = (tid & 3) * 8;
  const int lds0 = tid * 8;
  const int lds1 = (tid + 256) * 8;

  f32x4 acc[4][4];
#pragma unroll
  for (int i = 0; i < 4; ++i)
#pragma unroll
    for (int j = 0; j < 4; ++j) acc[i][j] = (f32x4){0.f, 0.f, 0.f, 0.f};

  const int arow = lane & 15;
  const int koff = (lane >> 4) * 8;
  const int K = DD;

  for (int k0 = 0; k0 < K; k0 += 32){
    const size_t ga0 = (size_t)(m0 + rowA) * K + k0 + qe;
    const size_t ga1 = (size_t)(m0 + rowA + 64) * K + k0 + qe;
    const size_t gb0 = (size_t)(n0 + rowA) * K + k0 + qe;
    const size_t gb1 = (size_t)(n0 + rowA + 64) * K + k0 + qe;
    GLD16(Ah + ga0, &AsH[lds0]);  GLD16(Ah + ga1, &AsH[lds1]);
    GLD16(Al + ga0, &AsL[lds0]);  GLD16(Al + ga1, &AsL[lds1]);
    GLD16(Bh + gb0, &BsH[lds0]);  GLD16(Bh + gb1, &BsH[lds1]);
    __syncthreads();

    bf16x8 ah[4], al[4], bh[4];
#pragma unroll
    for (int i = 0; i < 4; ++i){
      ah[i] = *(const bf16x8*)&AsH[(wm + i * 16 + arow) * 32 + koff];
      al[i] = *(const bf16x8*)&AsL[(wm + i * 16 + arow) * 32 + koff];
      bh[i] = *(const bf16x8*)&BsH[(wn + i * 16 + arow) * 32 + koff];
    }
#pragma unroll
    for (int i = 0; i < 4; ++i)
#pragma unroll
      for (int j = 0; j < 4; ++j){
        acc[i][j] = __builtin_amdgcn_mfma_f32_16x16x32_bf16(ah[i], bh[j], acc[i][j], 0, 0, 0);
        acc[i][j] = __builtin_amdgcn_mfma_f32_16x16x32_bf16(al[i], bh[j], acc[i][j], 0, 0, 0);
      }
    __syncthreads();
  }

  const int crow = (lane >> 4) * 4;
  const int ccol = lane & 15;
#pragma unroll
  for (int i = 0; i < 4; ++i){
    const int gr0 = m0 + wm + i * 16 + crow;
#pragma unroll
    for (int j = 0; j < 4; ++j){
      const int gc = n0 + wn + j * 16 + ccol;
      const float bvv = bias[gc];
#pragma unroll
      for (int r = 0; r < 4; ++r){
        float v = fmaxf(acc[i][j][r] + bvv, 0.f);
        Chid[(size_t)(gr0 + r) * DFF + gc] = f2bf_rtn(v);
      }
    }
  }
}

// ---------- FFN2: A single bf16 (hid), B=w2 split (x2), split-K=2 partial fp32 out ----------
__global__ __launch_bounds__(256) void gemm_ffn2(
    const ushort_t* __restrict__ Ahid,
    const ushort_t* __restrict__ Bh, const ushort_t* __restrict__ Bl,
    float* __restrict__ pbuf, size_t pstr){
  __shared__ __align__(16) ushort_t AsH[128 * 32];
  __shared__ __align__(16) ushort_t BsH[128 * 32];
  __shared__ __align__(16) ushort_t BsL[128 * 32];
  const int tid  = threadIdx.x;
  const int lane = tid & 63;
  const int wv   = tid >> 6;
  const int nblk = (int)blockIdx.x >> 1;
  const int kq   = (int)blockIdx.x & 1;
  const int m0   = blockIdx.y * 128;
  const int n0   = nblk * 128;
  const int wm   = (wv & 1) * 64;
  const int wn   = (wv >> 1) * 64;
  const int rowA = tid >> 2;
  const int qe   = (tid & 3) * 8;
  const int lds0 = tid * 8;
  const int lds1 = (tid + 256) * 8;

  f32x4 acc[4][4];
#pragma unroll
  for (int i = 0; i < 4; ++i)
#pragma unroll
    for (int j = 0; j < 4; ++j) acc[i][j] = (f32x4){0.f, 0.f, 0.f, 0.f};

  const int arow = lane & 15;
  const int koff = (lane >> 4) * 8;
  const int K = DFF;
  const int kper = K / 2;
  const int kbeg = kq * kper;

  for (int k0 = kbeg; k0 < kbeg + kper; k0 += 32){
    const size_t ga0 = (size_t)(m0 + rowA) * K + k0 + qe;
    const size_t ga1 = (size_t)(m0 + rowA + 64) * K + k0 + qe;
    const size_t gb0 = (size_t)(n0 + rowA) * K + k0 + qe;
    const size_t gb1 = (size_t)(n0 + rowA + 64) * K + k0 + qe;
    GLD16(Ahid + ga0, &AsH[lds0]);  GLD16(Ahid + ga1, &AsH[lds1]);
    GLD16(Bh + gb0, &BsH[lds0]);    GLD16(Bh + gb1, &BsH[lds1]);
    GLD16(Bl + gb0, &BsL[lds0]);    GLD16(Bl + gb1, &BsL[lds1]);
    __syncthreads();

    bf16x8 ah[4], bh[4], bl[4];
#pragma unroll
    for (int i = 0; i < 4; ++i){
      ah[i] = *(const bf16x8*)&AsH[(wm + i * 16 + arow) * 32 + koff];
      bh[i] = *(const bf16x8*)&BsH[(wn + i * 16 + arow) * 32 + koff];
      bl[i] = *(const bf16x8*)&BsL[(wn + i * 16 + arow) * 32 + koff];
    }
#pragma unroll
    for (int i = 0; i < 4; ++i)
#pragma unroll
      for (int j = 0; j < 4; ++j){
        acc[i][j] = __builtin_amdgcn_mfma_f32_16x16x32_bf16(ah[i], bh[j], acc[i][j], 0, 0, 0);
        acc[i][j] = __builtin_amdgcn_mfma_f32_16x16x32_bf16(ah[i], bl[j], acc[i][j], 0, 0, 0);
      }
    __syncthreads();
  }

  const int crow = (lane >> 4) * 4;
  const int ccol = lane & 15;
#pragma unroll
  for (int i = 0; i < 4; ++i){
    const int gr0 = m0 + wm + i * 16 + crow;
#pragma unroll
    for (int j = 0; j < 4; ++j){
      const int gc = n0 + wn + j * 16 + ccol;
#pragma unroll
      for (int r = 0; r < 4; ++r)
        pbuf[(size_t)kq * pstr + (size_t)(gr0 + r) * DD + gc] = acc[i][j][r];
    }
  }
}

// ---------- qs scoring, one quarter ----------
__global__ __launch_bounds__(256) void qs_kernel(const float* __restrict__ qbuf, float* __restrict__ qsb){
  int tid = threadIdx.x;
  int lane = tid & 63;
  int wv = tid >> 6;
  int rid = blockIdx.x * 4 + wv;
  int bloc = rid >> 15;
  int hh = (rid >> 12) & 7;
  int l  = rid & (LL - 1);
  float qv = qbuf[((size_t)bloc * LL + l) * DD + hh * DKK + lane];
  float l2 = sqrtf(wsum(qv * qv));
  float mx = wmax(qv);
  float e  = expf(qv - mx);
  float se = wsum(e);
  float p  = e / se;
  float ent = -wsum(p * logf(p + 1e-9f));
  float mu  = wsum(qv) * (1.0f / 64.0f);
  float dv  = qv - mu;
  float var = wsum(dv * dv) * (1.0f / 63.0f);
  float val = 0.5f * l2 + 0.3f * ent + 0.2f * var;
  if (lane == 0) qsb[(size_t)(bloc * HH + hh) * LL + l] = val;
}

// ---------- selection ----------
__global__ __launch_bounds__(256) void select_kernel(const float* __restrict__ qsb,
    int* __restrict__ topidx, int* __restrict__ ufac, int qtr){
  __shared__ float vals[LL];
  __shared__ float bv[256];
  __shared__ int   bi[256];
  __shared__ double r1[256], r2[256];
  const int bloc = blockIdx.y;
  const int b = qtr * NB + bloc;
  int tid = threadIdx.x;
  if (blockIdx.x == 8){
    const float* row = qsb + (size_t)bloc * HH * LL;
    double s = 0.0, s2 = 0.0;
    for (int l = tid; l < LL; l += 256){ double v = row[l]; s += v; s2 += v * v; }
    r1[tid] = s; r2[tid] = s2; __syncthreads();
    for (int st = 128; st; st >>= 1){
      if (tid < st){ r1[tid] += r1[tid+st]; r2[tid] += r2[tid+st]; }
      __syncthreads();
    }
    if (tid == 0){
      double mean = r1[0] / (double)LL;
      double var  = (r2[0] - (double)LL * mean * mean) / (double)(LL - 1);
      if (var < 0.0) var = 0.0;
      double f = rint(sqrt(var) / (mean + 1e-6) * 10.0);
      if (f < 3.0) f = 3.0;
      if (f > 10.0) f = 10.0;
      ufac[b] = (int)f;
    }
    return;
  }
  int hh = blockIdx.x;
  const float* row = qsb + ((size_t)bloc * HH + hh) * LL;
  for (int l = tid; l < LL; l += 256) vals[l] = row[l];
  __syncthreads();
  for (int it = 0; it < UMAX; ++it){
    float best = -INFINITY; int bidx = 0;
    for (int l = tid; l < LL; l += 256){
      float v = vals[l];
      if (v > best){ best = v; bidx = l; }
    }
    bv[tid] = best; bi[tid] = bidx; __syncthreads();
    for (int st = 128; st; st >>= 1){
      if (tid < st){
        if (bv[tid+st] > bv[tid] || (bv[tid+st] == bv[tid] && bi[tid+st] < bi[tid])){
          bv[tid] = bv[tid+st]; bi[tid] = bi[tid+st];
        }
      }
      __syncthreads();
    }
    if (tid == 0){ topidx[(b * HH + hh) * UMAX + it] = bi[0]; vals[bi[0]] = -INFINITY; }
    __syncthreads();
  }
}

// ---------- slot init / build ----------
__global__ void initslot_kernel(int* __restrict__ slotmap, int* __restrict__ scount){
  int i = blockIdx.x * 256 + threadIdx.x;
  if (i < BB * LL) slotmap[i] = -1;
  if (i < BB) scount[i] = 0;
}
__global__ __launch_bounds__(128) void slotbuild_kernel(const int* __restrict__ topidx,
    const int* __restrict__ ufac, int* __restrict__ slotmap, int* __restrict__ scount, int qtr){
  int t = threadIdx.x;
  int b = qtr * NB + blockIdx.x;
  if (t >= HH * UMAX) return;
  int hh = t / UMAX, rank = t % UMAX;
  if (rank >= ufac[b]) return;
  int qpos = topidx[(b * HH + hh) * UMAX + rank];
  int* cell = &slotmap[b * LL + qpos];
  int old = atomicCAS(cell, -1, -2);
  if (old == -1){
    int s = atomicAdd(&scount[b], 1);
    atomicExch(cell, s);
  }
}

// ---------- attention pass 1 ----------
__global__ __launch_bounds__(256) void attn_p1_kernel(const float* __restrict__ qbuf,
    const ushort_t* __restrict__ kvbuf,
    const int* __restrict__ topidx, const int* __restrict__ ufac,
    float* __restrict__ part, int qtr, int lmin){
  const int bloc = blockIdx.z;
  const int b = qtr * NB + bloc;
  const int rowid = blockIdx.y;
  const int hh = rowid / UMAX, rank = rowid % UMAX;
  if (rank >= ufac[b]) return;
  const int qpos = topidx[(b * HH + hh) * UMAX + rank];
  if (qpos < lmin) return;

  const int tid = threadIdx.x, lane = tid & 63, wv = tid >> 6;
  const int base = blockIdx.x * LCHUNK + wv * (LCHUNK / 4);

  __shared__ float qrow[DKK];
  __shared__ float wm4[4], ws4[4];
  __shared__ float pvs[4][DKK];
  if (tid < DKK) qrow[tid] = qbuf[((size_t)bloc * LL + qpos) * DD + hh * DKK + tid];
  __syncthreads();

  const ushort_t* Kp = kvbuf + (size_t)bloc * LL * 1024 + hh * DKK;
  const ushort_t* Vp = Kp + 512;
  const float qv = qrow[lane];

  float sc[32];
  float mloc = -INFINITY;
#pragma unroll
  for (int i = 0; i < 32; ++i){
    float s = wsum(qv * bf2f(Kp[(size_t)(base + i) * 1024 + lane])) * 0.125f;
    sc[i] = s;
    mloc = fmaxf(mloc, s);
  }
  if (lane == 0) wm4[wv] = mloc;
  __syncthreads();
  const float M4 = fmaxf(fmaxf(wm4[0], wm4[1]), fmaxf(wm4[2], wm4[3]));

  float ssum = 0.f;
#pragma unroll
  for (int i = 0; i < 32; ++i){ float e = expf(sc[i] - M4); sc[i] = e; ssum += e; }

  float pv = 0.f;
#pragma unroll
  for (int i = 0; i < 32; ++i) pv += sc[i] * bf2f(Vp[(size_t)(base + i) * 1024 + lane]);

  pvs[wv][lane] = pv;
  if (lane == 0) ws4[wv] = ssum;
  __syncthreads();
  if (wv == 0){
    float* rec = part + (size_t)((bloc * HH * UMAX + rowid) * NSPLIT + blockIdx.x) * PSTRIDE;
    rec[lane] = pvs[0][lane] + pvs[1][lane] + pvs[2][lane] + pvs[3][lane];
    if (lane == 0){ rec[64] = M4; rec[65] = ws4[0] + ws4[1] + ws4[2] + ws4[3]; }
  }
}

// ---------- attention pass 2: combine + wo projection -> adelta ----------
__global__ __launch_bounds__(256) void attn_p2_kernel(const float* __restrict__ part,
    const float* __restrict__ wo, const int* __restrict__ topidx, const int* __restrict__ ufac,
    const int* __restrict__ slotmap, float* __restrict__ adelta, int qtr, int lmin){
  const int bloc = blockIdx.y;
  const int b = qtr * NB + bloc;
  const int rowid = blockIdx.x;
  const int hh = rowid / UMAX, rank = rowid % UMAX;
  if (rank >= ufac[b]) return;
  const int qpos = topidx[(b * HH + hh) * UMAX + rank];
  if (qpos < lmin) return;
  const int slot = slotmap[b * LL + qpos];

  const int tid = threadIdx.x;
  const float* pbase = part + (size_t)(bloc * HH * UMAX + rowid) * NSPLIT * PSTRIDE;
  __shared__ float pm[NSPLIT], ps[NSPLIT];
  __shared__ float orow[DKK];
  if (tid < NSPLIT){
    pm[tid] = pbase[(size_t)tid * PSTRIDE + 64];
    ps[tid] = pbase[(size_t)tid * PSTRIDE + 65];
  }
  __syncthreads();
  float M = -INFINITY;
#pragma unroll
  for (int i = 0; i < NSPLIT; ++i) M = fmaxf(M, pm[i]);
  float S = 0.f;
#pragma unroll
  for (int i = 0; i < NSPLIT; ++i) S += ps[i] * expf(pm[i] - M);
  if (tid < DKK){
    float acc = 0.f;
#pragma unroll
    for (int i = 0; i < NSPLIT; ++i)
      acc += pbase[(size_t)i * PSTRIDE + tid] * expf(pm[i] - M);
    orow[tid] = acc / S;
  }
  __syncthreads();
  float* drow = adelta + ((size_t)b * MAXSLOT + slot) * DD;
  for (int j = tid; j < DD; j += 256){
    float a = 0.f;
#pragma unroll
    for (int dd = 0; dd < DKK; ++dd) a += orow[dd] * wo[(size_t)(hh * DKK + dd) * DD + j];
    atomicAdd(&drow[j], a);
  }
}

// ---------- zero fill ----------
__global__ void zero_kernel(float* __restrict__ p, size_t n){
  size_t i = (size_t)blockIdx.x * 256 + threadIdx.x;
  size_t stride = (size_t)gridDim.x * 256;
  for (; i < n; i += stride) p[i] = 0.f;
}

// ---------- LN1: out = LN(h + bo + adelta[slot]) (split out) ----------
template<bool TAIL>
__global__ __launch_bounds__(256) void ln1_kernel(
    const ushort_t* __restrict__ hh_, const ushort_t* __restrict__ hl_,
    const float* __restrict__ bo,
    const int* __restrict__ slotmap, const float* __restrict__ adelta,
    ushort_t* __restrict__ oh, ushort_t* __restrict__ ol,
    const float* __restrict__ g, const float* __restrict__ bb){
  __shared__ float red[256];
  int r = blockIdx.x, tid = threadIdx.x;
  int b, l;
  if (TAIL){ b = r / OUTLEN; l = TAIL0 + (r % OUTLEN); }
  else     { b = r >> 12;    l = r & (LL - 1); }
  const size_t gi = ((size_t)b * LL + l) * DD;
  float v0 = bf2f(hh_[gi + tid])       + bf2f(hl_[gi + tid])       + bo[tid];
  float v1 = bf2f(hh_[gi + tid + 256]) + bf2f(hl_[gi + tid + 256]) + bo[tid + 256];
  int s = slotmap[b * LL + l];
  if (s >= 0){
    const float* dr = adelta + ((size_t)b * MAXSLOT + s) * DD;
    v0 += dr[tid]; v1 += dr[tid + 256];
  }
  red[tid] = v0 + v1; __syncthreads();
  for (int st = 128; st; st >>= 1){ if (tid < st) red[tid] += red[tid+st]; __syncthreads(); }
  float mu = red[0] * (1.0f / DD); __syncthreads();
  float d0 = v0 - mu, d1 = v1 - mu;
  red[tid] = d0*d0 + d1*d1; __syncthreads();
  for (int st = 128; st; st >>= 1){ if (tid < st) red[tid] += red[tid+st]; __syncthreads(); }
  float rstd = rsqrtf(red[0] * (1.0f / DD) + 1e-5f);
  float o0 = d0 * rstd * g[tid]       + bb[tid];
  float o1 = d1 * rstd * g[tid + 256] + bb[tid + 256];
  const size_t oo = TAIL ? (size_t)r * DD : gi;
  ushort_t hu, lu;
  split2(o0, hu, lu); oh[oo + tid] = hu;       ol[oo + tid] = lu;
  split2(o1, hu, lu); oh[oo + tid + 256] = hu; ol[oo + tid + 256] = lu;
}

// ---------- LN2: out = LN(ln1out + p0 + p1 + b2) ----------
template<bool TAIL>
__global__ __launch_bounds__(256) void ln2_kernel(
    const ushort_t* __restrict__ ih, const ushort_t* __restrict__ il,
    const float* __restrict__ pbuf, size_t pstr, const float* __restrict__ b2,
    ushort_t* __restrict__ oh, ushort_t* __restrict__ ol, float* __restrict__ ofp,
    const float* __restrict__ g, const float* __restrict__ bb, size_t rowoff){
  __shared__ float red[256];
  int r = blockIdx.x, tid = threadIdx.x;
  const size_t gi = (rowoff + r) * DD;
  const size_t pi = (size_t)r * DD;
  float v0 = bf2f(ih[gi + tid]) + bf2f(il[gi + tid])
           + pbuf[pi + tid] + pbuf[pstr + pi + tid] + b2[tid];
  float v1 = bf2f(ih[gi + tid + 256]) + bf2f(il[gi + tid + 256])
           + pbuf[pi + tid + 256] + pbuf[pstr + pi + tid + 256] + b2[tid + 256];
  red[tid] = v0 + v1; __syncthreads();
  for (int st = 128; st; st >>= 1){ if (tid < st) red[tid] += red[tid+st]; __syncthreads(); }
  float mu = red[0] * (1.0f / DD); __syncthreads();
  float d0 = v0 - mu, d1 = v1 - mu;
  red[tid] = d0*d0 + d1*d1; __syncthreads();
  for (int st = 128; st; st >>= 1){ if (tid < st) red[tid] += red[tid+st]; __syncthreads(); }
  float rstd = rsqrtf(red[0] * (1.0f / DD) + 1e-5f);
  float o0 = d0 * rstd * g[tid]       + bb[tid];
  float o1 = d1 * rstd * g[tid + 256] + bb[tid + 256];
  if (TAIL){
    ofp[pi + tid] = o0; ofp[pi + tid + 256] = o1;
  } else {
    ushort_t hu, lu;
    split2(o0, hu, lu); oh[gi + tid] = hu;       ol[gi + tid] = lu;
    split2(o1, hu, lu); oh[gi + tid + 256] = hu; ol[gi + tid + 256] = lu;
  }
}

// ---------- final ----------
__global__ __launch_bounds__(64) void pred_kernel(const float* __restrict__ ht,
    const float* __restrict__ wout, const float* __restrict__ bout, float* __restrict__ out){
  int r = blockIdx.x, lane = threadIdx.x;
  float acc = 0.f;
  for (int dd = lane; dd < DD; dd += 64) acc += ht[(size_t)r * DD + dd] * wout[dd];
  acc = wsum(acc);
  if (lane == 0) out[r] = acc + bout[0];
}

extern "C" void kernel_launch(void* const* d_in, const int* in_sizes, int n_in,
                              void* d_out, int out_size, void* d_ws, size_t ws_size,
                              hipStream_t stream){
  const float* x    = (const float*)d_in[0];
  const float* wemb = (const float*)d_in[1];
  const float* bemb = (const float*)d_in[2];
  const float* wq   = (const float*)d_in[3];
  const float* bq   = (const float*)d_in[4];
  const float* wk   = (const float*)d_in[5];
  const float* bk   = (const float*)d_in[6];
  const float* wv   = (const float*)d_in[7];
  const float* bvv  = (const float*)d_in[8];
  const float* wo   = (const float*)d_in[9];
  const float* bo   = (const float*)d_in[10];
  const float* w1   = (const float*)d_in[11];
  const float* b1   = (const float*)d_in[12];
  const float* w2   = (const float*)d_in[13];
  const float* b2   = (const float*)d_in[14];
  const float* g1   = (const float*)d_in[15];
  const float* be1  = (const float*)d_in[16];
  const float* g2   = (const float*)d_in[17];
  const float* be2  = (const float*)d_in[18];
  const float* wout = (const float*)d_in[19];
  const float* bout = (const float*)d_in[20];
  float* out = (float*)d_out;
  char* wsb  = (char*)d_ws;

  const size_t MiB = 1024 * 1024;
  const size_t NE  = (size_t)BB * LL * DD;   // 33.5M elems

  size_t o = 0;
  ushort_t* hh    = (ushort_t*)(wsb + o); o += NE * 2;          // 64 MiB
  ushort_t* hl    = (ushort_t*)(wsb + o); o += NE * 2;          // 64 MiB
  char*     arena = wsb + o;              o += 64 * MiB;        // shared arena
  // QKV phase:
  float*    qbuf  = (float*)arena;                              // QM*512*4 = 32 MiB
  ushort_t* kvbuf = (ushort_t*)(arena + 32 * MiB);              // QM*1024*2 = 32 MiB
  // FFN phase (overlay): layer-1
  ushort_t* hid   = (ushort_t*)arena;                           // CH*DFF*2 = 32 MiB
  float*    pbuf  = (float*)(arena + 32 * MiB);                 // 2*CH*512*4 = 32 MiB
  // FFN phase tail overlay
  ushort_t* hidt  = (ushort_t*)arena;                           // NTAIL*DFF*2 = 6 MiB
  float*    pbuft = (float*)(arena + 32 * MiB);                 // 2*NTAIL*512*4 = 6 MiB
  ushort_t* asht  = (ushort_t*)(arena + 48 * MiB);              // NTAIL*512*2 = 1.5 MiB
  ushort_t* aslt  = (ushort_t*)(arena + 50 * MiB);              // 1.5 MiB
  // weights + small:
  ushort_t* wtqkvh = (ushort_t*)(wsb + o); o += (size_t)QKVN * DD * 2;
  ushort_t* wtqkvl = (ushort_t*)(wsb + o); o += (size_t)QKVN * DD * 2;
  ushort_t* w1th   = (ushort_t*)(wsb + o); o += (size_t)DFF * DD * 2;
  ushort_t* w2th   = (ushort_t*)(wsb + o); o += (size_t)DD * DFF * 2;
  ushort_t* w2tl   = (ushort_t*)(wsb + o); o += (size_t)DD * DFF * 2;
  ushort_t* w1tl   = (ushort_t*)(wsb + o); o += (size_t)DFF * DD * 2;  // written, unused
  float*    bqkv   = (float*)(wsb + o);  o += QKVN * 4;
  float*    qsb    = (float*)(wsb + o);  o += (size_t)NB * HH * LL * 4;
  float*    part   = (float*)(wsb + o);  o += (size_t)NB * HH * UMAX * NSPLIT * PSTRIDE * 4;
  float*    adelta = (float*)(wsb + o);  o += (size_t)BB * MAXSLOT * DD * 4;   // 4 MiB
  float*    htail  = (float*)(wsb + o);  o += (size_t)NTAIL * DD * 4;          // 3 MiB
  int*      slotmap= (int*)(wsb + o);    o += (size_t)BB * LL * 4;             // 256 KiB
  int*      scount = (int*)(wsb + o);    o += BB * 4;
  int*      topidx = (int*)(wsb + o);    o += (size_t)BB * HH * UMAX * 4;
  int*      ufac   = (int*)(wsb + o);    o += 64;
  // total ~215 MiB (<= 234 proven-safe)

  wqkv_prep_kernel<<<(QKVN*DD + 255)/256, 256, 0, stream>>>(wq, wk, wv, wtqkvh, wtqkvl);
  bqkv_prep_kernel<<<(QKVN + 255)/256, 256, 0, stream>>>(bq, bk, bvv, bqkv);
  wsplit_t_kernel<<<(DFF*DD + 255)/256, 256, 0, stream>>>(w1, w1th, w1tl, DD, DFF);
  wsplit_t_kernel<<<(DD*DFF + 255)/256, 256, 0, stream>>>(w2, w2th, w2tl, DFF, DD);

  embed_kernel<<<BB * LL, 256, 0, stream>>>(x, wemb, bemb, hh, hl);

  for (int layer = 0; layer < 2; ++layer){
    const bool tail = (layer == 1);
    const int lmin = tail ? TAIL0 : 0;

    initslot_kernel<<<(BB*LL + 255)/256, 256, 0, stream>>>(slotmap, scount);
    zero_kernel<<<1024, 256, 0, stream>>>(adelta, (size_t)BB * MAXSLOT * DD);

    for (int qtr = 0; qtr < BB / NB; ++qtr){
      const size_t hoff = (size_t)qtr * QM * DD;
      gemm_qkv<<<dim3(QKVN/128, QM/128), 256, 0, stream>>>(
          hh + hoff, hl + hoff, wtqkvh, wtqkvl, bqkv, qbuf, kvbuf);
      qs_kernel<<<(NB*HH*LL)/4, 256, 0, stream>>>(qbuf, qsb);
      select_kernel<<<dim3(9, NB), 256, 0, stream>>>(qsb, topidx, ufac, qtr);
      slotbuild_kernel<<<NB, 128, 0, stream>>>(topidx, ufac, slotmap, scount, qtr);
      attn_p1_kernel<<<dim3(NSPLIT, HH*UMAX, NB), 256, 0, stream>>>(
          qbuf, kvbuf, topidx, ufac, part, qtr, lmin);
      attn_p2_kernel<<<dim3(HH*UMAX, NB), 256, 0, stream>>>(
          part, wo, topidx, ufac, slotmap, adelta, qtr, lmin);
    }

    if (!tail){
      ln1_kernel<false><<<BB*LL, 256, 0, stream>>>(hh, hl, bo, slotmap, adelta, hh, hl, g1, be1);
      for (int c = 0; c < (BB*LL)/CH; ++c){
        const size_t roff = (size_t)c * CH;
        gemm_ffn1<<<dim3(DFF/128, CH/128), 256, 0, stream>>>(
            hh + roff * DD, hl + roff * DD, w1th, b1, hid);
        gemm_ffn2<<<dim3(8, CH/128), 256, 0, stream>>>(hid, w2th, w2tl, pbuf, (size_t)CH * DD);
        ln2_kernel<false><<<CH, 256, 0, stream>>>(
            hh, hl, pbuf, (size_t)CH * DD, b2, hh, hl, nullptr, g2, be2, roff);
      }
    } else {
      ln1_kernel<true><<<NTAIL, 256, 0, stream>>>(hh, hl, bo, slotmap, adelta, asht, aslt, g1, be1);
      gemm_ffn1<<<dim3(DFF/128, NTAIL/128), 256, 0, stream>>>(asht, aslt, w1th, b1, hidt);
      gemm_ffn2<<<dim3(8, NTAIL/128), 256, 0, stream>>>(hidt, w2th, w2tl, pbuft, (size_t)NTAIL * DD);
      ln2_kernel<true><<<NTAIL, 256, 0, stream>>>(
          asht, aslt, pbuft, (size_t)NTAIL * DD, b2, nullptr, nullptr, htail, g2, be2, 0);
      pred_kernel<<<NTAIL, 64, 0, stream>>>(htail, wout, bout, out);
    }
  }
  (void)in_sizes; (void)n_in; (void)out_size; (void)ws_size;
}

// Round 8
// 2549.433 us; speedup vs baseline: 6.6993x; 1.0132x over previous
//
#include <hip/hip_runtime.h>
#include <math.h>

#define BB 16
#define LL 4096
#define DIN 8
#define DD 512
#define HH 8
#define DKK 64
#define DFF 2048
#define OUTLEN 96
#define TAIL0 (LL - OUTLEN)   /* 4000 */
#define NTAIL (BB * OUTLEN)   /* 1536 */
#define UMAX 10
#define CH 8192               /* FFN row chunk */
#define QKVN 1536
#define NB 4                  /* batches per quarter */
#define QM (NB * LL)          /* 16384 rows per quarter */
#define NSPLIT 32
#define LCHUNK (LL / NSPLIT)  /* 128 */
#define PSTRIDE 68
#define MAXSLOT 128

typedef unsigned short ushort_t;
typedef unsigned int uint_t;
typedef short bf16x8 __attribute__((ext_vector_type(8)));
typedef float f32x4 __attribute__((ext_vector_type(4)));

#define GLD16(gp, lp) __builtin_amdgcn_global_load_lds((const __attribute__((address_space(1))) void*)(gp), (__attribute__((address_space(3))) void*)(lp), 16, 0, 0)

// ---------- helpers ----------
__device__ inline float wsum(float v){
#pragma unroll
  for (int o = 32; o > 0; o >>= 1) v += __shfl_xor(v, o);
  return v;
}
__device__ inline float wmax(float v){
#pragma unroll
  for (int o = 32; o > 0; o >>= 1) v = fmaxf(v, __shfl_xor(v, o));
  return v;
}
__device__ inline ushort_t f2bf_rtn(float f){
  uint_t u = __float_as_uint(f);
  uint_t r = u + 0x7FFF + ((u >> 16) & 1);
  return (ushort_t)(r >> 16);
}
__device__ inline float bf2f(ushort_t u){
  return __uint_as_float(((uint_t)u) << 16);
}
__device__ inline void split2(float x, ushort_t& hi, ushort_t& lo){
  uint_t u = __float_as_uint(x);
  hi = (ushort_t)(u >> 16);
  lo = f2bf_rtn(x - __uint_as_float(u & 0xFFFF0000u));
}
// bijective XCD-chunked swizzle (m204): consecutive linear ids -> same XCD chunk
__device__ inline void xcd_map(int& bx, int& by){
  const int gx = gridDim.x;
  const int nwg = gx * gridDim.y;
  const int wg = (int)blockIdx.y * gx + (int)blockIdx.x;
  const int q = nwg >> 3, r = nwg & 7;
  const int xcd = wg & 7, idx = wg >> 3;
  const int swz = (xcd < r ? xcd * (q + 1) : r * (q + 1) + (xcd - r) * q) + idx;
  bx = swz % gx; by = swz / gx;
}

// ---------- embed: h(split) = x @ w_embed + b_embed (packed uint stores) ----------
__global__ __launch_bounds__(256) void embed_kernel(const float* __restrict__ x,
    const float* __restrict__ we, const float* __restrict__ be,
    ushort_t* __restrict__ hh, ushort_t* __restrict__ hl){
  int row = blockIdx.x;
  __shared__ float xs[DIN];
  if (threadIdx.x < DIN) xs[threadIdx.x] = x[(size_t)row * DIN + threadIdx.x];
  __syncthreads();
  const int t = threadIdx.x;
  const int j0 = 2 * t;
  float a0 = be[j0], a1 = be[j0 + 1];
#pragma unroll
  for (int i = 0; i < DIN; ++i){
    a0 += xs[i] * we[i * DD + j0];
    a1 += xs[i] * we[i * DD + j0 + 1];
  }
  ushort_t h0, l0, h1, l1;
  split2(a0, h0, l0); split2(a1, h1, l1);
  ((uint_t*)(hh + (size_t)row * DD))[t] = (uint_t)h0 | ((uint_t)h1 << 16);
  ((uint_t*)(hl + (size_t)row * DD))[t] = (uint_t)l0 | ((uint_t)l1 << 16);
}

// ---------- weight prep ----------
__global__ __launch_bounds__(256) void wsplit_t_kernel(const float* __restrict__ W,
    ushort_t* __restrict__ Th, ushort_t* __restrict__ Tl, int K, int N){
  int idx = blockIdx.x * 256 + threadIdx.x;
  if (idx >= N * K) return;
  int n = idx / K, k = idx - n * K;
  ushort_t hi, lo;
  split2(W[(size_t)k * N + n], hi, lo);
  Th[idx] = hi; Tl[idx] = lo;
}
__global__ __launch_bounds__(256) void wqkv_prep_kernel(const float* __restrict__ wq,
    const float* __restrict__ wk, const float* __restrict__ wv,
    ushort_t* __restrict__ Th, ushort_t* __restrict__ Tl){
  int idx = blockIdx.x * 256 + threadIdx.x;
  if (idx >= QKVN * DD) return;
  int n = idx >> 9, k = idx & (DD - 1);
  const float* src = (n < 512) ? wq : (n < 1024) ? wk : wv;
  ushort_t hi, lo;
  split2(src[(size_t)k * DD + (n & 511)], hi, lo);
  Th[idx] = hi; Tl[idx] = lo;
}
__global__ __launch_bounds__(256) void bqkv_prep_kernel(const float* __restrict__ bq,
    const float* __restrict__ bk, const float* __restrict__ bv, float* __restrict__ bo_){
  int n = blockIdx.x * 256 + threadIdx.x;
  if (n >= QKVN) return;
  bo_[n] = (n < 512) ? bq[n] : (n < 1024) ? bk[n - 512] : bv[n - 1024];
}

// ---------- QKV GEMM: A pre-split bf16, Q cols x3 -> fp32, KV cols x2 -> bf16 ----------
__global__ __launch_bounds__(256) void gemm_qkv(
    const ushort_t* __restrict__ Ah, const ushort_t* __restrict__ Al,
    const ushort_t* __restrict__ Bh, const ushort_t* __restrict__ Bl,
    const float* __restrict__ bias, float* __restrict__ Q,
    ushort_t* __restrict__ KV){
  __shared__ __align__(16) ushort_t AsH[128 * 32];
  __shared__ __align__(16) ushort_t AsL[128 * 32];
  __shared__ __align__(16) ushort_t BsH[128 * 32];
  __shared__ __align__(16) ushort_t BsL[128 * 32];
  int bx, by; xcd_map(bx, by);
  const int tid  = threadIdx.x;
  const int lane = tid & 63;
  const int wv   = tid >> 6;
  const int m0   = by * 128;
  const int n0   = bx * 128;
  const bool isQ = (n0 < 512);
  const int wm   = (wv & 1) * 64;
  const int wn   = (wv >> 1) * 64;

  const int rowA = tid >> 2;
  const int qe   = (tid & 3) * 8;
  const int lds0 = tid * 8;
  const int lds1 = (tid + 256) * 8;

  f32x4 acc[4][4];
#pragma unroll
  for (int i = 0; i < 4; ++i)
#pragma unroll
    for (int j = 0; j < 4; ++j) acc[i][j] = (f32x4){0.f, 0.f, 0.f, 0.f};

  const int arow = lane & 15;
  const int koff = (lane >> 4) * 8;
  const int K = DD;

  for (int k0 = 0; k0 < K; k0 += 32){
    const size_t ga0 = (size_t)(m0 + rowA) * K + k0 + qe;
    const size_t ga1 = (size_t)(m0 + rowA + 64) * K + k0 + qe;
    const size_t gb0 = (size_t)(n0 + rowA) * K + k0 + qe;
    const size_t gb1 = (size_t)(n0 + rowA + 64) * K + k0 + qe;
    GLD16(Ah + ga0, &AsH[lds0]);  GLD16(Ah + ga1, &AsH[lds1]);
    GLD16(Al + ga0, &AsL[lds0]);  GLD16(Al + ga1, &AsL[lds1]);
    GLD16(Bh + gb0, &BsH[lds0]);  GLD16(Bh + gb1, &BsH[lds1]);
    if (isQ){ GLD16(Bl + gb0, &BsL[lds0]);  GLD16(Bl + gb1, &BsL[lds1]); }
    __syncthreads();

    bf16x8 ah[4], al[4], bh[4], bl[4];
#pragma unroll
    for (int i = 0; i < 4; ++i){
      ah[i] = *(const bf16x8*)&AsH[(wm + i * 16 + arow) * 32 + koff];
      al[i] = *(const bf16x8*)&AsL[(wm + i * 16 + arow) * 32 + koff];
      bh[i] = *(const bf16x8*)&BsH[(wn + i * 16 + arow) * 32 + koff];
      if (isQ) bl[i] = *(const bf16x8*)&BsL[(wn + i * 16 + arow) * 32 + koff];
    }
#pragma unroll
    for (int i = 0; i < 4; ++i)
#pragma unroll
      for (int j = 0; j < 4; ++j){
        acc[i][j] = __builtin_amdgcn_mfma_f32_16x16x32_bf16(ah[i], bh[j], acc[i][j], 0, 0, 0);
        acc[i][j] = __builtin_amdgcn_mfma_f32_16x16x32_bf16(al[i], bh[j], acc[i][j], 0, 0, 0);
        if (isQ)
          acc[i][j] = __builtin_amdgcn_mfma_f32_16x16x32_bf16(ah[i], bl[j], acc[i][j], 0, 0, 0);
      }
    __syncthreads();
  }

  const int crow = (lane >> 4) * 4;
  const int ccol = lane & 15;
#pragma unroll
  for (int i = 0; i < 4; ++i){
    const int gr0 = m0 + wm + i * 16 + crow;
#pragma unroll
    for (int j = 0; j < 4; ++j){
      const int gc = n0 + wn + j * 16 + ccol;
      const float bvv = bias[gc];
#pragma unroll
      for (int r = 0; r < 4; ++r){
        float v = acc[i][j][r] + bvv;
        const int gr = gr0 + r;
        if (isQ) Q[(size_t)gr * 512 + gc] = v;
        else     KV[(size_t)gr * 1024 + (gc - 512)] = f2bf_rtn(v);
      }
    }
  }
}

// ---------- FFN1: A split bf16, B=w1 hi only (x2), out = relu bf16 ----------
__global__ __launch_bounds__(256) void gemm_ffn1(
    const ushort_t* __restrict__ Ah, const ushort_t* __restrict__ Al,
    const ushort_t* __restrict__ Bh, const float* __restrict__ bias,
    ushort_t* __restrict__ Chid){
  __shared__ __align__(16) ushort_t AsH[128 * 32];
  __shared__ __align__(16) ushort_t AsL[128 * 32];
  __shared__ __align__(16) ushort_t BsH[128 * 32];
  int bx, by; xcd_map(bx, by);
  const int tid  = threadIdx.x;
  const int lane = tid & 63;
  const int wv   = tid >> 6;
  const int m0   = by * 128;
  const int n0   = bx * 128;
  const int wm   = (wv & 1) * 64;
  const int wn   = (wv >> 1) * 64;
  const int rowA = tid >> 2;
  const int qe   = (tid & 3) * 8;
  const int lds0 = tid * 8;
  const int lds1 = (tid + 256) * 8;

  f32x4 acc[4][4];
#pragma unroll
  for (int i = 0; i < 4; ++i)
#pragma unroll
    for (int j = 0; j < 4; ++j) acc[i][j] = (f32x4){0.f, 0.f, 0.f, 0.f};

  const int arow = lane & 15;
  const int koff = (lane >> 4) * 8;
  const int K = DD;

  for (int k0 = 0; k0 < K; k0 += 32){
    const size_t ga0 = (size_t)(m0 + rowA) * K + k0 + qe;
    const size_t ga1 = (size_t)(m0 + rowA + 64) * K + k0 + qe;
    const size_t gb0 = (size_t)(n0 + rowA) * K + k0 + qe;
    const size_t gb1 = (size_t)(n0 + rowA + 64) * K + k0 + qe;
    GLD16(Ah + ga0, &AsH[lds0]);  GLD16(Ah + ga1, &AsH[lds1]);
    GLD16(Al + ga0, &AsL[lds0]);  GLD16(Al + ga1, &AsL[lds1]);
    GLD16(Bh + gb0, &BsH[lds0]);  GLD16(Bh + gb1, &BsH[lds1]);
    __syncthreads();

    bf16x8 ah[4], al[4], bh[4];
#pragma unroll
    for (int i = 0; i < 4; ++i){
      ah[i] = *(const bf16x8*)&AsH[(wm + i * 16 + arow) * 32 + koff];
      al[i] = *(const bf16x8*)&AsL[(wm + i * 16 + arow) * 32 + koff];
      bh[i] = *(const bf16x8*)&BsH[(wn + i * 16 + arow) * 32 + koff];
    }
#pragma unroll
    for (int i = 0; i < 4; ++i)
#pragma unroll
      for (int j = 0; j < 4; ++j){
        acc[i][j] = __builtin_amdgcn_mfma_f32_16x16x32_bf16(ah[i], bh[j], acc[i][j], 0, 0, 0);
        acc[i][j] = __builtin_amdgcn_mfma_f32_16x16x32_bf16(al[i], bh[j], acc[i][j], 0, 0, 0);
      }
    __syncthreads();
  }

  const int crow = (lane >> 4) * 4;
  const int ccol = lane & 15;
#pragma unroll
  for (int i = 0; i < 4; ++i){
    const int gr0 = m0 + wm + i * 16 + crow;
#pragma unroll
    for (int j = 0; j < 4; ++j){
      const int gc = n0 + wn + j * 16 + ccol;
      const float bvv = bias[gc];
#pragma unroll
      for (int r = 0; r < 4; ++r){
        float v = fmaxf(acc[i][j][r] + bvv, 0.f);
        Chid[(size_t)(gr0 + r) * DFF + gc] = f2bf_rtn(v);
      }
    }
  }
}

// ---------- FFN2: A single bf16 (hid), B=w2 split (x2), split-K=2 partial fp32 out ----------
__global__ __launch_bounds__(256) void gemm_ffn2(
    const ushort_t* __restrict__ Ahid,
    const ushort_t* __restrict__ Bh, const ushort_t* __restrict__ Bl,
    float* __restrict__ pbuf, size_t pstr){
  __shared__ __align__(16) ushort_t AsH[128 * 32];
  __shared__ __align__(16) ushort_t BsH[128 * 32];
  __shared__ __align__(16) ushort_t BsL[128 * 32];
  int bx, by; xcd_map(bx, by);
  const int tid  = threadIdx.x;
  const int lane = tid & 63;
  const int wv   = tid >> 6;
  const int nblk = bx >> 1;
  const int kq   = bx & 1;
  const int m0   = by * 128;
  const int n0   = nblk * 128;
  const int wm   = (wv & 1) * 64;
  const int wn   = (wv >> 1) * 64;
  const int rowA = tid >> 2;
  const int qe   = (tid & 3) * 8;
  const int lds0 = tid * 8;
  const int lds1 = (tid + 256) * 8;

  f32x4 acc[4][4];
#pragma unroll
  for (int i = 0; i < 4; ++i)
#pragma unroll
    for (int j = 0; j < 4; ++j) acc[i][j] = (f32x4){0.f, 0.f, 0.f, 0.f};

  const int arow = lane & 15;
  const int koff = (lane >> 4) * 8;
  const int K = DFF;
  const int kper = K / 2;
  const int kbeg = kq * kper;

  for (int k0 = kbeg; k0 < kbeg + kper; k0 += 32){
    const size_t ga0 = (size_t)(m0 + rowA) * K + k0 + qe;
    const size_t ga1 = (size_t)(m0 + rowA + 64) * K + k0 + qe;
    const size_t gb0 = (size_t)(n0 + rowA) * K + k0 + qe;
    const size_t gb1 = (size_t)(n0 + rowA + 64) * K + k0 + qe;
    GLD16(Ahid + ga0, &AsH[lds0]);  GLD16(Ahid + ga1, &AsH[lds1]);
    GLD16(Bh + gb0, &BsH[lds0]);    GLD16(Bh + gb1, &BsH[lds1]);
    GLD16(Bl + gb0, &BsL[lds0]);    GLD16(Bl + gb1, &BsL[lds1]);
    __syncthreads();

    bf16x8 ah[4], bh[4], bl[4];
#pragma unroll
    for (int i = 0; i < 4; ++i){
      ah[i] = *(const bf16x8*)&AsH[(wm + i * 16 + arow) * 32 + koff];
      bh[i] = *(const bf16x8*)&BsH[(wn + i * 16 + arow) * 32 + koff];
      bl[i] = *(const bf16x8*)&BsL[(wn + i * 16 + arow) * 32 + koff];
    }
#pragma unroll
    for (int i = 0; i < 4; ++i)
#pragma unroll
      for (int j = 0; j < 4; ++j){
        acc[i][j] = __builtin_amdgcn_mfma_f32_16x16x32_bf16(ah[i], bh[j], acc[i][j], 0, 0, 0);
        acc[i][j] = __builtin_amdgcn_mfma_f32_16x16x32_bf16(ah[i], bl[j], acc[i][j], 0, 0, 0);
      }
    __syncthreads();
  }

  const int crow = (lane >> 4) * 4;
  const int ccol = lane & 15;
#pragma unroll
  for (int i = 0; i < 4; ++i){
    const int gr0 = m0 + wm + i * 16 + crow;
#pragma unroll
    for (int j = 0; j < 4; ++j){
      const int gc = n0 + wn + j * 16 + ccol;
#pragma unroll
      for (int r = 0; r < 4; ++r)
        pbuf[(size_t)kq * pstr + (size_t)(gr0 + r) * DD + gc] = acc[i][j][r];
    }
  }
}

// ---------- qs scoring, one quarter ----------
__global__ __launch_bounds__(256) void qs_kernel(const float* __restrict__ qbuf, float* __restrict__ qsb){
  int tid = threadIdx.x;
  int lane = tid & 63;
  int wv = tid >> 6;
  int rid = blockIdx.x * 4 + wv;
  int bloc = rid >> 15;
  int hh = (rid >> 12) & 7;
  int l  = rid & (LL - 1);
  float qv = qbuf[((size_t)bloc * LL + l) * DD + hh * DKK + lane];
  float l2 = sqrtf(wsum(qv * qv));
  float mx = wmax(qv);
  float e  = expf(qv - mx);
  float se = wsum(e);
  float p  = e / se;
  float ent = -wsum(p * logf(p + 1e-9f));
  float mu  = wsum(qv) * (1.0f / 64.0f);
  float dv  = qv - mu;
  float var = wsum(dv * dv) * (1.0f / 63.0f);
  float val = 0.5f * l2 + 0.3f * ent + 0.2f * var;
  if (lane == 0) qsb[(size_t)(bloc * HH + hh) * LL + l] = val;
}

// ---------- selection (incremental top-k: rescan only the winner's stripe) ----------
__global__ __launch_bounds__(256) void select_kernel(const float* __restrict__ qsb,
    int* __restrict__ topidx, int* __restrict__ ufac, int qtr){
  __shared__ float vals[LL];
  __shared__ float bv[256];
  __shared__ int   bi[256];
  __shared__ int   widx_s;
  __shared__ double r1[256], r2[256];
  const int bloc = blockIdx.y;
  const int b = qtr * NB + bloc;
  int tid = threadIdx.x;
  if (blockIdx.x == 8){
    const float* row = qsb + (size_t)bloc * HH * LL;
    double s = 0.0, s2 = 0.0;
    for (int l = tid; l < LL; l += 256){ double v = row[l]; s += v; s2 += v * v; }
    r1[tid] = s; r2[tid] = s2; __syncthreads();
    for (int st = 128; st; st >>= 1){
      if (tid < st){ r1[tid] += r1[tid+st]; r2[tid] += r2[tid+st]; }
      __syncthreads();
    }
    if (tid == 0){
      double mean = r1[0] / (double)LL;
      double var  = (r2[0] - (double)LL * mean * mean) / (double)(LL - 1);
      if (var < 0.0) var = 0.0;
      double f = rint(sqrt(var) / (mean + 1e-6) * 10.0);
      if (f < 3.0) f = 3.0;
      if (f > 10.0) f = 10.0;
      ufac[b] = (int)f;
    }
    return;
  }
  int hh = blockIdx.x;
  const float* row = qsb + ((size_t)bloc * HH + hh) * LL;
  for (int l = tid; l < LL; l += 256) vals[l] = row[l];
  __syncthreads();
  // local scan (strictly-greater keeps lowest index within stripe)
  float lmax = -INFINITY; int lidx = 0;
  for (int l = tid; l < LL; l += 256){
    float v = vals[l];
    if (v > lmax){ lmax = v; lidx = l; }
  }
  for (int it = 0; it < UMAX; ++it){
    bv[tid] = lmax; bi[tid] = lidx;
    __syncthreads();
    for (int st = 128; st; st >>= 1){
      if (tid < st){
        if (bv[tid+st] > bv[tid] || (bv[tid+st] == bv[tid] && bi[tid+st] < bi[tid])){
          bv[tid] = bv[tid+st]; bi[tid] = bi[tid+st];
        }
      }
      __syncthreads();
    }
    if (tid == 0){ topidx[(b * HH + hh) * UMAX + it] = bi[0]; widx_s = bi[0]; }
    __syncthreads();
    const int w = widx_s;
    if ((w & 255) == tid){
      vals[w] = -INFINITY;
      lmax = -INFINITY; lidx = 0;
      for (int l = tid; l < LL; l += 256){
        float v = vals[l];
        if (v > lmax){ lmax = v; lidx = l; }
      }
    }
    __syncthreads();
  }
}

// ---------- slot init / build ----------
__global__ void initslot_kernel(int* __restrict__ slotmap, int* __restrict__ scount){
  int i = blockIdx.x * 256 + threadIdx.x;
  if (i < BB * LL) slotmap[i] = -1;
  if (i < BB) scount[i] = 0;
}
__global__ __launch_bounds__(128) void slotbuild_kernel(const int* __restrict__ topidx,
    const int* __restrict__ ufac, int* __restrict__ slotmap, int* __restrict__ scount, int qtr){
  int t = threadIdx.x;
  int b = qtr * NB + blockIdx.x;
  if (t >= HH * UMAX) return;
  int hh = t / UMAX, rank = t % UMAX;
  if (rank >= ufac[b]) return;
  int qpos = topidx[(b * HH + hh) * UMAX + rank];
  int* cell = &slotmap[b * LL + qpos];
  int old = atomicCAS(cell, -1, -2);
  if (old == -1){
    int s = atomicAdd(&scount[b], 1);
    atomicExch(cell, s);
  }
}

// ---------- attention pass 1: K/V in regs once, loop over ranks ----------
// grid (NSPLIT, HH, NB)
__global__ __launch_bounds__(256) void attn_p1_kernel(const float* __restrict__ qbuf,
    const ushort_t* __restrict__ kvbuf,
    const int* __restrict__ topidx, const int* __restrict__ ufac,
    float* __restrict__ part, int qtr, int lmin){
  const int bloc = blockIdx.z;
  const int b = qtr * NB + bloc;
  const int hh = blockIdx.y;
  const int u = ufac[b];
  const int tid = threadIdx.x, lane = tid & 63, wv = tid >> 6;
  const int base = blockIdx.x * LCHUNK + wv * 32;

  const ushort_t* Kp = kvbuf + (size_t)bloc * LL * 1024 + hh * DKK + lane;
  const ushort_t* Vp = Kp + 512;
  float kreg[32], vreg[32];
#pragma unroll
  for (int i = 0; i < 32; ++i){
    kreg[i] = bf2f(Kp[(size_t)(base + i) * 1024]);
    vreg[i] = bf2f(Vp[(size_t)(base + i) * 1024]);
  }

  __shared__ float wm4[4], ws4[4];
  __shared__ float pvs[4][DKK];

  for (int rank = 0; rank < u; ++rank){
    const int qpos = topidx[(b * HH + hh) * UMAX + rank];
    if (qpos < lmin) continue;                 // block-uniform
    const float qv = qbuf[((size_t)bloc * LL + qpos) * DD + hh * DKK + lane];

    float sc[32];
    float mloc = -INFINITY;
#pragma unroll
    for (int i = 0; i < 32; ++i){
      float s = wsum(qv * kreg[i]) * 0.125f;
      sc[i] = s;
      mloc = fmaxf(mloc, s);
    }
    if (lane == 0) wm4[wv] = mloc;
    __syncthreads();
    const float M4 = fmaxf(fmaxf(wm4[0], wm4[1]), fmaxf(wm4[2], wm4[3]));

    float ssum = 0.f;
#pragma unroll
    for (int i = 0; i < 32; ++i){ float e = expf(sc[i] - M4); sc[i] = e; ssum += e; }

    float pv = 0.f;
#pragma unroll
    for (int i = 0; i < 32; ++i) pv += sc[i] * vreg[i];

    pvs[wv][lane] = pv;
    if (lane == 0) ws4[wv] = ssum;
    __syncthreads();
    if (wv == 0){
      const int rowid = hh * UMAX + rank;
      float* rec = part + (size_t)((bloc * HH * UMAX + rowid) * NSPLIT + blockIdx.x) * PSTRIDE;
      rec[lane] = pvs[0][lane] + pvs[1][lane] + pvs[2][lane] + pvs[3][lane];
      if (lane == 0){ rec[64] = M4; rec[65] = ws4[0] + ws4[1] + ws4[2] + ws4[3]; }
    }
    __syncthreads();
  }
}

// ---------- attention pass 2: combine + wo projection -> adelta ----------
__global__ __launch_bounds__(256) void attn_p2_kernel(const float* __restrict__ part,
    const float* __restrict__ wo, const int* __restrict__ topidx, const int* __restrict__ ufac,
    const int* __restrict__ slotmap, float* __restrict__ adelta, int qtr, int lmin){
  const int bloc = blockIdx.y;
  const int b = qtr * NB + bloc;
  const int rowid = blockIdx.x;
  const int hh = rowid / UMAX, rank = rowid % UMAX;
  if (rank >= ufac[b]) return;
  const int qpos = topidx[(b * HH + hh) * UMAX + rank];
  if (qpos < lmin) return;
  const int slot = slotmap[b * LL + qpos];

  const int tid = threadIdx.x;
  const float* pbase = part + (size_t)(bloc * HH * UMAX + rowid) * NSPLIT * PSTRIDE;
  __shared__ float pm[NSPLIT], ps[NSPLIT];
  __shared__ float orow[DKK];
  if (tid < NSPLIT){
    pm[tid] = pbase[(size_t)tid * PSTRIDE + 64];
    ps[tid] = pbase[(size_t)tid * PSTRIDE + 65];
  }
  __syncthreads();
  float M = -INFINITY;
#pragma unroll
  for (int i = 0; i < NSPLIT; ++i) M = fmaxf(M, pm[i]);
  float S = 0.f;
#pragma unroll
  for (int i = 0; i < NSPLIT; ++i) S += ps[i] * expf(pm[i] - M);
  if (tid < DKK){
    float acc = 0.f;
#pragma unroll
    for (int i = 0; i < NSPLIT; ++i)
      acc += pbase[(size_t)i * PSTRIDE + tid] * expf(pm[i] - M);
    orow[tid] = acc / S;
  }
  __syncthreads();
  float* drow = adelta + ((size_t)b * MAXSLOT + slot) * DD;
  for (int j = tid; j < DD; j += 256){
    float a = 0.f;
#pragma unroll
    for (int dd = 0; dd < DKK; ++dd) a += orow[dd] * wo[(size_t)(hh * DKK + dd) * DD + j];
    atomicAdd(&drow[j], a);
  }
}

// ---------- zero fill ----------
__global__ void zero_kernel(float* __restrict__ p, size_t n){
  size_t i = (size_t)blockIdx.x * 256 + threadIdx.x;
  size_t stride = (size_t)gridDim.x * 256;
  for (; i < n; i += stride) p[i] = 0.f;
}

// ---------- LN1: out = LN(h + bo + adelta[slot]) (split out, packed) ----------
template<bool TAIL>
__global__ __launch_bounds__(256) void ln1_kernel(
    const ushort_t* __restrict__ hh_, const ushort_t* __restrict__ hl_,
    const float* __restrict__ bo,
    const int* __restrict__ slotmap, const float* __restrict__ adelta,
    ushort_t* __restrict__ oh, ushort_t* __restrict__ ol,
    const float* __restrict__ g, const float* __restrict__ bb){
  __shared__ float red[256];
  int r = blockIdx.x, tid = threadIdx.x;
  int b, l;
  if (TAIL){ b = r / OUTLEN; l = TAIL0 + (r % OUTLEN); }
  else     { b = r >> 12;    l = r & (LL - 1); }
  const size_t gi = ((size_t)b * LL + l) * DD;
  const int j0 = 2 * tid;
  const uint_t hp = *(const uint_t*)(hh_ + gi + j0);
  const uint_t lp = *(const uint_t*)(hl_ + gi + j0);
  const float2 bo2 = *(const float2*)&bo[j0];
  float v0 = bf2f((ushort_t)(hp & 0xFFFF)) + bf2f((ushort_t)(lp & 0xFFFF)) + bo2.x;
  float v1 = bf2f((ushort_t)(hp >> 16))    + bf2f((ushort_t)(lp >> 16))    + bo2.y;
  int s = slotmap[b * LL + l];
  if (s >= 0){
    const float2 dr = *(const float2*)&adelta[((size_t)b * MAXSLOT + s) * DD + j0];
    v0 += dr.x; v1 += dr.y;
  }
  red[tid] = v0 + v1; __syncthreads();
  for (int st = 128; st; st >>= 1){ if (tid < st) red[tid] += red[tid+st]; __syncthreads(); }
  float mu = red[0] * (1.0f / DD); __syncthreads();
  float d0 = v0 - mu, d1 = v1 - mu;
  red[tid] = d0*d0 + d1*d1; __syncthreads();
  for (int st = 128; st; st >>= 1){ if (tid < st) red[tid] += red[tid+st]; __syncthreads(); }
  float rstd = rsqrtf(red[0] * (1.0f / DD) + 1e-5f);
  const float2 g2 = *(const float2*)&g[j0];
  const float2 bb2 = *(const float2*)&bb[j0];
  float o0 = d0 * rstd * g2.x + bb2.x;
  float o1 = d1 * rstd * g2.y + bb2.y;
  const size_t oo = TAIL ? (size_t)r * DD : gi;
  ushort_t h0, l0, h1, l1;
  split2(o0, h0, l0); split2(o1, h1, l1);
  *(uint_t*)(oh + oo + j0) = (uint_t)h0 | ((uint_t)h1 << 16);
  *(uint_t*)(ol + oo + j0) = (uint_t)l0 | ((uint_t)l1 << 16);
}

// ---------- LN2: out = LN(ln1out + p0 + p1 + b2) (packed) ----------
template<bool TAIL>
__global__ __launch_bounds__(256) void ln2_kernel(
    const ushort_t* __restrict__ ih, const ushort_t* __restrict__ il,
    const float* __restrict__ pbuf, size_t pstr, const float* __restrict__ b2,
    ushort_t* __restrict__ oh, ushort_t* __restrict__ ol, float* __restrict__ ofp,
    const float* __restrict__ g, const float* __restrict__ bb, size_t rowoff){
  __shared__ float red[256];
  int r = blockIdx.x, tid = threadIdx.x;
  const size_t gi = (rowoff + r) * DD;
  const size_t pi = (size_t)r * DD;
  const int j0 = 2 * tid;
  const uint_t hp = *(const uint_t*)(ih + gi + j0);
  const uint_t lp = *(const uint_t*)(il + gi + j0);
  const float2 p0 = *(const float2*)&pbuf[pi + j0];
  const float2 p1 = *(const float2*)&pbuf[pstr + pi + j0];
  const float2 b22 = *(const float2*)&b2[j0];
  float v0 = bf2f((ushort_t)(hp & 0xFFFF)) + bf2f((ushort_t)(lp & 0xFFFF)) + p0.x + p1.x + b22.x;
  float v1 = bf2f((ushort_t)(hp >> 16))    + bf2f((ushort_t)(lp >> 16))    + p0.y + p1.y + b22.y;
  red[tid] = v0 + v1; __syncthreads();
  for (int st = 128; st; st >>= 1){ if (tid < st) red[tid] += red[tid+st]; __syncthreads(); }
  float mu = red[0] * (1.0f / DD); __syncthreads();
  float d0 = v0 - mu, d1 = v1 - mu;
  red[tid] = d0*d0 + d1*d1; __syncthreads();
  for (int st = 128; st; st >>= 1){ if (tid < st) red[tid] += red[tid+st]; __syncthreads(); }
  float rstd = rsqrtf(red[0] * (1.0f / DD) + 1e-5f);
  const float2 g2 = *(const float2*)&g[j0];
  const float2 bb2 = *(const float2*)&bb[j0];
  float o0 = d0 * rstd * g2.x + bb2.x;
  float o1 = d1 * rstd * g2.y + bb2.y;
  if (TAIL){
    ofp[pi + j0] = o0; ofp[pi + j0 + 1] = o1;
  } else {
    ushort_t h0, l0, h1, l1;
    split2(o0, h0, l0); split2(o1, h1, l1);
    *(uint_t*)(oh + gi + j0) = (uint_t)h0 | ((uint_t)h1 << 16);
    *(uint_t*)(ol + gi + j0) = (uint_t)l0 | ((uint_t)l1 << 16);
  }
}

// ---------- final ----------
__global__ __launch_bounds__(64) void pred_kernel(const float* __restrict__ ht,
    const float* __restrict__ wout, const float* __restrict__ bout, float* __restrict__ out){
  int r = blockIdx.x, lane = threadIdx.x;
  float acc = 0.f;
  for (int dd = lane; dd < DD; dd += 64) acc += ht[(size_t)r * DD + dd] * wout[dd];
  acc = wsum(acc);
  if (lane == 0) out[r] = acc + bout[0];
}

extern "C" void kernel_launch(void* const* d_in, const int* in_sizes, int n_in,
                              void* d_out, int out_size, void* d_ws, size_t ws_size,
                              hipStream_t stream){
  const float* x    = (const float*)d_in[0];
  const float* wemb = (const float*)d_in[1];
  const float* bemb = (const float*)d_in[2];
  const float* wq   = (const float*)d_in[3];
  const float* bq   = (const float*)d_in[4];
  const float* wk   = (const float*)d_in[5];
  const float* bk   = (const float*)d_in[6];
  const float* wv   = (const float*)d_in[7];
  const float* bvv  = (const float*)d_in[8];
  const float* wo   = (const float*)d_in[9];
  const float* bo   = (const float*)d_in[10];
  const float* w1   = (const float*)d_in[11];
  const float* b1   = (const float*)d_in[12];
  const float* w2   = (const float*)d_in[13];
  const float* b2   = (const float*)d_in[14];
  const float* g1   = (const float*)d_in[15];
  const float* be1  = (const float*)d_in[16];
  const float* g2   = (const float*)d_in[17];
  const float* be2  = (const float*)d_in[18];
  const float* wout = (const float*)d_in[19];
  const float* bout = (const float*)d_in[20];
  float* out = (float*)d_out;
  char* wsb  = (char*)d_ws;

  const size_t MiB = 1024 * 1024;
  const size_t NE  = (size_t)BB * LL * DD;   // 33.5M elems

  size_t o = 0;
  ushort_t* hh    = (ushort_t*)(wsb + o); o += NE * 2;          // 64 MiB
  ushort_t* hl    = (ushort_t*)(wsb + o); o += NE * 2;          // 64 MiB
  char*     arena = wsb + o;              o += 64 * MiB;        // shared arena
  // QKV phase:
  float*    qbuf  = (float*)arena;                              // QM*512*4 = 32 MiB
  ushort_t* kvbuf = (ushort_t*)(arena + 32 * MiB);              // QM*1024*2 = 32 MiB
  // FFN phase (overlay): layer-1
  ushort_t* hid   = (ushort_t*)arena;                           // CH*DFF*2 = 32 MiB
  float*    pbuf  = (float*)(arena + 32 * MiB);                 // 2*CH*512*4 = 32 MiB
  // FFN phase tail overlay
  ushort_t* hidt  = (ushort_t*)arena;                           // NTAIL*DFF*2 = 6 MiB
  float*    pbuft = (float*)(arena + 32 * MiB);                 // 2*NTAIL*512*4 = 6 MiB
  ushort_t* asht  = (ushort_t*)(arena + 48 * MiB);              // NTAIL*512*2 = 1.5 MiB
  ushort_t* aslt  = (ushort_t*)(arena + 50 * MiB);              // 1.5 MiB
  // weights + small:
  ushort_t* wtqkvh = (ushort_t*)(wsb + o); o += (size_t)QKVN * DD * 2;
  ushort_t* wtqkvl = (ushort_t*)(wsb + o); o += (size_t)QKVN * DD * 2;
  ushort_t* w1th   = (ushort_t*)(wsb + o); o += (size_t)DFF * DD * 2;
  ushort_t* w2th   = (ushort_t*)(wsb + o); o += (size_t)DD * DFF * 2;
  ushort_t* w2tl   = (ushort_t*)(wsb + o); o += (size_t)DD * DFF * 2;
  ushort_t* w1tl   = (ushort_t*)(wsb + o); o += (size_t)DFF * DD * 2;  // scratch (unused)
  float*    bqkv   = (float*)(wsb + o);  o += QKVN * 4;
  float*    qsb    = (float*)(wsb + o);  o += (size_t)NB * HH * LL * 4;
  float*    part   = (float*)(wsb + o);  o += (size_t)NB * HH * UMAX * NSPLIT * PSTRIDE * 4;
  float*    adelta = (float*)(wsb + o);  o += (size_t)BB * MAXSLOT * DD * 4;   // 4 MiB
  float*    htail  = (float*)(wsb + o);  o += (size_t)NTAIL * DD * 4;          // 3 MiB
  int*      slotmap= (int*)(wsb + o);    o += (size_t)BB * LL * 4;             // 256 KiB
  int*      scount = (int*)(wsb + o);    o += BB * 4;
  int*      topidx = (int*)(wsb + o);    o += (size_t)BB * HH * UMAX * 4;
  int*      ufac   = (int*)(wsb + o);    o += 64;
  // total ~215 MiB (<= 234 proven-safe)

  wqkv_prep_kernel<<<(QKVN*DD + 255)/256, 256, 0, stream>>>(wq, wk, wv, wtqkvh, wtqkvl);
  bqkv_prep_kernel<<<(QKVN + 255)/256, 256, 0, stream>>>(bq, bk, bvv, bqkv);
  wsplit_t_kernel<<<(DFF*DD + 255)/256, 256, 0, stream>>>(w1, w1th, w1tl, DD, DFF);
  wsplit_t_kernel<<<(DD*DFF + 255)/256, 256, 0, stream>>>(w2, w2th, w2tl, DFF, DD);

  embed_kernel<<<BB * LL, 256, 0, stream>>>(x, wemb, bemb, hh, hl);

  for (int layer = 0; layer < 2; ++layer){
    const bool tail = (layer == 1);
    const int lmin = tail ? TAIL0 : 0;

    initslot_kernel<<<(BB*LL + 255)/256, 256, 0, stream>>>(slotmap, scount);
    zero_kernel<<<1024, 256, 0, stream>>>(adelta, (size_t)BB * MAXSLOT * DD);

    for (int qtr = 0; qtr < BB / NB; ++qtr){
      const size_t hoff = (size_t)qtr * QM * DD;
      gemm_qkv<<<dim3(QKVN/128, QM/128), 256, 0, stream>>>(
          hh + hoff, hl + hoff, wtqkvh, wtqkvl, bqkv, qbuf, kvbuf);
      qs_kernel<<<(NB*HH*LL)/4, 256, 0, stream>>>(qbuf, qsb);
      select_kernel<<<dim3(9, NB), 256, 0, stream>>>(qsb, topidx, ufac, qtr);
      slotbuild_kernel<<<NB, 128, 0, stream>>>(topidx, ufac, slotmap, scount, qtr);
      attn_p1_kernel<<<dim3(NSPLIT, HH, NB), 256, 0, stream>>>(
          qbuf, kvbuf, topidx, ufac, part, qtr, lmin);
      attn_p2_kernel<<<dim3(HH*UMAX, NB), 256, 0, stream>>>(
          part, wo, topidx, ufac, slotmap, adelta, qtr, lmin);
    }

    if (!tail){
      ln1_kernel<false><<<BB*LL, 256, 0, stream>>>(hh, hl, bo, slotmap, adelta, hh, hl, g1, be1);
      for (int c = 0; c < (BB*LL)/CH; ++c){
        const size_t roff = (size_t)c * CH;
        gemm_ffn1<<<dim3(DFF/128, CH/128), 256, 0, stream>>>(
            hh + roff * DD, hl + roff * DD, w1th, b1, hid);
        gemm_ffn2<<<dim3(8, CH/128), 256, 0, stream>>>(hid, w2th, w2tl, pbuf, (size_t)CH * DD);
        ln2_kernel<false><<<CH, 256, 0, stream>>>(
            hh, hl, pbuf, (size_t)CH * DD, b2, hh, hl, nullptr, g2, be2, roff);
      }
    } else {
      ln1_kernel<true><<<NTAIL, 256, 0, stream>>>(hh, hl, bo, slotmap, adelta, asht, aslt, g1, be1);
      gemm_ffn1<<<dim3(DFF/128, NTAIL/128), 256, 0, stream>>>(asht, aslt, w1th, b1, hidt);
      gemm_ffn2<<<dim3(8, NTAIL/128), 256, 0, stream>>>(hidt, w2th, w2tl, pbuft, (size_t)NTAIL * DD);
      ln2_kernel<true><<<NTAIL, 256, 0, stream>>>(
          asht, aslt, pbuft, (size_t)NTAIL * DD, b2, nullptr, nullptr, htail, g2, be2, 0);
      pred_kernel<<<NTAIL, 64, 0, stream>>>(htail, wout, bout, out);
    }
  }
  (void)in_sizes; (void)n_in; (void)out_size; (void)ws_size;
}